// Round 1
// baseline (3590.438 us; speedup 1.0000x reference)
//
#include <hip/hip_runtime.h>
#include <math.h>

// ---------------------------------------------------------------------------
// RatLayer forward, f32 baseline.
// H=1024 C=4 RH=16 HS=64 DR=8 M=4096 NH=16 HD=64 A_SIZE=48 B_SIZE=64
// B=2 L=2048 -> NTOK=4096 tokens.
// ---------------------------------------------------------------------------

constexpr int NTOK = 4096;

__device__ __forceinline__ float softplus_f(float x) {
    return (x > 20.0f) ? x : log1pf(expf(x));
}

// ---------------------------------------------------------------------------
// rat_read: y[o,h] = sum_c res[h*4+c] * W[h,o,c]; LayerNorm over h per o;
// out[t][o*1024+h] = yn*gamma + beta.  One block per token.
// ---------------------------------------------------------------------------
template <int NO>
__global__ __launch_bounds__(256) void rat_read_kernel(
    const float* __restrict__ res, const float* __restrict__ W,
    const float* __restrict__ gamma, const float* __restrict__ beta,
    float* __restrict__ out)
{
    const int t = blockIdx.x;
    const int tid = threadIdx.x;
    const float* rp = res + (size_t)t * 4096;
    float y[4][NO];
#pragma unroll
    for (int i = 0; i < 4; ++i) {
        const int h = tid + 256 * i;
        const float4 x = *(const float4*)(rp + h * 4);
#pragma unroll
        for (int o = 0; o < NO; ++o) {
            const float4 w = *(const float4*)(W + ((size_t)h * NO + o) * 4);
            y[i][o] = x.x * w.x + x.y * w.y + x.z * w.z + x.w * w.w;
        }
    }
    __shared__ float red[4][NO][2];
    const int lane = tid & 63, wid = tid >> 6;
#pragma unroll
    for (int o = 0; o < NO; ++o) {
        float s = 0.f, ss = 0.f;
#pragma unroll
        for (int i = 0; i < 4; ++i) { s += y[i][o]; ss += y[i][o] * y[i][o]; }
        for (int off = 32; off > 0; off >>= 1) {
            s += __shfl_down(s, off);
            ss += __shfl_down(ss, off);
        }
        if (lane == 0) { red[wid][o][0] = s; red[wid][o][1] = ss; }
    }
    __syncthreads();
    float mu[NO], rs[NO];
#pragma unroll
    for (int o = 0; o < NO; ++o) {
        const float s  = red[0][o][0] + red[1][o][0] + red[2][o][0] + red[3][o][0];
        const float ss = red[0][o][1] + red[1][o][1] + red[2][o][1] + red[3][o][1];
        const float m = s * (1.0f / 1024.0f);
        const float v = ss * (1.0f / 1024.0f) - m * m;
        mu[o] = m;
        rs[o] = rsqrtf(v + 1e-5f);
    }
    float* op = out + (size_t)t * (NO * 1024);
#pragma unroll
    for (int i = 0; i < 4; ++i) {
        const int h = tid + 256 * i;
#pragma unroll
        for (int o = 0; o < NO; ++o) {
            op[o * 1024 + h] = (y[i][o] - mu[o]) * rs[o] * gamma[o * 1024 + h] + beta[o * 1024 + h];
        }
    }
}

// ---------------------------------------------------------------------------
// f32 GEMM: C[m,o] = sum_k A[m,k] * W[o,k]  (A row-major lda, W row-major ldw)
// 128x128 tile, BK=16, 256 threads, 8x8 per thread, k-major LDS.
// grid.z = split-K chunks (Kblk each), partials at C + z*NTOK*ldc.
// EPI: 0 plain, 1 +bias[col], 2 silu(acc)*C_inplace (gate*up fusion).
// ---------------------------------------------------------------------------
template <int EPI>
__global__ __launch_bounds__(256) void gemm_kernel(
    const float* __restrict__ A, int lda,
    const float* __restrict__ W, int ldw,
    const float* __restrict__ bias,
    float* __restrict__ C, int ldc,
    int Kblk, int O)
{
    __shared__ float As[16][128];
    __shared__ float Bs[16][128];
    const int bm = blockIdx.x * 128;
    const int bo = blockIdx.y * 128;
    const int kstart = blockIdx.z * Kblk;
    const int tid = threadIdx.x;
    const int tx = tid & 15, ty = tid >> 4;
    const int lr = tid >> 2;
    const int lk = (tid & 3) * 4;
    float acc[8][8];
#pragma unroll
    for (int i = 0; i < 8; ++i)
#pragma unroll
        for (int j = 0; j < 8; ++j) acc[i][j] = 0.0f;

    const int o0 = bo + lr, o1 = bo + lr + 64;
    const float* Ar0 = A + (size_t)(bm + lr) * lda + lk;
    const float* Ar1 = A + (size_t)(bm + lr + 64) * lda + lk;
    const float* Wr0 = W + (size_t)o0 * ldw + lk;
    const float* Wr1 = W + (size_t)o1 * ldw + lk;
    const bool vo0 = (o0 < O), vo1 = (o1 < O);
    float* Cz = C + (size_t)blockIdx.z * NTOK * ldc;

    for (int k0 = kstart; k0 < kstart + Kblk; k0 += 16) {
        const float4 a0 = *(const float4*)(Ar0 + k0);
        const float4 a1 = *(const float4*)(Ar1 + k0);
        const float4 b0 = vo0 ? *(const float4*)(Wr0 + k0) : make_float4(0, 0, 0, 0);
        const float4 b1 = vo1 ? *(const float4*)(Wr1 + k0) : make_float4(0, 0, 0, 0);
        __syncthreads();
        {
            const float aa0[4] = {a0.x, a0.y, a0.z, a0.w};
            const float aa1[4] = {a1.x, a1.y, a1.z, a1.w};
            const float bb0[4] = {b0.x, b0.y, b0.z, b0.w};
            const float bb1[4] = {b1.x, b1.y, b1.z, b1.w};
#pragma unroll
            for (int j = 0; j < 4; ++j) {
                As[lk + j][lr]      = aa0[j];
                As[lk + j][lr + 64] = aa1[j];
                Bs[lk + j][lr]      = bb0[j];
                Bs[lk + j][lr + 64] = bb1[j];
            }
        }
        __syncthreads();
#pragma unroll
        for (int kk = 0; kk < 16; ++kk) {
            const float4 A0 = *(const float4*)&As[kk][ty * 4];
            const float4 A1 = *(const float4*)&As[kk][ty * 4 + 64];
            const float4 B0 = *(const float4*)&Bs[kk][tx * 4];
            const float4 B1 = *(const float4*)&Bs[kk][tx * 4 + 64];
            const float av[8] = {A0.x, A0.y, A0.z, A0.w, A1.x, A1.y, A1.z, A1.w};
            const float bv[8] = {B0.x, B0.y, B0.z, B0.w, B1.x, B1.y, B1.z, B1.w};
#pragma unroll
            for (int i = 0; i < 8; ++i)
#pragma unroll
                for (int j = 0; j < 8; ++j)
                    acc[i][j] = fmaf(av[i], bv[j], acc[i][j]);
        }
    }

#pragma unroll
    for (int i = 0; i < 8; ++i) {
        const int row = bm + ty * 4 + (i & 3) + (i >> 2) * 64;
#pragma unroll
        for (int j = 0; j < 8; ++j) {
            const int col = bo + tx * 4 + (j & 3) + (j >> 2) * 64;
            if (col < O) {
                float vv = acc[i][j];
                if (EPI == 1) vv += bias[col];
                if (EPI == 2) {
                    const float u = Cz[(size_t)row * ldc + col];
                    vv = vv / (1.0f + expf(-vv)) * u;   // silu(gate)*up
                }
                Cz[(size_t)row * ldc + col] = vv;
            }
        }
    }
}

// Sum split-K partials (nz x NTOK x 112) + bias -> C (NTOK x 112).
__global__ __launch_bounds__(256) void splitk_reduce_kernel(
    const float* __restrict__ part, const float* __restrict__ bias,
    float* __restrict__ C, int nz)
{
    const int idx = blockIdx.x * 256 + threadIdx.x;   // < NTOK*112
    const int col = idx % 112;
    float s = bias[col];
    for (int z = 0; z < nz; ++z) s += part[(size_t)z * NTOK * 112 + idx];
    C[idx] = s;
}

// ---------------------------------------------------------------------------
// RoPE in-place on q,k (N x 1024), pos = token & 2047 (position_ids = arange).
// ---------------------------------------------------------------------------
__global__ __launch_bounds__(256) void rope_kernel(float* __restrict__ q, float* __restrict__ k)
{
    const int idx = blockIdx.x * 256 + threadIdx.x;   // < NTOK*16*32
    const int i  = idx & 31;
    const int nh = (idx >> 5) & 15;
    const int t  = idx >> 9;
    const int pos = t & 2047;
    const float inv = expf(-(float)i * (9.210340371976184f / 32.0f));  // 10000^(-i/32)
    float s, c;
    sincosf((float)pos * inv, &s, &c);
    const size_t base = (size_t)t * 1024 + nh * 64 + i;
    const float q1 = q[base], q2 = q[base + 32];
    q[base]      = q1 * c - q2 * s;
    q[base + 32] = q2 * c + q1 * s;
    const float k1 = k[base], k2 = k[base + 32];
    k[base]      = k1 * c - k2 * s;
    k[base + 32] = k2 * c + k1 * s;
}

// ---------------------------------------------------------------------------
// Flash attention, f32. Block = 256 thr, one (b,h,qtile of 64 rows).
// Q,K transposed in LDS; V via broadcast global loads (L2-hot).
// Online softmax; scale 1/8; causal.
// ---------------------------------------------------------------------------
__global__ __launch_bounds__(256) void attn_kernel(
    const float* __restrict__ Q, const float* __restrict__ K,
    const float* __restrict__ V, float* __restrict__ Out)
{
    __shared__ float Qs[64][64];
    __shared__ float Ks[64][64];
    __shared__ float Ps[64][65];
    __shared__ float redm[4][64];
    __shared__ float reds[4][64];
    const int qb = blockIdx.x;          // 0..31
    const int bh = blockIdx.y;          // 0..31
    const int b = bh >> 4, h = bh & 15;
    const int tid = threadIdx.x;
    const size_t tok0 = (size_t)b * 2048;
    const int hoff = h * 64;

    {   // stage Q tile transposed: Qs[d][r]
        const int rr0 = tid >> 4;
        const int d0 = (tid & 15) * 4;
        for (int rr = rr0; rr < 64; rr += 16) {
            const float4 qv = *(const float4*)(Q + (tok0 + qb * 64 + rr) * 1024 + hoff + d0);
            Qs[d0 + 0][rr] = qv.x; Qs[d0 + 1][rr] = qv.y;
            Qs[d0 + 2][rr] = qv.z; Qs[d0 + 3][rr] = qv.w;
        }
    }
    const int tx = tid & 15, ty = tid >> 4;       // S-GEMM mapping
    const int r_own = tid & 63, part = tid >> 6;  // softmax/PV mapping
    float m_run = -3.0e38f, l_run = 0.0f;
    float o_acc[16];
#pragma unroll
    for (int i = 0; i < 16; ++i) o_acc[i] = 0.0f;
    const float* Vbase = V + tok0 * 1024 + hoff + part * 16;

    for (int kb = 0; kb <= qb; ++kb) {
        __syncthreads();   // prior iteration's Ks/Ps reads done
        {   // stage K tile transposed: Ks[d][c]
            const int rr0 = tid >> 4;
            const int d0 = (tid & 15) * 4;
            for (int rr = rr0; rr < 64; rr += 16) {
                const float4 kv = *(const float4*)(K + (tok0 + kb * 64 + rr) * 1024 + hoff + d0);
                Ks[d0 + 0][rr] = kv.x; Ks[d0 + 1][rr] = kv.y;
                Ks[d0 + 2][rr] = kv.z; Ks[d0 + 3][rr] = kv.w;
            }
        }
        __syncthreads();

        // S = Q K^T (4x4 per thread)
        float s[4][4];
#pragma unroll
        for (int i = 0; i < 4; ++i)
#pragma unroll
            for (int j = 0; j < 4; ++j) s[i][j] = 0.0f;
#pragma unroll 4
        for (int d = 0; d < 64; ++d) {
            const float4 qv = *(const float4*)&Qs[d][ty * 4];
            const float4 kv = *(const float4*)&Ks[d][tx * 4];
            const float qa[4] = {qv.x, qv.y, qv.z, qv.w};
            const float ka[4] = {kv.x, kv.y, kv.z, kv.w};
#pragma unroll
            for (int i = 0; i < 4; ++i)
#pragma unroll
                for (int j = 0; j < 4; ++j)
                    s[i][j] = fmaf(qa[i], ka[j], s[i][j]);
        }
        // mask + scale -> Ps
#pragma unroll
        for (int i = 0; i < 4; ++i) {
            const int rq = qb * 64 + ty * 4 + i;
#pragma unroll
            for (int j = 0; j < 4; ++j) {
                const int ck = kb * 64 + tx * 4 + j;
                Ps[ty * 4 + i][tx * 4 + j] = (ck <= rq) ? s[i][j] * 0.125f : -1.0e30f;
            }
        }
        __syncthreads();

        // online softmax: thread owns (row r_own, 16 cols at part*16)
        float sv[16];
        float mloc = -3.0e38f;
#pragma unroll
        for (int i = 0; i < 16; ++i) {
            sv[i] = Ps[r_own][part * 16 + i];
            mloc = fmaxf(mloc, sv[i]);
        }
        redm[part][r_own] = mloc;
        __syncthreads();
        const float mtile = fmaxf(fmaxf(redm[0][r_own], redm[1][r_own]),
                                  fmaxf(redm[2][r_own], redm[3][r_own]));
        const float mnew = fmaxf(m_run, mtile);
        float lsum = 0.0f;
#pragma unroll
        for (int i = 0; i < 16; ++i) {
            const float p = __expf(sv[i] - mnew);
            Ps[r_own][part * 16 + i] = p;
            lsum += p;
        }
        reds[part][r_own] = lsum;
        const float fac = __expf(m_run - mnew);
        __syncthreads();
        l_run = l_run * fac + reds[0][r_own] + reds[1][r_own] + reds[2][r_own] + reds[3][r_own];
        m_run = mnew;
#pragma unroll
        for (int i = 0; i < 16; ++i) o_acc[i] *= fac;

        // PV: o[r, part*16+i] += sum_j P[r][j] * V[kb*64+j][part*16+i]
        const float* Vk = Vbase + (size_t)(kb * 64) * 1024;
#pragma unroll 4
        for (int j = 0; j < 64; ++j) {
            const float p = Ps[r_own][j];
            const float4 v0 = *(const float4*)(Vk + (size_t)j * 1024 + 0);
            const float4 v1 = *(const float4*)(Vk + (size_t)j * 1024 + 4);
            const float4 v2 = *(const float4*)(Vk + (size_t)j * 1024 + 8);
            const float4 v3 = *(const float4*)(Vk + (size_t)j * 1024 + 12);
            o_acc[0]  = fmaf(p, v0.x, o_acc[0]);  o_acc[1]  = fmaf(p, v0.y, o_acc[1]);
            o_acc[2]  = fmaf(p, v0.z, o_acc[2]);  o_acc[3]  = fmaf(p, v0.w, o_acc[3]);
            o_acc[4]  = fmaf(p, v1.x, o_acc[4]);  o_acc[5]  = fmaf(p, v1.y, o_acc[5]);
            o_acc[6]  = fmaf(p, v1.z, o_acc[6]);  o_acc[7]  = fmaf(p, v1.w, o_acc[7]);
            o_acc[8]  = fmaf(p, v2.x, o_acc[8]);  o_acc[9]  = fmaf(p, v2.y, o_acc[9]);
            o_acc[10] = fmaf(p, v2.z, o_acc[10]); o_acc[11] = fmaf(p, v2.w, o_acc[11]);
            o_acc[12] = fmaf(p, v3.x, o_acc[12]); o_acc[13] = fmaf(p, v3.y, o_acc[13]);
            o_acc[14] = fmaf(p, v3.z, o_acc[14]); o_acc[15] = fmaf(p, v3.w, o_acc[15]);
        }
    }

    const float invl = 1.0f / l_run;
    float* op = Out + (tok0 + qb * 64 + r_own) * 1024 + hoff + part * 16;
#pragma unroll
    for (int i = 0; i < 4; ++i) {
        *(float4*)(op + i * 4) = make_float4(o_acc[4 * i + 0] * invl, o_acc[4 * i + 1] * invl,
                                             o_acc[4 * i + 2] * invl, o_acc[4 * i + 3] * invl);
    }
}

// ---------------------------------------------------------------------------
// rat_write: fused du-projection (K=8) + softplus + SSM update.
// out[t][h*4+c] = res[t][h*4+c]*A_full[c] + od[t][h]*B_full[c]
// One block per token. res/out may alias (elementwise same-thread RMW).
// ---------------------------------------------------------------------------
__global__ __launch_bounds__(256) void rat_write_kernel(
    const float* res, const float* __restrict__ od,
    const float* __restrict__ AB, const float* __restrict__ du_w,
    const float* __restrict__ du_b, float* out)
{
    const int t = blockIdx.x;
    const int tid = threadIdx.x;
    __shared__ float sAB[112];
    __shared__ float sdl[8];
    if (tid < 112) sAB[tid] = AB[(size_t)t * 112 + tid];
    if (tid >= 128 && tid < 136) sdl[tid - 128] = od[(size_t)t * 1032 + 1024 + (tid - 128)];
    __syncthreads();
    const float* rp = res + (size_t)t * 4096;
    const float* odp = od + (size_t)t * 1032;
    float* op = out + (size_t)t * 4096;
#pragma unroll
    for (int ii = 0; ii < 4; ++ii) {
        const int hh = tid + 256 * ii;
        const int rh = hh & 15;
        const float4 w0 = *(const float4*)(du_w + hh * 8);
        const float4 w1 = *(const float4*)(du_w + hh * 8 + 4);
        float dacc = du_b[hh];
        dacc += sdl[0] * w0.x + sdl[1] * w0.y + sdl[2] * w0.z + sdl[3] * w0.w;
        dacc += sdl[4] * w1.x + sdl[5] * w1.y + sdl[6] * w1.z + sdl[7] * w1.w;
        const float delta = softplus_f(dacc);
        const float oh = odp[hh];
        const float4 hs = *(const float4*)(rp + hh * 4);
        const float r4[4] = {hs.x, hs.y, hs.z, hs.w};
        float o4[4];
#pragma unroll
        for (int c = 0; c < 3; ++c) {
            const float Aneg = -softplus_f(sAB[rh * 3 + c]);
            const float Abar = expf(delta * Aneg);
            const float Bbar = (Abar - 1.0f) / (Aneg - 1e-5f) * sAB[48 + rh * 3 + c];
            o4[c] = r4[c] * Abar + oh * Bbar;
        }
        o4[3] = r4[3] + oh * (delta * sAB[96 + rh]);
        *(float4*)(op + hh * 4) = make_float4(o4[0], o4[1], o4[2], o4[3]);
    }
}

// ---------------------------------------------------------------------------
extern "C" void kernel_launch(void* const* d_in, const int* in_sizes, int n_in,
                              void* d_out, int out_size, void* d_ws, size_t ws_size,
                              hipStream_t stream)
{
    const float* hidden      = (const float*)d_in[0];
    // d_in[1] = position_ids (== arange(L) tiled; pos derived from token index)
    const float* attn_read_w = (const float*)d_in[2];
    const float* attn_read_g = (const float*)d_in[3];
    const float* attn_read_b = (const float*)d_in[4];
    const float* qkv_w       = (const float*)d_in[5];
    const float* attn_wod_w  = (const float*)d_in[6];
    const float* attn_wab_w  = (const float*)d_in[7];
    const float* attn_wab_b  = (const float*)d_in[8];
    const float* attn_du_w   = (const float*)d_in[9];
    const float* attn_du_b   = (const float*)d_in[10];
    const float* mlp_read_w  = (const float*)d_in[11];
    const float* mlp_read_g  = (const float*)d_in[12];
    const float* mlp_read_b  = (const float*)d_in[13];
    const float* mlp_in_w    = (const float*)d_in[14];
    const float* mlp_wod_w   = (const float*)d_in[15];
    const float* mlp_wab_w   = (const float*)d_in[16];
    const float* mlp_wab_b   = (const float*)d_in[17];
    const float* mlp_du_w    = (const float*)d_in[18];
    const float* mlp_du_b    = (const float*)d_in[19];
    float* out = (float*)d_out;
    float* ws  = (float*)d_ws;
    const size_t N = NTOK;

    // workspace layout (floats), phase-aliased; total N*8184 = 134 MB
    float* qkv_in = ws;                       // [N*3072]   attn phase
    float* q_     = ws + N * 3072;            // [N*1024]
    float* k_     = ws + N * 4096;            // [N*1024]
    float* v_     = ws + N * 5120;            // [N*1024]
    float* atno   = ws + N * 6144;            // [N*1024]
    float* od_a   = ws;                       // [N*1032]   after qkv_in dead
    float* ab_a   = ws + N * 1032;            // [N*112]
    float* mlp_in = ws;                       // [N*2048]   after od_a/ab_a dead
    float* up_    = ws + N * 2048;            // [N*4096]
    float* od_m   = ws + N * 6144;            // [N*1032]
    float* ab_m   = ws + N * 7176;            // [N*112]
    float* skp    = ws + N * 7288;            // [8*N*112]  split-K partials

    // ---- attention half ----
    rat_read_kernel<3><<<N, 256, 0, stream>>>(hidden, attn_read_w, attn_read_g, attn_read_b, qkv_in);

    gemm_kernel<0><<<dim3(32, 8), 256, 0, stream>>>(qkv_in + 0,    3072, qkv_w + 0,                1024, nullptr, q_, 1024, 1024, 1024);
    gemm_kernel<0><<<dim3(32, 8), 256, 0, stream>>>(qkv_in + 1024, 3072, qkv_w + 1024 * 1024,      1024, nullptr, k_, 1024, 1024, 1024);
    gemm_kernel<0><<<dim3(32, 8), 256, 0, stream>>>(qkv_in + 2048, 3072, qkv_w + 2 * 1024 * 1024,  1024, nullptr, v_, 1024, 1024, 1024);

    rope_kernel<<<(N * 16 * 32) / 256, 256, 0, stream>>>(q_, k_);

    attn_kernel<<<dim3(32, 32), 256, 0, stream>>>(q_, k_, v_, atno);

    gemm_kernel<0><<<dim3(32, 9), 256, 0, stream>>>(atno, 1024, attn_wod_w, 1024, nullptr, od_a, 1032, 1024, 1032);
    gemm_kernel<0><<<dim3(32, 1, 8), 256, 0, stream>>>(atno, 1024, attn_wab_w, 1024, nullptr, skp, 112, 128, 112);
    splitk_reduce_kernel<<<(N * 112) / 256, 256, 0, stream>>>(skp, attn_wab_b, ab_a, 8);

    rat_write_kernel<<<N, 256, 0, stream>>>(hidden, od_a, ab_a, attn_du_w, attn_du_b, out);

    // ---- MLP half ----
    rat_read_kernel<2><<<N, 256, 0, stream>>>(out, mlp_read_w, mlp_read_g, mlp_read_b, mlp_in);

    gemm_kernel<0><<<dim3(32, 32), 256, 0, stream>>>(mlp_in + 1024, 2048, mlp_in_w + 4096 * 1024, 1024, nullptr, up_, 4096, 1024, 4096);
    gemm_kernel<2><<<dim3(32, 32), 256, 0, stream>>>(mlp_in + 0,    2048, mlp_in_w,               1024, nullptr, up_, 4096, 1024, 4096);

    gemm_kernel<0><<<dim3(32, 9), 256, 0, stream>>>(up_, 4096, mlp_wod_w, 4096, nullptr, od_m, 1032, 4096, 1032);
    gemm_kernel<0><<<dim3(32, 1, 8), 256, 0, stream>>>(up_, 4096, mlp_wab_w, 4096, nullptr, skp, 112, 512, 112);
    splitk_reduce_kernel<<<(N * 112) / 256, 256, 0, stream>>>(skp, mlp_wab_b, ab_m, 8);

    rat_write_kernel<<<N, 256, 0, stream>>>(out, od_m, ab_m, mlp_du_w, mlp_du_b, out);
}

// Round 2
// 1385.639 us; speedup vs baseline: 2.5912x; 2.5912x over previous
//
#include <hip/hip_runtime.h>
#include <math.h>
#include <stdint.h>

// ---------------------------------------------------------------------------
// RatLayer forward, bf16-MFMA version.
// H=1024 C=4 RH=16 HS=64 DR=8 M=4096 NH=16 HD=64 A_SIZE=48 B_SIZE=64
// B=2 L=2048 -> NTOK=4096 tokens.
// ---------------------------------------------------------------------------

constexpr int NTOK = 4096;

typedef __attribute__((ext_vector_type(8))) short short8_t;
typedef __attribute__((ext_vector_type(4))) float f32x4;

__device__ __forceinline__ ushort f2bf(float f) {
    union { float f; uint32_t u; } v; v.f = f;
    uint32_t r = v.u + 0x7fffu + ((v.u >> 16) & 1u);
    return (ushort)(r >> 16);
}
__device__ __forceinline__ float bf2f(ushort b) {
    union { uint32_t u; float f; } v; v.u = ((uint32_t)b) << 16;
    return v.f;
}
__device__ __forceinline__ uint32_t pack2(float lo, float hi) {
    return (uint32_t)f2bf(lo) | ((uint32_t)f2bf(hi) << 16);
}
__device__ __forceinline__ float softplus_f(float x) {
    return (x > 20.0f) ? x : log1pf(expf(x));
}

// ---------------------------------------------------------------------------
// Weight conversion f32 -> bf16 (flat, and row-padded variants).
// ---------------------------------------------------------------------------
__global__ __launch_bounds__(256) void convert_flat_kernel(
    const float* __restrict__ src, ushort* __restrict__ dst)
{
    const size_t i = ((size_t)blockIdx.x * 256 + threadIdx.x) * 8;
    const float4 a = *(const float4*)(src + i);
    const float4 b = *(const float4*)(src + i + 4);
    union { ushort u[8]; uint4 v; } o;
    o.u[0] = f2bf(a.x); o.u[1] = f2bf(a.y); o.u[2] = f2bf(a.z); o.u[3] = f2bf(a.w);
    o.u[4] = f2bf(b.x); o.u[5] = f2bf(b.y); o.u[6] = f2bf(b.z); o.u[7] = f2bf(b.w);
    *(uint4*)(dst + i) = o.v;
}

__global__ __launch_bounds__(256) void convert_pad_kernel(
    const float* __restrict__ src, ushort* __restrict__ dst, int O, int K)
{
    const size_t i = ((size_t)blockIdx.x * 256 + threadIdx.x) * 8;
    const int row = (int)(i / (size_t)K);
    union { ushort u[8]; uint4 v; } o;
    if (row < O) {
        const float4 a = *(const float4*)(src + i);
        const float4 b = *(const float4*)(src + i + 4);
        o.u[0] = f2bf(a.x); o.u[1] = f2bf(a.y); o.u[2] = f2bf(a.z); o.u[3] = f2bf(a.w);
        o.u[4] = f2bf(b.x); o.u[5] = f2bf(b.y); o.u[6] = f2bf(b.z); o.u[7] = f2bf(b.w);
    } else {
        o.v = make_uint4(0, 0, 0, 0);
    }
    *(uint4*)(dst + i) = o.v;
}

// ---------------------------------------------------------------------------
// rat_read: y[o,h] = sum_c res[h*4+c] * W[h,o,c]; LayerNorm over h per o;
// writes bf16. One block per token.
// ---------------------------------------------------------------------------
template <int NO>
__global__ __launch_bounds__(256) void rat_read_kernel(
    const float* __restrict__ res, const float* __restrict__ W,
    const float* __restrict__ gamma, const float* __restrict__ beta,
    ushort* __restrict__ out)
{
    const int t = blockIdx.x;
    const int tid = threadIdx.x;
    const float* rp = res + (size_t)t * 4096;
    float y[4][NO];
#pragma unroll
    for (int i = 0; i < 4; ++i) {
        const int h = tid + 256 * i;
        const float4 x = *(const float4*)(rp + h * 4);
#pragma unroll
        for (int o = 0; o < NO; ++o) {
            const float4 w = *(const float4*)(W + ((size_t)h * NO + o) * 4);
            y[i][o] = x.x * w.x + x.y * w.y + x.z * w.z + x.w * w.w;
        }
    }
    __shared__ float red[4][NO][2];
    const int lane = tid & 63, wid = tid >> 6;
#pragma unroll
    for (int o = 0; o < NO; ++o) {
        float s = 0.f, ss = 0.f;
#pragma unroll
        for (int i = 0; i < 4; ++i) { s += y[i][o]; ss += y[i][o] * y[i][o]; }
        for (int off = 32; off > 0; off >>= 1) {
            s += __shfl_down(s, off);
            ss += __shfl_down(ss, off);
        }
        if (lane == 0) { red[wid][o][0] = s; red[wid][o][1] = ss; }
    }
    __syncthreads();
    float mu[NO], rs[NO];
#pragma unroll
    for (int o = 0; o < NO; ++o) {
        const float s  = red[0][o][0] + red[1][o][0] + red[2][o][0] + red[3][o][0];
        const float ss = red[0][o][1] + red[1][o][1] + red[2][o][1] + red[3][o][1];
        const float m = s * (1.0f / 1024.0f);
        const float v = ss * (1.0f / 1024.0f) - m * m;
        mu[o] = m;
        rs[o] = rsqrtf(v + 1e-5f);
    }
    ushort* op = out + (size_t)t * (NO * 1024);
#pragma unroll
    for (int i = 0; i < 4; ++i) {
        const int h = tid + 256 * i;
#pragma unroll
        for (int o = 0; o < NO; ++o) {
            op[o * 1024 + h] = f2bf((y[i][o] - mu[o]) * rs[o] * gamma[o * 1024 + h] + beta[o * 1024 + h]);
        }
    }
}

// ---------------------------------------------------------------------------
// bf16 MFMA GEMM: C[m,o] = sum_k A[m,k] * W[o,k], A [M][lda] bf16, W [Opad][ldw] bf16.
// 128x128 tile, BK=64, 256 thr = 4 waves (2x2 of 64x64), XOR-swizzled LDS.
// grid.z = split-K (Kblk each); EPI: 0 f32 (+z-offset partials), 1 bf16,
// 2 silu(acc)*U -> bf16, 3 transposed bf16 store C[col*ldc+row].
// ---------------------------------------------------------------------------
template <int EPI>
__global__ __launch_bounds__(256) void mfma_gemm_kernel(
    const ushort* __restrict__ A, int lda,
    const ushort* __restrict__ W, int ldw,
    void* __restrict__ Cp, int ldc, int O,
    const ushort* __restrict__ U,
    int Kblk)
{
    __shared__ ushort As[128 * 64];
    __shared__ ushort Bs[128 * 64];
    const int tid = threadIdx.x;
    const int bm = blockIdx.x * 128;
    const int bo = blockIdx.y * 128;
    const int w = tid >> 6, l = tid & 63;
    const int wr = (w >> 1) * 64, wc = (w & 1) * 64;
    const int lq = l & 15, lg = l >> 4;

    f32x4 acc[4][4];
#pragma unroll
    for (int i = 0; i < 4; ++i)
#pragma unroll
        for (int j = 0; j < 4; ++j) acc[i][j] = (f32x4){0.f, 0.f, 0.f, 0.f};

    const int srow = tid >> 3;            // staging row (8 thr/row, +32 per pass)
    const int scol = (tid & 7) * 8;       // bf16 elems
    const int sws  = scol ^ ((srow & 7) * 8);

    const ushort* Ap = A + (size_t)(bm + srow) * lda + (size_t)blockIdx.z * Kblk + scol;
    const ushort* Wp = W + (size_t)(bo + srow) * ldw + (size_t)blockIdx.z * Kblk + scol;
    const size_t a32 = (size_t)32 * lda, w32 = (size_t)32 * ldw;

    for (int k0 = 0; k0 < Kblk; k0 += 64) {
        uint4 av[4], bv[4];
#pragma unroll
        for (int p = 0; p < 4; ++p) {
            av[p] = *(const uint4*)(Ap + k0 + a32 * p);
            bv[p] = *(const uint4*)(Wp + k0 + w32 * p);
        }
        __syncthreads();   // prior tile's LDS reads complete
#pragma unroll
        for (int p = 0; p < 4; ++p) {
            *(uint4*)(As + (srow + 32 * p) * 64 + sws) = av[p];
            *(uint4*)(Bs + (srow + 32 * p) * 64 + sws) = bv[p];
        }
        __syncthreads();
#pragma unroll
        for (int ks = 0; ks < 2; ++ks) {
            short8_t af[4], bf[4];
            const int cE = ks * 32 + lg * 8;
#pragma unroll
            for (int mf = 0; mf < 4; ++mf) {
                const int ra = wr + mf * 16 + lq;
                af[mf] = *(const short8_t*)(As + ra * 64 + (cE ^ ((ra & 7) * 8)));
                const int rb = wc + mf * 16 + lq;
                bf[mf] = *(const short8_t*)(Bs + rb * 64 + (cE ^ ((rb & 7) * 8)));
            }
#pragma unroll
            for (int mf = 0; mf < 4; ++mf)
#pragma unroll
                for (int nf = 0; nf < 4; ++nf)
                    acc[mf][nf] = __builtin_amdgcn_mfma_f32_16x16x32_bf16(
                        af[mf], bf[nf], acc[mf][nf], 0, 0, 0);
        }
    }

#pragma unroll
    for (int mf = 0; mf < 4; ++mf) {
#pragma unroll
        for (int r = 0; r < 4; ++r) {
            const int row = bm + wr + mf * 16 + lg * 4 + r;
#pragma unroll
            for (int nf = 0; nf < 4; ++nf) {
                const int col = bo + wc + nf * 16 + lq;
                const float v = acc[mf][nf][r];
                if (EPI == 0) {
                    if (col < O)
                        ((float*)Cp)[(size_t)blockIdx.z * NTOK * ldc + (size_t)row * ldc + col] = v;
                } else if (EPI == 1) {
                    ((ushort*)Cp)[(size_t)row * ldc + col] = f2bf(v);
                } else if (EPI == 2) {
                    const float u = bf2f(U[(size_t)row * ldc + col]);
                    const float s = v / (1.0f + __expf(-v));
                    ((ushort*)Cp)[(size_t)row * ldc + col] = f2bf(s * u);
                } else {
                    ((ushort*)Cp)[(size_t)col * ldc + row] = f2bf(v);   // transposed
                }
            }
        }
    }
}

// Sum split-K partials (nz x NTOK x 112) + bias -> C (NTOK x 112) f32.
__global__ __launch_bounds__(256) void splitk_reduce_kernel(
    const float* __restrict__ part, const float* __restrict__ bias,
    float* __restrict__ C, int nz)
{
    const int idx = blockIdx.x * 256 + threadIdx.x;
    const int col = idx % 112;
    float s = bias[col];
    for (int z = 0; z < nz; ++z) s += part[(size_t)z * NTOK * 112 + idx];
    C[idx] = s;
}

// ---------------------------------------------------------------------------
// RoPE: read q,k f32, write bf16 Qb (scaled by 1/8) and Kb. pos = token & 2047.
// ---------------------------------------------------------------------------
__global__ __launch_bounds__(256) void rope_bf16_kernel(
    const float* __restrict__ q, const float* __restrict__ k,
    ushort* __restrict__ Qb, ushort* __restrict__ Kb)
{
    const int idx = blockIdx.x * 256 + threadIdx.x;   // < NTOK*512
    const int i  = idx & 31;
    const int nh = (idx >> 5) & 15;
    const int t  = idx >> 9;
    const int pos = t & 2047;
    const float inv = expf(-(float)i * (9.210340371976184f / 32.0f));
    float s, c;
    sincosf((float)pos * inv, &s, &c);
    const size_t base = (size_t)t * 1024 + nh * 64 + i;
    const float q1 = q[base], q2 = q[base + 32];
    Qb[base]      = f2bf((q1 * c - q2 * s) * 0.125f);
    Qb[base + 32] = f2bf((q2 * c + q1 * s) * 0.125f);
    const float k1 = k[base], k2 = k[base + 32];
    Kb[base]      = f2bf(k1 * c - k2 * s);
    Kb[base + 32] = f2bf(k2 * c + k1 * s);
}

// ---------------------------------------------------------------------------
// MFMA flash attention, bf16. Block = 256 thr = 4 independent waves, each
// owning 16 q-rows; grid (32 q-tiles, 32 b*h). LDS-free.
// Swapped QK^T (mfma(K,Q)) -> lane-local softmax; P redistributed via shfl.
// Vt is [1024 d][4096 tok] bf16. Qb pre-scaled by 1/8.
// ---------------------------------------------------------------------------
__global__ __launch_bounds__(256) void attn_mfma_kernel(
    const ushort* __restrict__ Qb, const ushort* __restrict__ Kb,
    const ushort* __restrict__ Vt, ushort* __restrict__ atno)
{
    const int qb = blockIdx.x;
    const int bh = blockIdx.y;
    const int b = bh >> 4, h = bh & 15;
    const int w = threadIdx.x >> 6, l = threadIdx.x & 63;
    const int g = l >> 4, t = l & 15;
    const int tok0 = b * 2048;
    const int hoff = h * 64;
    const int qrow = tok0 + qb * 64 + w * 16 + t;

    short8_t qf[2];
#pragma unroll
    for (int ks = 0; ks < 2; ++ks)
        qf[ks] = *(const short8_t*)(Qb + (size_t)qrow * 1024 + hoff + ks * 32 + g * 8);

    float m_run = -3.0e38f, l_run = 0.0f;
    f32x4 oacc[4];
#pragma unroll
    for (int nf = 0; nf < 4; ++nf) oacc[nf] = (f32x4){0.f, 0.f, 0.f, 0.f};

    const int srcA = ((g & 1) * 2) * 16 + t;
    const int srcB = srcA + 16;
    const bool hiSel = (g >> 1) != 0;

    for (int kb = 0; kb <= qb; ++kb) {
        const size_t kbase = (size_t)(tok0 + kb * 64) * 1024 + hoff;
        f32x4 sa[4];
#pragma unroll
        for (int mf = 0; mf < 4; ++mf) sa[mf] = (f32x4){0.f, 0.f, 0.f, 0.f};
#pragma unroll
        for (int ks = 0; ks < 2; ++ks) {
#pragma unroll
            for (int mf = 0; mf < 4; ++mf) {
                const short8_t kf = *(const short8_t*)(Kb + kbase + (size_t)(mf * 16 + t) * 1024 + ks * 32 + g * 8);
                sa[mf] = __builtin_amdgcn_mfma_f32_16x16x32_bf16(kf, qf[ks], sa[mf], 0, 0, 0);
            }
        }
        // lane holds S^T[k = mf*16+g*4+r][q-row = t] for this wave's q-rows.
        float p[4][4];
        float mloc = -3.0e38f;
#pragma unroll
        for (int mf = 0; mf < 4; ++mf)
#pragma unroll
            for (int r = 0; r < 4; ++r) {
                float s = sa[mf][r];
                if (kb == qb && (mf * 16 + g * 4 + r) > (w * 16 + t)) s = -3.0e38f;
                p[mf][r] = s;
                mloc = fmaxf(mloc, s);
            }
        mloc = fmaxf(mloc, __shfl_xor(mloc, 16));
        mloc = fmaxf(mloc, __shfl_xor(mloc, 32));
        const float mnew = fmaxf(m_run, mloc);
        float lsum = 0.f;
#pragma unroll
        for (int mf = 0; mf < 4; ++mf)
#pragma unroll
            for (int r = 0; r < 4; ++r) {
                const float e = __expf(p[mf][r] - mnew);
                p[mf][r] = e;
                lsum += e;
            }
        lsum += __shfl_xor(lsum, 16);
        lsum += __shfl_xor(lsum, 32);
        const float fac = __expf(m_run - mnew);
        l_run = l_run * fac + lsum;
        m_run = mnew;
        // rescale O: O rows are q = g*4+r, fac lives with lane t==q (lanes 0..15)
#pragma unroll
        for (int r = 0; r < 4; ++r) {
            const float fr = __shfl(fac, g * 4 + r);
#pragma unroll
            for (int nf = 0; nf < 4; ++nf) oacc[nf][r] *= fr;
        }
        // pack P rows to bf16 pairs
        uint32_t pk[4][2];
#pragma unroll
        for (int mf = 0; mf < 4; ++mf) {
            pk[mf][0] = pack2(p[mf][0], p[mf][1]);
            pk[mf][1] = pack2(p[mf][2], p[mf][3]);
        }
        // redistribute P to PV A-fragment layout + PV MFMAs
#pragma unroll
        for (int ks = 0; ks < 2; ++ks) {
            const uint32_t a00 = __shfl(pk[2 * ks][0], srcA);
            const uint32_t a01 = __shfl(pk[2 * ks][1], srcA);
            const uint32_t a10 = __shfl(pk[2 * ks + 1][0], srcA);
            const uint32_t a11 = __shfl(pk[2 * ks + 1][1], srcA);
            const uint32_t b00 = __shfl(pk[2 * ks][0], srcB);
            const uint32_t b01 = __shfl(pk[2 * ks][1], srcB);
            const uint32_t b10 = __shfl(pk[2 * ks + 1][0], srcB);
            const uint32_t b11 = __shfl(pk[2 * ks + 1][1], srcB);
            union { uint32_t u[4]; short8_t v; } pa;
            pa.u[0] = hiSel ? a10 : a00;
            pa.u[1] = hiSel ? a11 : a01;
            pa.u[2] = hiSel ? b10 : b00;
            pa.u[3] = hiSel ? b11 : b01;
#pragma unroll
            for (int nf = 0; nf < 4; ++nf) {
                const short8_t vf = *(const short8_t*)(
                    Vt + (size_t)(hoff + nf * 16 + t) * NTOK + tok0 + kb * 64 + ks * 32 + g * 8);
                oacc[nf] = __builtin_amdgcn_mfma_f32_16x16x32_bf16(pa.v, vf, oacc[nf], 0, 0, 0);
            }
        }
    }
    const float inv = 1.0f / l_run;
#pragma unroll
    for (int r = 0; r < 4; ++r) {
        const float ir = __shfl(inv, g * 4 + r);
        const int orow = tok0 + qb * 64 + w * 16 + g * 4 + r;
#pragma unroll
        for (int nf = 0; nf < 4; ++nf)
            atno[(size_t)orow * 1024 + hoff + nf * 16 + t] = f2bf(oacc[nf][r] * ir);
    }
}

// ---------------------------------------------------------------------------
// rat_write: fused du-projection (K=8) + softplus + SSM update. f32.
// ---------------------------------------------------------------------------
__global__ __launch_bounds__(256) void rat_write_kernel(
    const float* res, const float* __restrict__ od,
    const float* __restrict__ AB, const float* __restrict__ du_w,
    const float* __restrict__ du_b, float* out)
{
    const int t = blockIdx.x;
    const int tid = threadIdx.x;
    __shared__ float sAB[112];
    __shared__ float sdl[8];
    if (tid < 112) sAB[tid] = AB[(size_t)t * 112 + tid];
    if (tid >= 128 && tid < 136) sdl[tid - 128] = od[(size_t)t * 1032 + 1024 + (tid - 128)];
    __syncthreads();
    const float* rp = res + (size_t)t * 4096;
    const float* odp = od + (size_t)t * 1032;
    float* op = out + (size_t)t * 4096;
#pragma unroll
    for (int ii = 0; ii < 4; ++ii) {
        const int hh = tid + 256 * ii;
        const int rh = hh & 15;
        const float4 w0 = *(const float4*)(du_w + hh * 8);
        const float4 w1 = *(const float4*)(du_w + hh * 8 + 4);
        float dacc = du_b[hh];
        dacc += sdl[0] * w0.x + sdl[1] * w0.y + sdl[2] * w0.z + sdl[3] * w0.w;
        dacc += sdl[4] * w1.x + sdl[5] * w1.y + sdl[6] * w1.z + sdl[7] * w1.w;
        const float delta = softplus_f(dacc);
        const float oh = odp[hh];
        const float4 hs = *(const float4*)(rp + hh * 4);
        const float r4[4] = {hs.x, hs.y, hs.z, hs.w};
        float o4[4];
#pragma unroll
        for (int c = 0; c < 3; ++c) {
            const float Aneg = -softplus_f(sAB[rh * 3 + c]);
            const float Abar = expf(delta * Aneg);
            const float Bbar = (Abar - 1.0f) / (Aneg - 1e-5f) * sAB[48 + rh * 3 + c];
            o4[c] = r4[c] * Abar + oh * Bbar;
        }
        o4[3] = r4[3] + oh * (delta * sAB[96 + rh]);
        *(float4*)(op + hh * 4) = make_float4(o4[0], o4[1], o4[2], o4[3]);
    }
}

// ---------------------------------------------------------------------------
extern "C" void kernel_launch(void* const* d_in, const int* in_sizes, int n_in,
                              void* d_out, int out_size, void* d_ws, size_t ws_size,
                              hipStream_t stream)
{
    const float* hidden      = (const float*)d_in[0];
    const float* attn_read_w = (const float*)d_in[2];
    const float* attn_read_g = (const float*)d_in[3];
    const float* attn_read_b = (const float*)d_in[4];
    const float* qkv_w       = (const float*)d_in[5];
    const float* attn_wod_w  = (const float*)d_in[6];
    const float* attn_wab_w  = (const float*)d_in[7];
    const float* attn_wab_b  = (const float*)d_in[8];
    const float* attn_du_w   = (const float*)d_in[9];
    const float* attn_du_b   = (const float*)d_in[10];
    const float* mlp_read_w  = (const float*)d_in[11];
    const float* mlp_read_g  = (const float*)d_in[12];
    const float* mlp_read_b  = (const float*)d_in[13];
    const float* mlp_in_w    = (const float*)d_in[14];
    const float* mlp_wod_w   = (const float*)d_in[15];
    const float* mlp_wab_w   = (const float*)d_in[16];
    const float* mlp_wab_b   = (const float*)d_in[17];
    const float* mlp_du_w    = (const float*)d_in[18];
    const float* mlp_du_b    = (const float*)d_in[19];
    float* out = (float*)d_out;
    char* wsb = (char*)d_ws;
    const size_t N = NTOK;

    // ---- workspace layout (bytes), total 128.5 MB ----
    ushort* qkv_wb  = (ushort*)(wsb + 0);          // 3*1024*1024
    ushort* wodA_b  = (ushort*)(wsb + 6291456);    // 1152*1024
    ushort* wabA_b  = (ushort*)(wsb + 8650752);    // 128*1024
    ushort* mlpin_b = (ushort*)(wsb + 8912896);    // 2*4096*1024
    ushort* wodM_b  = (ushort*)(wsb + 25690112);   // 1152*4096
    ushort* wabM_b  = (ushort*)(wsb + 35127296);   // 128*4096
    char* R1 = wsb + 36175872;                     // 25.2 MB region
    char* R2 = wsb + 61341696;                     // 67.1 MB region
    ushort* qkv_in = (ushort*)R1;                  // [N*3072] bf16
    ushort* Qb     = (ushort*)R1;                  // [N*1024] bf16 (after qkv GEMMs)
    ushort* Kb     = (ushort*)(R1 + 8388608);
    ushort* Vt     = (ushort*)(R1 + 16777216);     // [1024][N] bf16
    ushort* mlp_in = (ushort*)R1;                  // [N*2048] bf16 (phase M)
    float*  od_m   = (float*)R1;                   // [N*1032] (after mlp_in dead)
    float*  ab_m   = (float*)(R1 + 16908288);      // [N*112]
    float*  q_     = (float*)R2;                   // [N*1024] f32
    float*  k_     = (float*)(R2 + 16777216);
    ushort* atno   = (ushort*)R2;                  // [N*1024] bf16 (after rope)
    float*  od_a   = (float*)(R2 + 8388608);       // [N*1032]
    float*  ab_a   = (float*)(R2 + 25296896);      // [N*112]
    float*  skpA   = (float*)(R2 + 27131904);      // [8*N*112]
    ushort* up_    = (ushort*)R2;                  // [N*4096] bf16 (phase M)
    ushort* upb    = (ushort*)(R2 + 33554432);     // [N*4096] bf16
    float*  skpM   = (float*)R2;                   // [8*N*112] (after up_ dead)

    // ---- weight conversion (bf16, zero-padded output rows) ----
    convert_flat_kernel<<<1536, 256, 0, stream>>>(qkv_w, qkv_wb);
    convert_flat_kernel<<<4096, 256, 0, stream>>>(mlp_in_w, mlpin_b);
    convert_pad_kernel<<<576, 256, 0, stream>>>(attn_wod_w, wodA_b, 1032, 1024);
    convert_pad_kernel<<<64, 256, 0, stream>>>(attn_wab_w, wabA_b, 112, 1024);
    convert_pad_kernel<<<2304, 256, 0, stream>>>(mlp_wod_w, wodM_b, 1032, 4096);
    convert_pad_kernel<<<256, 256, 0, stream>>>(mlp_wab_w, wabM_b, 112, 4096);

    // ---- attention half ----
    rat_read_kernel<3><<<N, 256, 0, stream>>>(hidden, attn_read_w, attn_read_g, attn_read_b, qkv_in);

    mfma_gemm_kernel<0><<<dim3(32, 8), 256, 0, stream>>>(qkv_in, 3072, qkv_wb, 1024, q_, 1024, 1024, nullptr, 1024);
    mfma_gemm_kernel<0><<<dim3(32, 8), 256, 0, stream>>>(qkv_in + 1024, 3072, qkv_wb + 1048576, 1024, k_, 1024, 1024, nullptr, 1024);
    mfma_gemm_kernel<3><<<dim3(32, 8), 256, 0, stream>>>(qkv_in + 2048, 3072, qkv_wb + 2097152, 1024, Vt, NTOK, 1024, nullptr, 1024);

    rope_bf16_kernel<<<8192, 256, 0, stream>>>(q_, k_, Qb, Kb);

    attn_mfma_kernel<<<dim3(32, 32), 256, 0, stream>>>(Qb, Kb, Vt, atno);

    mfma_gemm_kernel<0><<<dim3(32, 9), 256, 0, stream>>>(atno, 1024, wodA_b, 1024, od_a, 1032, 1032, nullptr, 1024);
    mfma_gemm_kernel<0><<<dim3(32, 1, 8), 256, 0, stream>>>(atno, 1024, wabA_b, 1024, skpA, 112, 112, nullptr, 128);
    splitk_reduce_kernel<<<1792, 256, 0, stream>>>(skpA, attn_wab_b, ab_a, 8);

    rat_write_kernel<<<N, 256, 0, stream>>>(hidden, od_a, ab_a, attn_du_w, attn_du_b, out);

    // ---- MLP half ----
    rat_read_kernel<2><<<N, 256, 0, stream>>>(out, mlp_read_w, mlp_read_g, mlp_read_b, mlp_in);

    mfma_gemm_kernel<1><<<dim3(32, 32), 256, 0, stream>>>(mlp_in + 1024, 2048, mlpin_b + 4194304, 1024, up_, 4096, 4096, nullptr, 1024);
    mfma_gemm_kernel<2><<<dim3(32, 32), 256, 0, stream>>>(mlp_in, 2048, mlpin_b, 1024, upb, 4096, 4096, up_, 1024);

    mfma_gemm_kernel<0><<<dim3(32, 9), 256, 0, stream>>>(upb, 4096, wodM_b, 4096, od_m, 1032, 1032, nullptr, 4096);
    mfma_gemm_kernel<0><<<dim3(32, 1, 8), 256, 0, stream>>>(upb, 4096, wabM_b, 4096, skpM, 112, 112, nullptr, 512);
    splitk_reduce_kernel<<<1792, 256, 0, stream>>>(skpM, mlp_wab_b, ab_m, 8);

    rat_write_kernel<<<N, 256, 0, stream>>>(out, od_m, ab_m, mlp_du_w, mlp_du_b, out);
}

// Round 3
// 754.580 us; speedup vs baseline: 4.7582x; 1.8363x over previous
//
#include <hip/hip_runtime.h>
#include <math.h>
#include <stdint.h>

// ---------------------------------------------------------------------------
// RatLayer forward, bf16-MFMA + global_load_lds 2-phase pipelined GEMM.
// H=1024 C=4 RH=16 HS=64 DR=8 M=4096 NH=16 HD=64 A_SIZE=48 B_SIZE=64
// B=2 L=2048 -> NTOK=4096 tokens.
// ---------------------------------------------------------------------------

constexpr int NTOK = 4096;

typedef __attribute__((ext_vector_type(8))) short short8_t;
typedef __attribute__((ext_vector_type(4))) float f32x4;

__device__ __forceinline__ ushort f2bf(float f) {
    union { float f; uint32_t u; } v; v.f = f;
    uint32_t r = v.u + 0x7fffu + ((v.u >> 16) & 1u);
    return (ushort)(r >> 16);
}
__device__ __forceinline__ float bf2f(ushort b) {
    union { uint32_t u; float f; } v; v.u = ((uint32_t)b) << 16;
    return v.f;
}
__device__ __forceinline__ uint32_t pack2(float lo, float hi) {
    return (uint32_t)f2bf(lo) | ((uint32_t)f2bf(hi) << 16);
}
__device__ __forceinline__ float softplus_f(float x) {
    return (x > 20.0f) ? x : log1pf(expf(x));
}

// async global->LDS, 16B per lane; LDS dest is wave-uniform base + lane*16.
__device__ __forceinline__ void gload_lds16(const void* g, void* l) {
    __builtin_amdgcn_global_load_lds(
        (const __attribute__((address_space(1))) uint32_t*)g,
        (__attribute__((address_space(3))) uint32_t*)l,
        16, 0, 0);
}

// ---------------------------------------------------------------------------
// Weight conversion f32 -> bf16 (flat, and row-padded variants).
// ---------------------------------------------------------------------------
__global__ __launch_bounds__(256) void convert_flat_kernel(
    const float* __restrict__ src, ushort* __restrict__ dst)
{
    const size_t i = ((size_t)blockIdx.x * 256 + threadIdx.x) * 8;
    const float4 a = *(const float4*)(src + i);
    const float4 b = *(const float4*)(src + i + 4);
    union { ushort u[8]; uint4 v; } o;
    o.u[0] = f2bf(a.x); o.u[1] = f2bf(a.y); o.u[2] = f2bf(a.z); o.u[3] = f2bf(a.w);
    o.u[4] = f2bf(b.x); o.u[5] = f2bf(b.y); o.u[6] = f2bf(b.z); o.u[7] = f2bf(b.w);
    *(uint4*)(dst + i) = o.v;
}

__global__ __launch_bounds__(256) void convert_pad_kernel(
    const float* __restrict__ src, ushort* __restrict__ dst, int O, int K)
{
    const size_t i = ((size_t)blockIdx.x * 256 + threadIdx.x) * 8;
    const int row = (int)(i / (size_t)K);
    union { ushort u[8]; uint4 v; } o;
    if (row < O) {
        const float4 a = *(const float4*)(src + i);
        const float4 b = *(const float4*)(src + i + 4);
        o.u[0] = f2bf(a.x); o.u[1] = f2bf(a.y); o.u[2] = f2bf(a.z); o.u[3] = f2bf(a.w);
        o.u[4] = f2bf(b.x); o.u[5] = f2bf(b.y); o.u[6] = f2bf(b.z); o.u[7] = f2bf(b.w);
    } else {
        o.v = make_uint4(0, 0, 0, 0);
    }
    *(uint4*)(dst + i) = o.v;
}

// ---------------------------------------------------------------------------
// rat_read: y[o,h] = sum_c res[h*4+c] * W[h,o,c]; LayerNorm over h per o;
// writes bf16. One block per token.
// ---------------------------------------------------------------------------
template <int NO>
__global__ __launch_bounds__(256) void rat_read_kernel(
    const float* __restrict__ res, const float* __restrict__ W,
    const float* __restrict__ gamma, const float* __restrict__ beta,
    ushort* __restrict__ out)
{
    const int t = blockIdx.x;
    const int tid = threadIdx.x;
    const float* rp = res + (size_t)t * 4096;
    float y[4][NO];
#pragma unroll
    for (int i = 0; i < 4; ++i) {
        const int h = tid + 256 * i;
        const float4 x = *(const float4*)(rp + h * 4);
#pragma unroll
        for (int o = 0; o < NO; ++o) {
            const float4 w = *(const float4*)(W + ((size_t)h * NO + o) * 4);
            y[i][o] = x.x * w.x + x.y * w.y + x.z * w.z + x.w * w.w;
        }
    }
    __shared__ float red[4][NO][2];
    const int lane = tid & 63, wid = tid >> 6;
#pragma unroll
    for (int o = 0; o < NO; ++o) {
        float s = 0.f, ss = 0.f;
#pragma unroll
        for (int i = 0; i < 4; ++i) { s += y[i][o]; ss += y[i][o] * y[i][o]; }
        for (int off = 32; off > 0; off >>= 1) {
            s += __shfl_down(s, off);
            ss += __shfl_down(ss, off);
        }
        if (lane == 0) { red[wid][o][0] = s; red[wid][o][1] = ss; }
    }
    __syncthreads();
    float mu[NO], rs[NO];
#pragma unroll
    for (int o = 0; o < NO; ++o) {
        const float s  = red[0][o][0] + red[1][o][0] + red[2][o][0] + red[3][o][0];
        const float ss = red[0][o][1] + red[1][o][1] + red[2][o][1] + red[3][o][1];
        const float m = s * (1.0f / 1024.0f);
        const float v = ss * (1.0f / 1024.0f) - m * m;
        mu[o] = m;
        rs[o] = rsqrtf(v + 1e-5f);
    }
    ushort* op = out + (size_t)t * (NO * 1024);
#pragma unroll
    for (int i = 0; i < 4; ++i) {
        const int h = tid + 256 * i;
#pragma unroll
        for (int o = 0; o < NO; ++o) {
            op[o * 1024 + h] = f2bf((y[i][o] - mu[o]) * rs[o] * gamma[o * 1024 + h] + beta[o * 1024 + h]);
        }
    }
}

// ---------------------------------------------------------------------------
// bf16 MFMA GEMM, 2-phase pipelined with global_load_lds.
// C[m,o] = sum_k A[m,k]*W[o,k]; A [M][lda] bf16, W [Opad][ldw] bf16.
// 128x128 tile, BK=64, 256 thr = 4 waves (2x2 of 64x64).
// LDS: double-buffered As/Bs [128][64] with XOR k-chunk swizzle applied on the
// GLOBAL source (linear LDS dest, required by global_load_lds) and on reads.
// grid.z = split-K (Kblk each); EPI: 0 f32 (+z-offset partials, col<O guard),
// 1 bf16, 2 silu(acc)*U -> bf16, 3 transposed bf16 store C[col*ldc+row].
// ---------------------------------------------------------------------------
__device__ __forceinline__ void stage_tile(
    ushort* AsB, ushort* BsB, const ushort* Ag, const ushort* Wg,
    size_t lda8, size_t ldw8, int w, int kofs)
{
#pragma unroll
    for (int i = 0; i < 4; ++i) {
        gload_lds16(Ag + kofs + i * lda8, AsB + (w * 4 + i) * 512);
        gload_lds16(Wg + kofs + i * ldw8, BsB + (w * 4 + i) * 512);
    }
}

template <int EPI>
__global__ __launch_bounds__(256) void mfma_gemm_kernel(
    const ushort* __restrict__ A, int lda,
    const ushort* __restrict__ W, int ldw,
    void* __restrict__ Cp, int ldc, int O,
    const ushort* __restrict__ U,
    int Kblk)
{
    __shared__ ushort As[2][128 * 64];
    __shared__ ushort Bs[2][128 * 64];
    const int tid = threadIdx.x;
    // bijective XCD swizzle over (bx,by); all grids have nwg%8==0
    const int nwg = gridDim.x * gridDim.y;
    const int id = blockIdx.y * gridDim.x + blockIdx.x;
    const int swz = (id & 7) * (nwg >> 3) + (id >> 3);
    const int bm = (swz % gridDim.x) * 128;
    const int bo = (swz / gridDim.x) * 128;

    const int w = tid >> 6, l = tid & 63;
    const int lq = l & 15, lg = l >> 4;
    const int wr = (w >> 1) * 64, wc = (w & 1) * 64;

    f32x4 acc[4][4];
#pragma unroll
    for (int i = 0; i < 4; ++i)
#pragma unroll
        for (int j = 0; j < 4; ++j) acc[i][j] = (f32x4){0.f, 0.f, 0.f, 0.f};

    // staging: wave w stages rows 32w..32w+31 of A and B tiles.
    // lane l -> row 32w + (l>>3) + 8i, source k-chunk ((l&7) ^ (l>>3)) (XOR
    // pre-swizzle; LDS dest is linear so LDS[r][jc] = global[r][jc ^ (r&7)]).
    const int srow = 32 * w + (l >> 3);
    const int skc  = ((l & 7) ^ (l >> 3)) * 8;
    const ushort* Ag = A + (size_t)(bm + srow) * lda + (size_t)blockIdx.z * Kblk + skc;
    const ushort* Wg = W + (size_t)(bo + srow) * ldw + (size_t)blockIdx.z * Kblk + skc;
    const size_t lda8 = (size_t)8 * lda, ldw8 = (size_t)8 * ldw;

    const int nt = Kblk >> 6;
    stage_tile(As[0], Bs[0], Ag, Wg, lda8, ldw8, w, 0);
    __syncthreads();   // drains vmcnt(0): tile 0 resident
    int cur = 0;
    for (int t = 0; t < nt; ++t) {
        if (t + 1 < nt)
            stage_tile(As[cur ^ 1], Bs[cur ^ 1], Ag, Wg, lda8, ldw8, w, (t + 1) * 64);
#pragma unroll
        for (int ks = 0; ks < 2; ++ks) {
            short8_t af[4], bf[4];
            const int jc = ks * 4 + lg;   // k-chunk 0..7
#pragma unroll
            for (int mf = 0; mf < 4; ++mf) {
                const int ra = wr + mf * 16 + lq;
                af[mf] = *(const short8_t*)&As[cur][ra * 64 + ((jc ^ (ra & 7)) * 8)];
                const int rb = wc + mf * 16 + lq;
                bf[mf] = *(const short8_t*)&Bs[cur][rb * 64 + ((jc ^ (rb & 7)) * 8)];
            }
#pragma unroll
            for (int mf = 0; mf < 4; ++mf)
#pragma unroll
                for (int nf = 0; nf < 4; ++nf)
                    acc[mf][nf] = __builtin_amdgcn_mfma_f32_16x16x32_bf16(
                        af[mf], bf[nf], acc[mf][nf], 0, 0, 0);
        }
        __syncthreads();   // all reads of buf done; next stage resident
        cur ^= 1;
    }

    if (EPI == 0) {
        // direct f32 stores (16 lanes x 4B = full 64B line per row-segment)
#pragma unroll
        for (int mf = 0; mf < 4; ++mf)
#pragma unroll
            for (int r = 0; r < 4; ++r) {
                const int row = bm + wr + mf * 16 + lg * 4 + r;
#pragma unroll
                for (int nf = 0; nf < 4; ++nf) {
                    const int col = bo + wc + nf * 16 + lq;
                    if (col < O)
                        ((float*)Cp)[(size_t)blockIdx.z * NTOK * ldc + (size_t)row * ldc + col] = acc[mf][nf][r];
                }
            }
    } else {
        // LDS-transpose epilogue: wave-local 8KB staging in dead As/Bs space
        ushort* eb = &As[0][0] + w * 4096;
#pragma unroll
        for (int mf = 0; mf < 4; ++mf)
#pragma unroll
            for (int r = 0; r < 4; ++r)
#pragma unroll
                for (int nf = 0; nf < 4; ++nf) {
                    const int rl = mf * 16 + lg * 4 + r;   // local row (m)
                    const int cl = nf * 16 + lq;           // local col (o)
                    if (EPI == 3) eb[cl * 64 + rl] = f2bf(acc[mf][nf][r]);
                    else          eb[rl * 64 + cl] = f2bf(acc[mf][nf][r]);
                }
        // wave-local: compiler inserts lgkmcnt wait before readback
#pragma unroll
        for (int p = 0; p < 8; ++p) {
            const int rl = p * 8 + (l >> 3);
            const int cl = (l & 7) * 8;
            uint4 v = *(const uint4*)&eb[rl * 64 + cl];
            if (EPI == 1) {
                *(uint4*)((ushort*)Cp + (size_t)(bm + wr + rl) * ldc + bo + wc + cl) = v;
            } else if (EPI == 2) {
                const ushort* up = U + (size_t)(bm + wr + rl) * ldc + bo + wc + cl;
                const uint4 uv = *(const uint4*)up;
                union { uint4 v; ushort u[8]; } g, uu, o;
                g.v = v; uu.v = uv;
#pragma unroll
                for (int e = 0; e < 8; ++e) {
                    const float gf = bf2f(g.u[e]);
                    o.u[e] = f2bf(gf / (1.0f + __expf(-gf)) * bf2f(uu.u[e]));
                }
                *(uint4*)((ushort*)Cp + (size_t)(bm + wr + rl) * ldc + bo + wc + cl) = o.v;
            } else {   // EPI == 3: transposed; eb holds [o_local][m_local]
                *(uint4*)((ushort*)Cp + (size_t)(bo + wc + rl) * ldc + bm + wr + cl) = v;
            }
        }
    }
}

// Sum split-K partials (nz x NTOK x 112) + bias -> C (NTOK x 112) f32.
__global__ __launch_bounds__(256) void splitk_reduce_kernel(
    const float* __restrict__ part, const float* __restrict__ bias,
    float* __restrict__ C, int nz)
{
    const int idx = blockIdx.x * 256 + threadIdx.x;
    const int col = idx % 112;
    float s = bias[col];
    for (int z = 0; z < nz; ++z) s += part[(size_t)z * NTOK * 112 + idx];
    C[idx] = s;
}

// ---------------------------------------------------------------------------
// RoPE: read q,k f32, write bf16 Qb (scaled by 1/8) and Kb. pos = token & 2047.
// ---------------------------------------------------------------------------
__global__ __launch_bounds__(256) void rope_bf16_kernel(
    const float* __restrict__ q, const float* __restrict__ k,
    ushort* __restrict__ Qb, ushort* __restrict__ Kb)
{
    const int idx = blockIdx.x * 256 + threadIdx.x;   // < NTOK*512
    const int i  = idx & 31;
    const int nh = (idx >> 5) & 15;
    const int t  = idx >> 9;
    const int pos = t & 2047;
    const float inv = expf(-(float)i * (9.210340371976184f / 32.0f));
    float s, c;
    sincosf((float)pos * inv, &s, &c);
    const size_t base = (size_t)t * 1024 + nh * 64 + i;
    const float q1 = q[base], q2 = q[base + 32];
    Qb[base]      = f2bf((q1 * c - q2 * s) * 0.125f);
    Qb[base + 32] = f2bf((q2 * c + q1 * s) * 0.125f);
    const float k1 = k[base], k2 = k[base + 32];
    Kb[base]      = f2bf(k1 * c - k2 * s);
    Kb[base + 32] = f2bf(k2 * c + k1 * s);
}

// ---------------------------------------------------------------------------
// MFMA flash attention, bf16. Block = 256 thr = 4 independent waves, each
// owning 16 q-rows; grid (32 q-tiles, 32 b*h). LDS-free.
// Swapped QK^T (mfma(K,Q)) -> lane-local softmax; P redistributed via shfl.
// Vt is [1024 d][4096 tok] bf16. Qb pre-scaled by 1/8.
// ---------------------------------------------------------------------------
__global__ __launch_bounds__(256) void attn_mfma_kernel(
    const ushort* __restrict__ Qb, const ushort* __restrict__ Kb,
    const ushort* __restrict__ Vt, ushort* __restrict__ atno)
{
    const int qb = blockIdx.x;
    const int bh = blockIdx.y;
    const int b = bh >> 4, h = bh & 15;
    const int w = threadIdx.x >> 6, l = threadIdx.x & 63;
    const int g = l >> 4, t = l & 15;
    const int tok0 = b * 2048;
    const int hoff = h * 64;
    const int qrow = tok0 + qb * 64 + w * 16 + t;

    short8_t qf[2];
#pragma unroll
    for (int ks = 0; ks < 2; ++ks)
        qf[ks] = *(const short8_t*)(Qb + (size_t)qrow * 1024 + hoff + ks * 32 + g * 8);

    float m_run = -3.0e38f, l_run = 0.0f;
    f32x4 oacc[4];
#pragma unroll
    for (int nf = 0; nf < 4; ++nf) oacc[nf] = (f32x4){0.f, 0.f, 0.f, 0.f};

    const int srcA = ((g & 1) * 2) * 16 + t;
    const int srcB = srcA + 16;
    const bool hiSel = (g >> 1) != 0;

    for (int kb = 0; kb <= qb; ++kb) {
        const size_t kbase = (size_t)(tok0 + kb * 64) * 1024 + hoff;
        f32x4 sa[4];
#pragma unroll
        for (int mf = 0; mf < 4; ++mf) sa[mf] = (f32x4){0.f, 0.f, 0.f, 0.f};
#pragma unroll
        for (int ks = 0; ks < 2; ++ks) {
#pragma unroll
            for (int mf = 0; mf < 4; ++mf) {
                const short8_t kf = *(const short8_t*)(Kb + kbase + (size_t)(mf * 16 + t) * 1024 + ks * 32 + g * 8);
                sa[mf] = __builtin_amdgcn_mfma_f32_16x16x32_bf16(kf, qf[ks], sa[mf], 0, 0, 0);
            }
        }
        float p[4][4];
        float mloc = -3.0e38f;
#pragma unroll
        for (int mf = 0; mf < 4; ++mf)
#pragma unroll
            for (int r = 0; r < 4; ++r) {
                float s = sa[mf][r];
                if (kb == qb && (mf * 16 + g * 4 + r) > (w * 16 + t)) s = -3.0e38f;
                p[mf][r] = s;
                mloc = fmaxf(mloc, s);
            }
        mloc = fmaxf(mloc, __shfl_xor(mloc, 16));
        mloc = fmaxf(mloc, __shfl_xor(mloc, 32));
        const float mnew = fmaxf(m_run, mloc);
        float lsum = 0.f;
#pragma unroll
        for (int mf = 0; mf < 4; ++mf)
#pragma unroll
            for (int r = 0; r < 4; ++r) {
                const float e = __expf(p[mf][r] - mnew);
                p[mf][r] = e;
                lsum += e;
            }
        lsum += __shfl_xor(lsum, 16);
        lsum += __shfl_xor(lsum, 32);
        const float fac = __expf(m_run - mnew);
        l_run = l_run * fac + lsum;
        m_run = mnew;
#pragma unroll
        for (int r = 0; r < 4; ++r) {
            const float fr = __shfl(fac, g * 4 + r);
#pragma unroll
            for (int nf = 0; nf < 4; ++nf) oacc[nf][r] *= fr;
        }
        uint32_t pk[4][2];
#pragma unroll
        for (int mf = 0; mf < 4; ++mf) {
            pk[mf][0] = pack2(p[mf][0], p[mf][1]);
            pk[mf][1] = pack2(p[mf][2], p[mf][3]);
        }
#pragma unroll
        for (int ks = 0; ks < 2; ++ks) {
            const uint32_t a00 = __shfl(pk[2 * ks][0], srcA);
            const uint32_t a01 = __shfl(pk[2 * ks][1], srcA);
            const uint32_t a10 = __shfl(pk[2 * ks + 1][0], srcA);
            const uint32_t a11 = __shfl(pk[2 * ks + 1][1], srcA);
            const uint32_t b00 = __shfl(pk[2 * ks][0], srcB);
            const uint32_t b01 = __shfl(pk[2 * ks][1], srcB);
            const uint32_t b10 = __shfl(pk[2 * ks + 1][0], srcB);
            const uint32_t b11 = __shfl(pk[2 * ks + 1][1], srcB);
            union { uint32_t u[4]; short8_t v; } pa;
            pa.u[0] = hiSel ? a10 : a00;
            pa.u[1] = hiSel ? a11 : a01;
            pa.u[2] = hiSel ? b10 : b00;
            pa.u[3] = hiSel ? b11 : b01;
#pragma unroll
            for (int nf = 0; nf < 4; ++nf) {
                const short8_t vf = *(const short8_t*)(
                    Vt + (size_t)(hoff + nf * 16 + t) * NTOK + tok0 + kb * 64 + ks * 32 + g * 8);
                oacc[nf] = __builtin_amdgcn_mfma_f32_16x16x32_bf16(pa.v, vf, oacc[nf], 0, 0, 0);
            }
        }
    }
    const float inv = 1.0f / l_run;
#pragma unroll
    for (int r = 0; r < 4; ++r) {
        const float ir = __shfl(inv, g * 4 + r);
        const int orow = tok0 + qb * 64 + w * 16 + g * 4 + r;
#pragma unroll
        for (int nf = 0; nf < 4; ++nf)
            atno[(size_t)orow * 1024 + hoff + nf * 16 + t] = f2bf(oacc[nf][r] * ir);
    }
}

// ---------------------------------------------------------------------------
// rat_write: fused du-projection (K=8) + softplus + SSM update. f32.
// ---------------------------------------------------------------------------
__global__ __launch_bounds__(256) void rat_write_kernel(
    const float* res, const float* __restrict__ od,
    const float* __restrict__ AB, const float* __restrict__ du_w,
    const float* __restrict__ du_b, float* out)
{
    const int t = blockIdx.x;
    const int tid = threadIdx.x;
    __shared__ float sAB[112];
    __shared__ float sdl[8];
    if (tid < 112) sAB[tid] = AB[(size_t)t * 112 + tid];
    if (tid >= 128 && tid < 136) sdl[tid - 128] = od[(size_t)t * 1032 + 1024 + (tid - 128)];
    __syncthreads();
    const float* rp = res + (size_t)t * 4096;
    const float* odp = od + (size_t)t * 1032;
    float* op = out + (size_t)t * 4096;
#pragma unroll
    for (int ii = 0; ii < 4; ++ii) {
        const int hh = tid + 256 * ii;
        const int rh = hh & 15;
        const float4 w0 = *(const float4*)(du_w + hh * 8);
        const float4 w1 = *(const float4*)(du_w + hh * 8 + 4);
        float dacc = du_b[hh];
        dacc += sdl[0] * w0.x + sdl[1] * w0.y + sdl[2] * w0.z + sdl[3] * w0.w;
        dacc += sdl[4] * w1.x + sdl[5] * w1.y + sdl[6] * w1.z + sdl[7] * w1.w;
        const float delta = softplus_f(dacc);
        const float oh = odp[hh];
        const float4 hs = *(const float4*)(rp + hh * 4);
        const float r4[4] = {hs.x, hs.y, hs.z, hs.w};
        float o4[4];
#pragma unroll
        for (int c = 0; c < 3; ++c) {
            const float Aneg = -softplus_f(sAB[rh * 3 + c]);
            const float Abar = expf(delta * Aneg);
            const float Bbar = (Abar - 1.0f) / (Aneg - 1e-5f) * sAB[48 + rh * 3 + c];
            o4[c] = r4[c] * Abar + oh * Bbar;
        }
        o4[3] = r4[3] + oh * (delta * sAB[96 + rh]);
        *(float4*)(op + hh * 4) = make_float4(o4[0], o4[1], o4[2], o4[3]);
    }
}

// ---------------------------------------------------------------------------
extern "C" void kernel_launch(void* const* d_in, const int* in_sizes, int n_in,
                              void* d_out, int out_size, void* d_ws, size_t ws_size,
                              hipStream_t stream)
{
    const float* hidden      = (const float*)d_in[0];
    const float* attn_read_w = (const float*)d_in[2];
    const float* attn_read_g = (const float*)d_in[3];
    const float* attn_read_b = (const float*)d_in[4];
    const float* qkv_w       = (const float*)d_in[5];
    const float* attn_wod_w  = (const float*)d_in[6];
    const float* attn_wab_w  = (const float*)d_in[7];
    const float* attn_wab_b  = (const float*)d_in[8];
    const float* attn_du_w   = (const float*)d_in[9];
    const float* attn_du_b   = (const float*)d_in[10];
    const float* mlp_read_w  = (const float*)d_in[11];
    const float* mlp_read_g  = (const float*)d_in[12];
    const float* mlp_read_b  = (const float*)d_in[13];
    const float* mlp_in_w    = (const float*)d_in[14];
    const float* mlp_wod_w   = (const float*)d_in[15];
    const float* mlp_wab_w   = (const float*)d_in[16];
    const float* mlp_wab_b   = (const float*)d_in[17];
    const float* mlp_du_w    = (const float*)d_in[18];
    const float* mlp_du_b    = (const float*)d_in[19];
    float* out = (float*)d_out;
    char* wsb = (char*)d_ws;
    const size_t N = NTOK;

    // ---- workspace layout (bytes) ----
    ushort* qkv_wb  = (ushort*)(wsb + 0);          // 3*1024*1024
    ushort* wodA_b  = (ushort*)(wsb + 6291456);    // 1152*1024
    ushort* wabA_b  = (ushort*)(wsb + 8650752);    // 128*1024
    ushort* mlpin_b = (ushort*)(wsb + 8912896);    // 2*4096*1024
    ushort* wodM_b  = (ushort*)(wsb + 25690112);   // 1152*4096
    ushort* wabM_b  = (ushort*)(wsb + 35127296);   // 128*4096
    char* R1 = wsb + 36175872;                     // 25.2 MB region
    char* R2 = wsb + 61341696;                     // 67.1 MB region
    ushort* qkv_in = (ushort*)R1;                  // [N*3072] bf16
    ushort* Qb     = (ushort*)R1;                  // [N*1024] bf16 (after qkv GEMMs)
    ushort* Kb     = (ushort*)(R1 + 8388608);
    ushort* Vt     = (ushort*)(R1 + 16777216);     // [1024][N] bf16
    ushort* mlp_in = (ushort*)R1;                  // [N*2048] bf16 (phase M)
    float*  od_m   = (float*)R1;                   // [N*1032] (after mlp_in dead)
    float*  ab_m   = (float*)(R1 + 16908288);      // [N*112]
    float*  q_     = (float*)R2;                   // [N*1024] f32
    float*  k_     = (float*)(R2 + 16777216);
    ushort* atno   = (ushort*)R2;                  // [N*1024] bf16 (after rope)
    float*  od_a   = (float*)(R2 + 8388608);       // [N*1032]
    float*  ab_a   = (float*)(R2 + 25296896);      // [N*112]
    float*  skpA   = (float*)(R2 + 27131904);      // [8*N*112]
    ushort* up_    = (ushort*)R2;                  // [N*4096] bf16 (phase M)
    ushort* upb    = (ushort*)(R2 + 33554432);     // [N*4096] bf16
    float*  skpM   = (float*)R2;                   // [8*N*112] (after up_ dead)

    // ---- weight conversion (bf16, zero-padded output rows) ----
    convert_flat_kernel<<<1536, 256, 0, stream>>>(qkv_w, qkv_wb);
    convert_flat_kernel<<<4096, 256, 0, stream>>>(mlp_in_w, mlpin_b);
    convert_pad_kernel<<<576, 256, 0, stream>>>(attn_wod_w, wodA_b, 1032, 1024);
    convert_pad_kernel<<<64, 256, 0, stream>>>(attn_wab_w, wabA_b, 112, 1024);
    convert_pad_kernel<<<2304, 256, 0, stream>>>(mlp_wod_w, wodM_b, 1032, 4096);
    convert_pad_kernel<<<256, 256, 0, stream>>>(mlp_wab_w, wabM_b, 112, 4096);

    // ---- attention half ----
    rat_read_kernel<3><<<N, 256, 0, stream>>>(hidden, attn_read_w, attn_read_g, attn_read_b, qkv_in);

    mfma_gemm_kernel<0><<<dim3(32, 8), 256, 0, stream>>>(qkv_in, 3072, qkv_wb, 1024, q_, 1024, 1024, nullptr, 1024);
    mfma_gemm_kernel<0><<<dim3(32, 8), 256, 0, stream>>>(qkv_in + 1024, 3072, qkv_wb + 1048576, 1024, k_, 1024, 1024, nullptr, 1024);
    mfma_gemm_kernel<3><<<dim3(32, 8), 256, 0, stream>>>(qkv_in + 2048, 3072, qkv_wb + 2097152, 1024, Vt, NTOK, 1024, nullptr, 1024);

    rope_bf16_kernel<<<8192, 256, 0, stream>>>(q_, k_, Qb, Kb);

    attn_mfma_kernel<<<dim3(32, 32), 256, 0, stream>>>(Qb, Kb, Vt, atno);

    mfma_gemm_kernel<0><<<dim3(32, 9), 256, 0, stream>>>(atno, 1024, wodA_b, 1024, od_a, 1032, 1032, nullptr, 1024);
    mfma_gemm_kernel<0><<<dim3(32, 1, 8), 256, 0, stream>>>(atno, 1024, wabA_b, 1024, skpA, 112, 112, nullptr, 128);
    splitk_reduce_kernel<<<1792, 256, 0, stream>>>(skpA, attn_wab_b, ab_a, 8);

    rat_write_kernel<<<N, 256, 0, stream>>>(hidden, od_a, ab_a, attn_du_w, attn_du_b, out);

    // ---- MLP half ----
    rat_read_kernel<2><<<N, 256, 0, stream>>>(out, mlp_read_w, mlp_read_g, mlp_read_b, mlp_in);

    mfma_gemm_kernel<1><<<dim3(32, 32), 256, 0, stream>>>(mlp_in + 1024, 2048, mlpin_b + 4194304, 1024, up_, 4096, 4096, nullptr, 1024);
    mfma_gemm_kernel<2><<<dim3(32, 32), 256, 0, stream>>>(mlp_in, 2048, mlpin_b, 1024, upb, 4096, 4096, up_, 1024);

    mfma_gemm_kernel<0><<<dim3(32, 9), 256, 0, stream>>>(upb, 4096, wodM_b, 4096, od_m, 1032, 1032, nullptr, 4096);
    mfma_gemm_kernel<0><<<dim3(32, 1, 8), 256, 0, stream>>>(upb, 4096, wabM_b, 4096, skpM, 112, 112, nullptr, 512);
    splitk_reduce_kernel<<<1792, 256, 0, stream>>>(skpM, mlp_wab_b, ab_m, 8);

    rat_write_kernel<<<N, 256, 0, stream>>>(out, od_m, ab_m, mlp_du_w, mlp_du_b, out);
}

// Round 4
// 605.032 us; speedup vs baseline: 5.9343x; 1.2472x over previous
//
#include <hip/hip_runtime.h>
#include <math.h>
#include <stdint.h>

// ---------------------------------------------------------------------------
// RatLayer forward, bf16-MFMA + global_load_lds 2-phase pipelined GEMM +
// LDS-staged double-buffered flash attention.
// H=1024 C=4 RH=16 HS=64 DR=8 M=4096 NH=16 HD=64 A_SIZE=48 B_SIZE=64
// B=2 L=2048 -> NTOK=4096 tokens.
// ---------------------------------------------------------------------------

constexpr int NTOK = 4096;

typedef __attribute__((ext_vector_type(8))) short short8_t;
typedef __attribute__((ext_vector_type(4))) float f32x4;

__device__ __forceinline__ ushort f2bf(float f) {
    union { float f; uint32_t u; } v; v.f = f;
    uint32_t r = v.u + 0x7fffu + ((v.u >> 16) & 1u);
    return (ushort)(r >> 16);
}
__device__ __forceinline__ float bf2f(ushort b) {
    union { uint32_t u; float f; } v; v.u = ((uint32_t)b) << 16;
    return v.f;
}
__device__ __forceinline__ uint32_t pack2(float lo, float hi) {
    return (uint32_t)f2bf(lo) | ((uint32_t)f2bf(hi) << 16);
}
__device__ __forceinline__ float softplus_f(float x) {
    return (x > 20.0f) ? x : log1pf(expf(x));
}

// async global->LDS, 16B per lane; LDS dest is wave-uniform base + lane*16.
__device__ __forceinline__ void gload_lds16(const void* g, void* l) {
    __builtin_amdgcn_global_load_lds(
        (const __attribute__((address_space(1))) uint32_t*)g,
        (__attribute__((address_space(3))) uint32_t*)l,
        16, 0, 0);
}

// ---------------------------------------------------------------------------
// Weight conversion f32 -> bf16 (flat, and row-padded variants).
// ---------------------------------------------------------------------------
__global__ __launch_bounds__(256) void convert_flat_kernel(
    const float* __restrict__ src, ushort* __restrict__ dst)
{
    const size_t i = ((size_t)blockIdx.x * 256 + threadIdx.x) * 8;
    const float4 a = *(const float4*)(src + i);
    const float4 b = *(const float4*)(src + i + 4);
    union { ushort u[8]; uint4 v; } o;
    o.u[0] = f2bf(a.x); o.u[1] = f2bf(a.y); o.u[2] = f2bf(a.z); o.u[3] = f2bf(a.w);
    o.u[4] = f2bf(b.x); o.u[5] = f2bf(b.y); o.u[6] = f2bf(b.z); o.u[7] = f2bf(b.w);
    *(uint4*)(dst + i) = o.v;
}

__global__ __launch_bounds__(256) void convert_pad_kernel(
    const float* __restrict__ src, ushort* __restrict__ dst, int O, int K)
{
    const size_t i = ((size_t)blockIdx.x * 256 + threadIdx.x) * 8;
    const int row = (int)(i / (size_t)K);
    union { ushort u[8]; uint4 v; } o;
    if (row < O) {
        const float4 a = *(const float4*)(src + i);
        const float4 b = *(const float4*)(src + i + 4);
        o.u[0] = f2bf(a.x); o.u[1] = f2bf(a.y); o.u[2] = f2bf(a.z); o.u[3] = f2bf(a.w);
        o.u[4] = f2bf(b.x); o.u[5] = f2bf(b.y); o.u[6] = f2bf(b.z); o.u[7] = f2bf(b.w);
    } else {
        o.v = make_uint4(0, 0, 0, 0);
    }
    *(uint4*)(dst + i) = o.v;
}

// ---------------------------------------------------------------------------
// rat_read: y[o,h] = sum_c res[h*4+c] * W[h,o,c]; LayerNorm over h per o;
// writes bf16. One block per token.
// ---------------------------------------------------------------------------
template <int NO>
__global__ __launch_bounds__(256) void rat_read_kernel(
    const float* __restrict__ res, const float* __restrict__ W,
    const float* __restrict__ gamma, const float* __restrict__ beta,
    ushort* __restrict__ out)
{
    const int t = blockIdx.x;
    const int tid = threadIdx.x;
    const float* rp = res + (size_t)t * 4096;
    float y[4][NO];
#pragma unroll
    for (int i = 0; i < 4; ++i) {
        const int h = tid + 256 * i;
        const float4 x = *(const float4*)(rp + h * 4);
#pragma unroll
        for (int o = 0; o < NO; ++o) {
            const float4 w = *(const float4*)(W + ((size_t)h * NO + o) * 4);
            y[i][o] = x.x * w.x + x.y * w.y + x.z * w.z + x.w * w.w;
        }
    }
    __shared__ float red[4][NO][2];
    const int lane = tid & 63, wid = tid >> 6;
#pragma unroll
    for (int o = 0; o < NO; ++o) {
        float s = 0.f, ss = 0.f;
#pragma unroll
        for (int i = 0; i < 4; ++i) { s += y[i][o]; ss += y[i][o] * y[i][o]; }
        for (int off = 32; off > 0; off >>= 1) {
            s += __shfl_down(s, off);
            ss += __shfl_down(ss, off);
        }
        if (lane == 0) { red[wid][o][0] = s; red[wid][o][1] = ss; }
    }
    __syncthreads();
    float mu[NO], rs[NO];
#pragma unroll
    for (int o = 0; o < NO; ++o) {
        const float s  = red[0][o][0] + red[1][o][0] + red[2][o][0] + red[3][o][0];
        const float ss = red[0][o][1] + red[1][o][1] + red[2][o][1] + red[3][o][1];
        const float m = s * (1.0f / 1024.0f);
        const float v = ss * (1.0f / 1024.0f) - m * m;
        mu[o] = m;
        rs[o] = rsqrtf(v + 1e-5f);
    }
    ushort* op = out + (size_t)t * (NO * 1024);
#pragma unroll
    for (int i = 0; i < 4; ++i) {
        const int h = tid + 256 * i;
#pragma unroll
        for (int o = 0; o < NO; ++o) {
            op[o * 1024 + h] = f2bf((y[i][o] - mu[o]) * rs[o] * gamma[o * 1024 + h] + beta[o * 1024 + h]);
        }
    }
}

// ---------------------------------------------------------------------------
// bf16 MFMA GEMM, 2-phase pipelined with global_load_lds.
// C[m,o] = sum_k A[m,k]*W[o,k]; A [M][lda] bf16, W [Opad][ldw] bf16.
// 128x128 tile, BK=64, 256 thr = 4 waves (2x2 of 64x64).
// ---------------------------------------------------------------------------
__device__ __forceinline__ void stage_tile(
    ushort* AsB, ushort* BsB, const ushort* Ag, const ushort* Wg,
    size_t lda8, size_t ldw8, int w, int kofs)
{
#pragma unroll
    for (int i = 0; i < 4; ++i) {
        gload_lds16(Ag + kofs + i * lda8, AsB + (w * 4 + i) * 512);
        gload_lds16(Wg + kofs + i * ldw8, BsB + (w * 4 + i) * 512);
    }
}

template <int EPI>
__global__ __launch_bounds__(256) void mfma_gemm_kernel(
    const ushort* __restrict__ A, int lda,
    const ushort* __restrict__ W, int ldw,
    void* __restrict__ Cp, int ldc, int O,
    const ushort* __restrict__ U,
    int Kblk)
{
    __shared__ ushort As[2][128 * 64];
    __shared__ ushort Bs[2][128 * 64];
    const int tid = threadIdx.x;
    const int nwg = gridDim.x * gridDim.y;
    const int id = blockIdx.y * gridDim.x + blockIdx.x;
    const int swz = (id & 7) * (nwg >> 3) + (id >> 3);
    const int bm = (swz % gridDim.x) * 128;
    const int bo = (swz / gridDim.x) * 128;

    const int w = tid >> 6, l = tid & 63;
    const int lq = l & 15, lg = l >> 4;
    const int wr = (w >> 1) * 64, wc = (w & 1) * 64;

    f32x4 acc[4][4];
#pragma unroll
    for (int i = 0; i < 4; ++i)
#pragma unroll
        for (int j = 0; j < 4; ++j) acc[i][j] = (f32x4){0.f, 0.f, 0.f, 0.f};

    const int srow = 32 * w + (l >> 3);
    const int skc  = ((l & 7) ^ (l >> 3)) * 8;
    const ushort* Ag = A + (size_t)(bm + srow) * lda + (size_t)blockIdx.z * Kblk + skc;
    const ushort* Wg = W + (size_t)(bo + srow) * ldw + (size_t)blockIdx.z * Kblk + skc;
    const size_t lda8 = (size_t)8 * lda, ldw8 = (size_t)8 * ldw;

    const int nt = Kblk >> 6;
    stage_tile(As[0], Bs[0], Ag, Wg, lda8, ldw8, w, 0);
    __syncthreads();
    int cur = 0;
    for (int t = 0; t < nt; ++t) {
        if (t + 1 < nt)
            stage_tile(As[cur ^ 1], Bs[cur ^ 1], Ag, Wg, lda8, ldw8, w, (t + 1) * 64);
#pragma unroll
        for (int ks = 0; ks < 2; ++ks) {
            short8_t af[4], bf[4];
            const int jc = ks * 4 + lg;
#pragma unroll
            for (int mf = 0; mf < 4; ++mf) {
                const int ra = wr + mf * 16 + lq;
                af[mf] = *(const short8_t*)&As[cur][ra * 64 + ((jc ^ (ra & 7)) * 8)];
                const int rb = wc + mf * 16 + lq;
                bf[mf] = *(const short8_t*)&Bs[cur][rb * 64 + ((jc ^ (rb & 7)) * 8)];
            }
#pragma unroll
            for (int mf = 0; mf < 4; ++mf)
#pragma unroll
                for (int nf = 0; nf < 4; ++nf)
                    acc[mf][nf] = __builtin_amdgcn_mfma_f32_16x16x32_bf16(
                        af[mf], bf[nf], acc[mf][nf], 0, 0, 0);
        }
        __syncthreads();
        cur ^= 1;
    }

    if (EPI == 0) {
#pragma unroll
        for (int mf = 0; mf < 4; ++mf)
#pragma unroll
            for (int r = 0; r < 4; ++r) {
                const int row = bm + wr + mf * 16 + lg * 4 + r;
#pragma unroll
                for (int nf = 0; nf < 4; ++nf) {
                    const int col = bo + wc + nf * 16 + lq;
                    if (col < O)
                        ((float*)Cp)[(size_t)blockIdx.z * NTOK * ldc + (size_t)row * ldc + col] = acc[mf][nf][r];
                }
            }
    } else {
        ushort* eb = &As[0][0] + w * 4096;
#pragma unroll
        for (int mf = 0; mf < 4; ++mf)
#pragma unroll
            for (int r = 0; r < 4; ++r)
#pragma unroll
                for (int nf = 0; nf < 4; ++nf) {
                    const int rl = mf * 16 + lg * 4 + r;
                    const int cl = nf * 16 + lq;
                    if (EPI == 3) eb[cl * 64 + rl] = f2bf(acc[mf][nf][r]);
                    else          eb[rl * 64 + cl] = f2bf(acc[mf][nf][r]);
                }
#pragma unroll
        for (int p = 0; p < 8; ++p) {
            const int rl = p * 8 + (l >> 3);
            const int cl = (l & 7) * 8;
            uint4 v = *(const uint4*)&eb[rl * 64 + cl];
            if (EPI == 1) {
                *(uint4*)((ushort*)Cp + (size_t)(bm + wr + rl) * ldc + bo + wc + cl) = v;
            } else if (EPI == 2) {
                const ushort* up = U + (size_t)(bm + wr + rl) * ldc + bo + wc + cl;
                const uint4 uv = *(const uint4*)up;
                union { uint4 v; ushort u[8]; } g, uu, o;
                g.v = v; uu.v = uv;
#pragma unroll
                for (int e = 0; e < 8; ++e) {
                    const float gf = bf2f(g.u[e]);
                    o.u[e] = f2bf(gf / (1.0f + __expf(-gf)) * bf2f(uu.u[e]));
                }
                *(uint4*)((ushort*)Cp + (size_t)(bm + wr + rl) * ldc + bo + wc + cl) = o.v;
            } else {
                *(uint4*)((ushort*)Cp + (size_t)(bo + wc + rl) * ldc + bm + wr + cl) = v;
            }
        }
    }
}

// Sum split-K partials (nz x NTOK x 112) + bias -> C (NTOK x 112) f32.
__global__ __launch_bounds__(256) void splitk_reduce_kernel(
    const float* __restrict__ part, const float* __restrict__ bias,
    float* __restrict__ C, int nz)
{
    const int idx = blockIdx.x * 256 + threadIdx.x;
    const int col = idx % 112;
    float s = bias[col];
    for (int z = 0; z < nz; ++z) s += part[(size_t)z * NTOK * 112 + idx];
    C[idx] = s;
}

// ---------------------------------------------------------------------------
// RoPE: read q,k f32, write bf16 Qb (scaled by 1/8) and Kb. pos = token & 2047.
// ---------------------------------------------------------------------------
__global__ __launch_bounds__(256) void rope_bf16_kernel(
    const float* __restrict__ q, const float* __restrict__ k,
    ushort* __restrict__ Qb, ushort* __restrict__ Kb)
{
    const int idx = blockIdx.x * 256 + threadIdx.x;   // < NTOK*512
    const int i  = idx & 31;
    const int nh = (idx >> 5) & 15;
    const int t  = idx >> 9;
    const int pos = t & 2047;
    const float inv = expf(-(float)i * (9.210340371976184f / 32.0f));
    float s, c;
    sincosf((float)pos * inv, &s, &c);
    const size_t base = (size_t)t * 1024 + nh * 64 + i;
    const float q1 = q[base], q2 = q[base + 32];
    Qb[base]      = f2bf((q1 * c - q2 * s) * 0.125f);
    Qb[base + 32] = f2bf((q2 * c + q1 * s) * 0.125f);
    const float k1 = k[base], k2 = k[base + 32];
    Kb[base]      = f2bf(k1 * c - k2 * s);
    Kb[base + 32] = f2bf(k2 * c + k1 * s);
}

// ---------------------------------------------------------------------------
// MFMA flash attention, bf16, LDS-staged K/V with double-buffered prefetch.
// Block = 256 thr = 4 waves, each owning 16 q-rows; grid (32 q-tiles, 32 b*h),
// qb remapped descending for load balance.
// K tile and V tile ([64 rows][64 cols] bf16, 8KB each) staged via
// global_load_lds with source-side XOR 16B-chunk swizzle (linear LDS dest);
// fragment ds_read_b128 applies the same XOR -> 2-way (free) bank access.
// Swapped QK^T (mfma(K,Q)) -> lane-local softmax; P redistributed via shfl.
// Vt is [1024 d][4096 tok] bf16. Qb pre-scaled by 1/8.
// ---------------------------------------------------------------------------
__global__ __launch_bounds__(256) void attn_mfma_kernel(
    const ushort* __restrict__ Qb, const ushort* __restrict__ Kb,
    const ushort* __restrict__ Vt, ushort* __restrict__ atno)
{
    __shared__ ushort Ks[2][64 * 64];
    __shared__ ushort Vs[2][64 * 64];
    const int qb = gridDim.x - 1 - blockIdx.x;   // biggest blocks dispatch first
    const int bh = blockIdx.y;
    const int b = bh >> 4, h = bh & 15;
    const int w = threadIdx.x >> 6, l = threadIdx.x & 63;
    const int g = l >> 4, t = l & 15;
    const int tok0 = b * 2048;
    const int hoff = h * 64;
    const int qrow = tok0 + qb * 64 + w * 16 + t;

    short8_t qf[2];
#pragma unroll
    for (int ks = 0; ks < 2; ++ks)
        qf[ks] = *(const short8_t*)(Qb + (size_t)qrow * 1024 + hoff + ks * 32 + g * 8);

    // staging: wave w stages rows w*16..w*16+15 of both tiles (2 instrs each).
    // lane l -> row w*16 + i*8 + (l>>3), dest chunk l&7, source chunk
    // (l&7)^(l>>3)  (XOR pre-swizzle; row&7 == l>>3 here).
    const int srow = w * 16 + (l >> 3);
    const int schunk = (l & 7) ^ (l >> 3);
    const ushort* Kg = Kb + (size_t)(tok0 + srow) * 1024 + hoff + schunk * 8;
    const ushort* Vg = Vt + (size_t)(hoff + srow) * NTOK + tok0 + schunk * 8;
    const int ldsbase = w * 1024;   // ushort offset of this wave's 16 rows

    float m_run = -3.0e38f, l_run = 0.0f;
    f32x4 oacc[4];
#pragma unroll
    for (int nf = 0; nf < 4; ++nf) oacc[nf] = (f32x4){0.f, 0.f, 0.f, 0.f};

    const int srcA = ((g & 1) * 2) * 16 + t;
    const int srcB = srcA + 16;
    const bool hiSel = (g >> 1) != 0;

    // prologue: stage kb=0
#pragma unroll
    for (int i = 0; i < 2; ++i) {
        gload_lds16(Kg + (size_t)(i * 8) * 1024, &Ks[0][ldsbase + i * 512]);
        gload_lds16(Vg + (size_t)(i * 8) * NTOK, &Vs[0][ldsbase + i * 512]);
    }
    __syncthreads();

    int buf = 0;
    for (int kb = 0; kb <= qb; ++kb) {
        if (kb < qb) {
            const int nk = (kb + 1) * 64;
#pragma unroll
            for (int i = 0; i < 2; ++i) {
                gload_lds16(Kg + (size_t)(nk + i * 8) * 1024, &Ks[buf ^ 1][ldsbase + i * 512]);
                gload_lds16(Vg + nk + (size_t)(i * 8) * NTOK, &Vs[buf ^ 1][ldsbase + i * 512]);
            }
        }
        // QK^T from LDS K tile
        f32x4 sa[4];
#pragma unroll
        for (int mf = 0; mf < 4; ++mf) sa[mf] = (f32x4){0.f, 0.f, 0.f, 0.f};
#pragma unroll
        for (int ks = 0; ks < 2; ++ks) {
            const int jc = ks * 4 + g;
#pragma unroll
            for (int mf = 0; mf < 4; ++mf) {
                const short8_t kf = *(const short8_t*)&Ks[buf][(mf * 16 + t) * 64 + ((jc ^ (t & 7)) * 8)];
                sa[mf] = __builtin_amdgcn_mfma_f32_16x16x32_bf16(kf, qf[ks], sa[mf], 0, 0, 0);
            }
        }
        float p[4][4];
        float mloc = -3.0e38f;
#pragma unroll
        for (int mf = 0; mf < 4; ++mf)
#pragma unroll
            for (int r = 0; r < 4; ++r) {
                float s = sa[mf][r];
                if (kb == qb && (mf * 16 + g * 4 + r) > (w * 16 + t)) s = -3.0e38f;
                p[mf][r] = s;
                mloc = fmaxf(mloc, s);
            }
        mloc = fmaxf(mloc, __shfl_xor(mloc, 16));
        mloc = fmaxf(mloc, __shfl_xor(mloc, 32));
        const float mnew = fmaxf(m_run, mloc);
        float lsum = 0.f;
#pragma unroll
        for (int mf = 0; mf < 4; ++mf)
#pragma unroll
            for (int r = 0; r < 4; ++r) {
                const float e = __expf(p[mf][r] - mnew);
                p[mf][r] = e;
                lsum += e;
            }
        lsum += __shfl_xor(lsum, 16);
        lsum += __shfl_xor(lsum, 32);
        const float fac = __expf(m_run - mnew);
        l_run = l_run * fac + lsum;
        m_run = mnew;
#pragma unroll
        for (int r = 0; r < 4; ++r) {
            const float fr = __shfl(fac, g * 4 + r);
#pragma unroll
            for (int nf = 0; nf < 4; ++nf) oacc[nf][r] *= fr;
        }
        uint32_t pk[4][2];
#pragma unroll
        for (int mf = 0; mf < 4; ++mf) {
            pk[mf][0] = pack2(p[mf][0], p[mf][1]);
            pk[mf][1] = pack2(p[mf][2], p[mf][3]);
        }
        // PV from LDS V tile
#pragma unroll
        for (int ks = 0; ks < 2; ++ks) {
            const uint32_t a00 = __shfl(pk[2 * ks][0], srcA);
            const uint32_t a01 = __shfl(pk[2 * ks][1], srcA);
            const uint32_t a10 = __shfl(pk[2 * ks + 1][0], srcA);
            const uint32_t a11 = __shfl(pk[2 * ks + 1][1], srcA);
            const uint32_t b00 = __shfl(pk[2 * ks][0], srcB);
            const uint32_t b01 = __shfl(pk[2 * ks][1], srcB);
            const uint32_t b10 = __shfl(pk[2 * ks + 1][0], srcB);
            const uint32_t b11 = __shfl(pk[2 * ks + 1][1], srcB);
            union { uint32_t u[4]; short8_t v; } pa;
            pa.u[0] = hiSel ? a10 : a00;
            pa.u[1] = hiSel ? a11 : a01;
            pa.u[2] = hiSel ? b10 : b00;
            pa.u[3] = hiSel ? b11 : b01;
            const int jc = ks * 4 + g;
#pragma unroll
            for (int nf = 0; nf < 4; ++nf) {
                const short8_t vf = *(const short8_t*)&Vs[buf][(nf * 16 + t) * 64 + ((jc ^ (t & 7)) * 8)];
                oacc[nf] = __builtin_amdgcn_mfma_f32_16x16x32_bf16(pa.v, vf, oacc[nf], 0, 0, 0);
            }
        }
        __syncthreads();   // prefetch resident + all reads of buf done
        buf ^= 1;
    }
    const float inv = 1.0f / l_run;
#pragma unroll
    for (int r = 0; r < 4; ++r) {
        const float ir = __shfl(inv, g * 4 + r);
        const int orow = tok0 + qb * 64 + w * 16 + g * 4 + r;
#pragma unroll
        for (int nf = 0; nf < 4; ++nf)
            atno[(size_t)orow * 1024 + hoff + nf * 16 + t] = f2bf(oacc[nf][r] * ir);
    }
}

// ---------------------------------------------------------------------------
// rat_write: fused du-projection (K=8) + softplus + SSM update. f32.
// ---------------------------------------------------------------------------
__global__ __launch_bounds__(256) void rat_write_kernel(
    const float* res, const float* __restrict__ od,
    const float* __restrict__ AB, const float* __restrict__ du_w,
    const float* __restrict__ du_b, float* out)
{
    const int t = blockIdx.x;
    const int tid = threadIdx.x;
    __shared__ float sAB[112];
    __shared__ float sdl[8];
    if (tid < 112) sAB[tid] = AB[(size_t)t * 112 + tid];
    if (tid >= 128 && tid < 136) sdl[tid - 128] = od[(size_t)t * 1032 + 1024 + (tid - 128)];
    __syncthreads();
    const float* rp = res + (size_t)t * 4096;
    const float* odp = od + (size_t)t * 1032;
    float* op = out + (size_t)t * 4096;
#pragma unroll
    for (int ii = 0; ii < 4; ++ii) {
        const int hh = tid + 256 * ii;
        const int rh = hh & 15;
        const float4 w0 = *(const float4*)(du_w + hh * 8);
        const float4 w1 = *(const float4*)(du_w + hh * 8 + 4);
        float dacc = du_b[hh];
        dacc += sdl[0] * w0.x + sdl[1] * w0.y + sdl[2] * w0.z + sdl[3] * w0.w;
        dacc += sdl[4] * w1.x + sdl[5] * w1.y + sdl[6] * w1.z + sdl[7] * w1.w;
        const float delta = softplus_f(dacc);
        const float oh = odp[hh];
        const float4 hs = *(const float4*)(rp + hh * 4);
        const float r4[4] = {hs.x, hs.y, hs.z, hs.w};
        float o4[4];
#pragma unroll
        for (int c = 0; c < 3; ++c) {
            const float Aneg = -softplus_f(sAB[rh * 3 + c]);
            const float Abar = expf(delta * Aneg);
            const float Bbar = (Abar - 1.0f) / (Aneg - 1e-5f) * sAB[48 + rh * 3 + c];
            o4[c] = r4[c] * Abar + oh * Bbar;
        }
        o4[3] = r4[3] + oh * (delta * sAB[96 + rh]);
        *(float4*)(op + hh * 4) = make_float4(o4[0], o4[1], o4[2], o4[3]);
    }
}

// ---------------------------------------------------------------------------
extern "C" void kernel_launch(void* const* d_in, const int* in_sizes, int n_in,
                              void* d_out, int out_size, void* d_ws, size_t ws_size,
                              hipStream_t stream)
{
    const float* hidden      = (const float*)d_in[0];
    const float* attn_read_w = (const float*)d_in[2];
    const float* attn_read_g = (const float*)d_in[3];
    const float* attn_read_b = (const float*)d_in[4];
    const float* qkv_w       = (const float*)d_in[5];
    const float* attn_wod_w  = (const float*)d_in[6];
    const float* attn_wab_w  = (const float*)d_in[7];
    const float* attn_wab_b  = (const float*)d_in[8];
    const float* attn_du_w   = (const float*)d_in[9];
    const float* attn_du_b   = (const float*)d_in[10];
    const float* mlp_read_w  = (const float*)d_in[11];
    const float* mlp_read_g  = (const float*)d_in[12];
    const float* mlp_read_b  = (const float*)d_in[13];
    const float* mlp_in_w    = (const float*)d_in[14];
    const float* mlp_wod_w   = (const float*)d_in[15];
    const float* mlp_wab_w   = (const float*)d_in[16];
    const float* mlp_wab_b   = (const float*)d_in[17];
    const float* mlp_du_w    = (const float*)d_in[18];
    const float* mlp_du_b    = (const float*)d_in[19];
    float* out = (float*)d_out;
    char* wsb = (char*)d_ws;
    const size_t N = NTOK;

    // ---- workspace layout (bytes) ----
    ushort* qkv_wb  = (ushort*)(wsb + 0);          // 3*1024*1024
    ushort* wodA_b  = (ushort*)(wsb + 6291456);    // 1152*1024
    ushort* wabA_b  = (ushort*)(wsb + 8650752);    // 128*1024
    ushort* mlpin_b = (ushort*)(wsb + 8912896);    // 2*4096*1024
    ushort* wodM_b  = (ushort*)(wsb + 25690112);   // 1152*4096
    ushort* wabM_b  = (ushort*)(wsb + 35127296);   // 128*4096
    char* R1 = wsb + 36175872;                     // 25.2 MB region
    char* R2 = wsb + 61341696;                     // 67.1 MB region
    ushort* qkv_in = (ushort*)R1;                  // [N*3072] bf16
    ushort* Qb     = (ushort*)R1;                  // [N*1024] bf16 (after qkv GEMMs)
    ushort* Kb     = (ushort*)(R1 + 8388608);
    ushort* Vt     = (ushort*)(R1 + 16777216);     // [1024][N] bf16
    ushort* mlp_in = (ushort*)R1;                  // [N*2048] bf16 (phase M)
    float*  od_m   = (float*)R1;                   // [N*1032] (after mlp_in dead)
    float*  ab_m   = (float*)(R1 + 16908288);      // [N*112]
    float*  q_     = (float*)R2;                   // [N*1024] f32
    float*  k_     = (float*)(R2 + 16777216);
    ushort* atno   = (ushort*)R2;                  // [N*1024] bf16 (after rope)
    float*  od_a   = (float*)(R2 + 8388608);       // [N*1032]
    float*  ab_a   = (float*)(R2 + 25296896);      // [N*112]
    float*  skpA   = (float*)(R2 + 27131904);      // [8*N*112]
    ushort* up_    = (ushort*)R2;                  // [N*4096] bf16 (phase M)
    ushort* upb    = (ushort*)(R2 + 33554432);     // [N*4096] bf16
    float*  skpM   = (float*)R2;                   // [8*N*112] (after up_ dead)

    // ---- weight conversion (bf16, zero-padded output rows) ----
    convert_flat_kernel<<<1536, 256, 0, stream>>>(qkv_w, qkv_wb);
    convert_flat_kernel<<<4096, 256, 0, stream>>>(mlp_in_w, mlpin_b);
    convert_pad_kernel<<<576, 256, 0, stream>>>(attn_wod_w, wodA_b, 1032, 1024);
    convert_pad_kernel<<<64, 256, 0, stream>>>(attn_wab_w, wabA_b, 112, 1024);
    convert_pad_kernel<<<2304, 256, 0, stream>>>(mlp_wod_w, wodM_b, 1032, 4096);
    convert_pad_kernel<<<256, 256, 0, stream>>>(mlp_wab_w, wabM_b, 112, 4096);

    // ---- attention half ----
    rat_read_kernel<3><<<N, 256, 0, stream>>>(hidden, attn_read_w, attn_read_g, attn_read_b, qkv_in);

    mfma_gemm_kernel<0><<<dim3(32, 8), 256, 0, stream>>>(qkv_in, 3072, qkv_wb, 1024, q_, 1024, 1024, nullptr, 1024);
    mfma_gemm_kernel<0><<<dim3(32, 8), 256, 0, stream>>>(qkv_in + 1024, 3072, qkv_wb + 1048576, 1024, k_, 1024, 1024, nullptr, 1024);
    mfma_gemm_kernel<3><<<dim3(32, 8), 256, 0, stream>>>(qkv_in + 2048, 3072, qkv_wb + 2097152, 1024, Vt, NTOK, 1024, nullptr, 1024);

    rope_bf16_kernel<<<8192, 256, 0, stream>>>(q_, k_, Qb, Kb);

    attn_mfma_kernel<<<dim3(32, 32), 256, 0, stream>>>(Qb, Kb, Vt, atno);

    mfma_gemm_kernel<0><<<dim3(32, 9), 256, 0, stream>>>(atno, 1024, wodA_b, 1024, od_a, 1032, 1032, nullptr, 1024);
    mfma_gemm_kernel<0><<<dim3(32, 1, 8), 256, 0, stream>>>(atno, 1024, wabA_b, 1024, skpA, 112, 112, nullptr, 128);
    splitk_reduce_kernel<<<1792, 256, 0, stream>>>(skpA, attn_wab_b, ab_a, 8);

    rat_write_kernel<<<N, 256, 0, stream>>>(hidden, od_a, ab_a, attn_du_w, attn_du_b, out);

    // ---- MLP half ----
    rat_read_kernel<2><<<N, 256, 0, stream>>>(out, mlp_read_w, mlp_read_g, mlp_read_b, mlp_in);

    mfma_gemm_kernel<1><<<dim3(32, 32), 256, 0, stream>>>(mlp_in + 1024, 2048, mlpin_b + 4194304, 1024, up_, 4096, 4096, nullptr, 1024);
    mfma_gemm_kernel<2><<<dim3(32, 32), 256, 0, stream>>>(mlp_in, 2048, mlpin_b, 1024, upb, 4096, 4096, up_, 1024);

    mfma_gemm_kernel<0><<<dim3(32, 9), 256, 0, stream>>>(upb, 4096, wodM_b, 4096, od_m, 1032, 1032, nullptr, 4096);
    mfma_gemm_kernel<0><<<dim3(32, 1, 8), 256, 0, stream>>>(upb, 4096, wabM_b, 4096, skpM, 112, 112, nullptr, 512);
    splitk_reduce_kernel<<<1792, 256, 0, stream>>>(skpM, mlp_wab_b, ab_m, 8);

    rat_write_kernel<<<N, 256, 0, stream>>>(out, od_m, ab_m, mlp_du_w, mlp_du_b, out);
}

// Round 5
// 574.761 us; speedup vs baseline: 6.2468x; 1.0527x over previous
//
#include <hip/hip_runtime.h>
#include <math.h>
#include <stdint.h>

// ---------------------------------------------------------------------------
// RatLayer forward. bf16 MFMA GEMMs (128^2 and 256^2 2-phase pipelined with
// global_load_lds), balanced-pair flash attention.
// H=1024 C=4 RH=16 HS=64 DR=8 M=4096 NH=16 HD=64 A_SIZE=48 B_SIZE=64
// B=2 L=2048 -> NTOK=4096 tokens.
// ---------------------------------------------------------------------------

constexpr int NTOK = 4096;

typedef __attribute__((ext_vector_type(8))) short short8_t;
typedef __attribute__((ext_vector_type(4))) float f32x4;

__device__ __forceinline__ ushort f2bf(float f) {
    union { float f; uint32_t u; } v; v.f = f;
    uint32_t r = v.u + 0x7fffu + ((v.u >> 16) & 1u);
    return (ushort)(r >> 16);
}
__device__ __forceinline__ float bf2f(ushort b) {
    union { uint32_t u; float f; } v; v.u = ((uint32_t)b) << 16;
    return v.f;
}
__device__ __forceinline__ uint32_t pack2(float lo, float hi) {
    return (uint32_t)f2bf(lo) | ((uint32_t)f2bf(hi) << 16);
}
__device__ __forceinline__ float softplus_f(float x) {
    return (x > 20.0f) ? x : log1pf(expf(x));
}

// async global->LDS, 16B per lane; LDS dest is wave-uniform base + lane*16.
__device__ __forceinline__ void gload_lds16(const void* g, void* l) {
    __builtin_amdgcn_global_load_lds(
        (const __attribute__((address_space(1))) uint32_t*)g,
        (__attribute__((address_space(3))) uint32_t*)l,
        16, 0, 0);
}

// ---------------------------------------------------------------------------
// Weight conversion f32 -> bf16 (flat, and row-padded variants).
// ---------------------------------------------------------------------------
__global__ __launch_bounds__(256) void convert_flat_kernel(
    const float* __restrict__ src, ushort* __restrict__ dst)
{
    const size_t i = ((size_t)blockIdx.x * 256 + threadIdx.x) * 8;
    const float4 a = *(const float4*)(src + i);
    const float4 b = *(const float4*)(src + i + 4);
    union { ushort u[8]; uint4 v; } o;
    o.u[0] = f2bf(a.x); o.u[1] = f2bf(a.y); o.u[2] = f2bf(a.z); o.u[3] = f2bf(a.w);
    o.u[4] = f2bf(b.x); o.u[5] = f2bf(b.y); o.u[6] = f2bf(b.z); o.u[7] = f2bf(b.w);
    *(uint4*)(dst + i) = o.v;
}

__global__ __launch_bounds__(256) void convert_pad_kernel(
    const float* __restrict__ src, ushort* __restrict__ dst, int O, int K)
{
    const size_t i = ((size_t)blockIdx.x * 256 + threadIdx.x) * 8;
    const int row = (int)(i / (size_t)K);
    union { ushort u[8]; uint4 v; } o;
    if (row < O) {
        const float4 a = *(const float4*)(src + i);
        const float4 b = *(const float4*)(src + i + 4);
        o.u[0] = f2bf(a.x); o.u[1] = f2bf(a.y); o.u[2] = f2bf(a.z); o.u[3] = f2bf(a.w);
        o.u[4] = f2bf(b.x); o.u[5] = f2bf(b.y); o.u[6] = f2bf(b.z); o.u[7] = f2bf(b.w);
    } else {
        o.v = make_uint4(0, 0, 0, 0);
    }
    *(uint4*)(dst + i) = o.v;
}

// ---------------------------------------------------------------------------
// rat_read: y[o,h] = sum_c res[h*4+c] * W[h,o,c]; LayerNorm over h per o;
// writes bf16. One block per token.
// ---------------------------------------------------------------------------
template <int NO>
__global__ __launch_bounds__(256) void rat_read_kernel(
    const float* __restrict__ res, const float* __restrict__ W,
    const float* __restrict__ gamma, const float* __restrict__ beta,
    ushort* __restrict__ out)
{
    const int t = blockIdx.x;
    const int tid = threadIdx.x;
    const float* rp = res + (size_t)t * 4096;
    float y[4][NO];
#pragma unroll
    for (int i = 0; i < 4; ++i) {
        const int h = tid + 256 * i;
        const float4 x = *(const float4*)(rp + h * 4);
#pragma unroll
        for (int o = 0; o < NO; ++o) {
            const float4 w = *(const float4*)(W + ((size_t)h * NO + o) * 4);
            y[i][o] = x.x * w.x + x.y * w.y + x.z * w.z + x.w * w.w;
        }
    }
    __shared__ float red[4][NO][2];
    const int lane = tid & 63, wid = tid >> 6;
#pragma unroll
    for (int o = 0; o < NO; ++o) {
        float s = 0.f, ss = 0.f;
#pragma unroll
        for (int i = 0; i < 4; ++i) { s += y[i][o]; ss += y[i][o] * y[i][o]; }
        for (int off = 32; off > 0; off >>= 1) {
            s += __shfl_down(s, off);
            ss += __shfl_down(ss, off);
        }
        if (lane == 0) { red[wid][o][0] = s; red[wid][o][1] = ss; }
    }
    __syncthreads();
    float mu[NO], rs[NO];
#pragma unroll
    for (int o = 0; o < NO; ++o) {
        const float s  = red[0][o][0] + red[1][o][0] + red[2][o][0] + red[3][o][0];
        const float ss = red[0][o][1] + red[1][o][1] + red[2][o][1] + red[3][o][1];
        const float m = s * (1.0f / 1024.0f);
        const float v = ss * (1.0f / 1024.0f) - m * m;
        mu[o] = m;
        rs[o] = rsqrtf(v + 1e-5f);
    }
    ushort* op = out + (size_t)t * (NO * 1024);
#pragma unroll
    for (int i = 0; i < 4; ++i) {
        const int h = tid + 256 * i;
#pragma unroll
        for (int o = 0; o < NO; ++o) {
            op[o * 1024 + h] = f2bf((y[i][o] - mu[o]) * rs[o] * gamma[o * 1024 + h] + beta[o * 1024 + h]);
        }
    }
}

// ---------------------------------------------------------------------------
// bf16 MFMA GEMM, 128x128 tile, BK=64, 2-phase pipelined (global_load_lds).
// EPI: 0 f32 (+z partials, col<O guard), 1 bf16, 2 silu*U bf16, 3 transposed.
// ---------------------------------------------------------------------------
__device__ __forceinline__ void stage_tile(
    ushort* AsB, ushort* BsB, const ushort* Ag, const ushort* Wg,
    size_t lda8, size_t ldw8, int w, int kofs)
{
#pragma unroll
    for (int i = 0; i < 4; ++i) {
        gload_lds16(Ag + kofs + i * lda8, AsB + (w * 4 + i) * 512);
        gload_lds16(Wg + kofs + i * ldw8, BsB + (w * 4 + i) * 512);
    }
}

template <int EPI>
__global__ __launch_bounds__(256) void mfma_gemm_kernel(
    const ushort* __restrict__ A, int lda,
    const ushort* __restrict__ W, int ldw,
    void* __restrict__ Cp, int ldc, int O,
    const ushort* __restrict__ U,
    int Kblk)
{
    __shared__ ushort As[2][128 * 64];
    __shared__ ushort Bs[2][128 * 64];
    const int tid = threadIdx.x;
    const int nwg = gridDim.x * gridDim.y;
    const int id = blockIdx.y * gridDim.x + blockIdx.x;
    const int swz = (id & 7) * (nwg >> 3) + (id >> 3);
    const int bm = (swz % gridDim.x) * 128;
    const int bo = (swz / gridDim.x) * 128;

    const int w = tid >> 6, l = tid & 63;
    const int lq = l & 15, lg = l >> 4;
    const int wr = (w >> 1) * 64, wc = (w & 1) * 64;

    f32x4 acc[4][4];
#pragma unroll
    for (int i = 0; i < 4; ++i)
#pragma unroll
        for (int j = 0; j < 4; ++j) acc[i][j] = (f32x4){0.f, 0.f, 0.f, 0.f};

    const int srow = 32 * w + (l >> 3);
    const int skc  = ((l & 7) ^ (l >> 3)) * 8;
    const ushort* Ag = A + (size_t)(bm + srow) * lda + (size_t)blockIdx.z * Kblk + skc;
    const ushort* Wg = W + (size_t)(bo + srow) * ldw + (size_t)blockIdx.z * Kblk + skc;
    const size_t lda8 = (size_t)8 * lda, ldw8 = (size_t)8 * ldw;

    const int nt = Kblk >> 6;
    stage_tile(As[0], Bs[0], Ag, Wg, lda8, ldw8, w, 0);
    __syncthreads();
    int cur = 0;
    for (int t = 0; t < nt; ++t) {
        if (t + 1 < nt)
            stage_tile(As[cur ^ 1], Bs[cur ^ 1], Ag, Wg, lda8, ldw8, w, (t + 1) * 64);
#pragma unroll
        for (int ks = 0; ks < 2; ++ks) {
            short8_t af[4], bf[4];
            const int jc = ks * 4 + lg;
#pragma unroll
            for (int mf = 0; mf < 4; ++mf) {
                const int ra = wr + mf * 16 + lq;
                af[mf] = *(const short8_t*)&As[cur][ra * 64 + ((jc ^ (ra & 7)) * 8)];
                const int rb = wc + mf * 16 + lq;
                bf[mf] = *(const short8_t*)&Bs[cur][rb * 64 + ((jc ^ (rb & 7)) * 8)];
            }
#pragma unroll
            for (int mf = 0; mf < 4; ++mf)
#pragma unroll
                for (int nf = 0; nf < 4; ++nf)
                    acc[mf][nf] = __builtin_amdgcn_mfma_f32_16x16x32_bf16(
                        af[mf], bf[nf], acc[mf][nf], 0, 0, 0);
        }
        __syncthreads();
        cur ^= 1;
    }

    if (EPI == 0) {
#pragma unroll
        for (int mf = 0; mf < 4; ++mf)
#pragma unroll
            for (int r = 0; r < 4; ++r) {
                const int row = bm + wr + mf * 16 + lg * 4 + r;
#pragma unroll
                for (int nf = 0; nf < 4; ++nf) {
                    const int col = bo + wc + nf * 16 + lq;
                    if (col < O)
                        ((float*)Cp)[(size_t)blockIdx.z * NTOK * ldc + (size_t)row * ldc + col] = acc[mf][nf][r];
                }
            }
    } else {
        ushort* eb = &As[0][0] + w * 4096;
#pragma unroll
        for (int mf = 0; mf < 4; ++mf)
#pragma unroll
            for (int r = 0; r < 4; ++r)
#pragma unroll
                for (int nf = 0; nf < 4; ++nf) {
                    const int rl = mf * 16 + lg * 4 + r;
                    const int cl = nf * 16 + lq;
                    if (EPI == 3) eb[cl * 64 + rl] = f2bf(acc[mf][nf][r]);
                    else          eb[rl * 64 + cl] = f2bf(acc[mf][nf][r]);
                }
#pragma unroll
        for (int p = 0; p < 8; ++p) {
            const int rl = p * 8 + (l >> 3);
            const int cl = (l & 7) * 8;
            uint4 v = *(const uint4*)&eb[rl * 64 + cl];
            if (EPI == 1) {
                *(uint4*)((ushort*)Cp + (size_t)(bm + wr + rl) * ldc + bo + wc + cl) = v;
            } else if (EPI == 2) {
                const ushort* up = U + (size_t)(bm + wr + rl) * ldc + bo + wc + cl;
                const uint4 uv = *(const uint4*)up;
                union { uint4 v; ushort u[8]; } g, uu, o;
                g.v = v; uu.v = uv;
#pragma unroll
                for (int e = 0; e < 8; ++e) {
                    const float gf = bf2f(g.u[e]);
                    o.u[e] = f2bf(gf / (1.0f + __expf(-gf)) * bf2f(uu.u[e]));
                }
                *(uint4*)((ushort*)Cp + (size_t)(bm + wr + rl) * ldc + bo + wc + cl) = o.v;
            } else {
                *(uint4*)((ushort*)Cp + (size_t)(bo + wc + rl) * ldc + bm + wr + cl) = v;
            }
        }
    }
}

// ---------------------------------------------------------------------------
// bf16 MFMA GEMM, 256x256 tile, BK=32, 512 thr = 8 waves (2M x 4N, 128x64
// each), 64KB LDS double-buffered, 2-phase global_load_lds pipeline.
// XOR swizzle key = (row>>1)&3 (64B rows wrap 32 banks every 2 rows).
// EPI: 1 bf16 store, 2 silu(acc)*U bf16 store.
// ---------------------------------------------------------------------------
template <int EPI>
__global__ __launch_bounds__(512) void gemm256_kernel(
    const ushort* __restrict__ A, int lda,
    const ushort* __restrict__ W, int ldw,
    ushort* __restrict__ Cp, int ldc,
    const ushort* __restrict__ U, int K)
{
    __shared__ ushort lds[2][2][256 * 32];   // [buf][A/B][row*32+col]
    const int tid = threadIdx.x;
    const int nwg = gridDim.x * gridDim.y;
    const int id = blockIdx.y * gridDim.x + blockIdx.x;
    const int swz = (id & 7) * (nwg >> 3) + (id >> 3);
    const int bm = (swz % gridDim.x) * 256;
    const int bo = (swz / gridDim.x) * 256;

    const int w = tid >> 6, l = tid & 63;
    const int lq = l & 15, lg = l >> 4;
    const int wrow = (w >> 2) * 128, wcol = (w & 3) * 64;

    f32x4 acc[8][4];
#pragma unroll
    for (int i = 0; i < 8; ++i)
#pragma unroll
        for (int j = 0; j < 4; ++j) acc[i][j] = (f32x4){0.f, 0.f, 0.f, 0.f};

    // staging: wave w stages rows w*32..w*32+31 (2 instrs of 16 rows each).
    // lane l -> row +(l>>2), dest chunk l&3, source chunk (l&3)^((l>>3)&3).
    const int srow = w * 32 + (l >> 2);
    const int schunk = (l & 3) ^ ((l >> 3) & 3);
    const ushort* Ag = A + (size_t)(bm + srow) * lda + schunk * 8;
    const ushort* Wg = W + (size_t)(bo + srow) * ldw + schunk * 8;
    const size_t lda16 = (size_t)16 * lda, ldw16 = (size_t)16 * ldw;

    const int nt = K >> 5;
    int cur = 0;
#pragma unroll
    for (int i = 0; i < 2; ++i) {
        gload_lds16(Ag + i * lda16, &lds[0][0][(w * 32 + i * 16) * 32]);
        gload_lds16(Wg + i * ldw16, &lds[0][1][(w * 32 + i * 16) * 32]);
    }
    __syncthreads();
    for (int t = 0; t < nt; ++t) {
        if (t + 1 < nt) {
            const int k0 = (t + 1) * 32;
#pragma unroll
            for (int i = 0; i < 2; ++i) {
                gload_lds16(Ag + k0 + i * lda16, &lds[cur ^ 1][0][(w * 32 + i * 16) * 32]);
                gload_lds16(Wg + k0 + i * ldw16, &lds[cur ^ 1][1][(w * 32 + i * 16) * 32]);
            }
        }
        short8_t af[8], bf[4];
#pragma unroll
        for (int mf = 0; mf < 8; ++mf) {
            const int ra = wrow + mf * 16 + lq;
            af[mf] = *(const short8_t*)&lds[cur][0][ra * 32 + ((lg ^ ((ra >> 1) & 3)) * 8)];
        }
#pragma unroll
        for (int nf = 0; nf < 4; ++nf) {
            const int rb = wcol + nf * 16 + lq;
            bf[nf] = *(const short8_t*)&lds[cur][1][rb * 32 + ((lg ^ ((rb >> 1) & 3)) * 8)];
        }
#pragma unroll
        for (int mf = 0; mf < 8; ++mf)
#pragma unroll
            for (int nf = 0; nf < 4; ++nf)
                acc[mf][nf] = __builtin_amdgcn_mfma_f32_16x16x32_bf16(
                    af[mf], bf[nf], acc[mf][nf], 0, 0, 0);
        __syncthreads();
        cur ^= 1;
    }

    // epilogue: per-wave LDS transpose staging, two 64-row halves.
    ushort* eb = &lds[0][0][0] + w * 4096;   // 8KB per wave
#pragma unroll
    for (int h = 0; h < 2; ++h) {
#pragma unroll
        for (int mf2 = 0; mf2 < 4; ++mf2)
#pragma unroll
            for (int r = 0; r < 4; ++r)
#pragma unroll
                for (int nf = 0; nf < 4; ++nf) {
                    const int rl = mf2 * 16 + lg * 4 + r;
                    const int cl = nf * 16 + lq;
                    eb[rl * 64 + cl] = f2bf(acc[h * 4 + mf2][nf][r]);
                }
#pragma unroll
        for (int p = 0; p < 8; ++p) {
            const int rl = p * 8 + (l >> 3);
            const int cl = (l & 7) * 8;
            const uint4 v = *(const uint4*)&eb[rl * 64 + cl];
            const size_t row = bm + wrow + h * 64 + rl;
            const size_t col = bo + wcol + cl;
            if (EPI == 1) {
                *(uint4*)(Cp + row * ldc + col) = v;
            } else {
                const uint4 uv = *(const uint4*)(U + row * ldc + col);
                union { uint4 v; ushort u[8]; } g, uu, o;
                g.v = v; uu.v = uv;
#pragma unroll
                for (int e = 0; e < 8; ++e) {
                    const float gf = bf2f(g.u[e]);
                    o.u[e] = f2bf(gf / (1.0f + __expf(-gf)) * bf2f(uu.u[e]));
                }
                *(uint4*)(Cp + row * ldc + col) = o.v;
            }
        }
    }
}

// Sum split-K partials (nz x NTOK x 112) + bias -> C (NTOK x 112) f32.
__global__ __launch_bounds__(256) void splitk_reduce_kernel(
    const float* __restrict__ part, const float* __restrict__ bias,
    float* __restrict__ C, int nz)
{
    const int idx = blockIdx.x * 256 + threadIdx.x;
    const int col = idx % 112;
    float s = bias[col];
    for (int z = 0; z < nz; ++z) s += part[(size_t)z * NTOK * 112 + idx];
    C[idx] = s;
}

// ---------------------------------------------------------------------------
// RoPE: read q,k f32, write bf16 Qb (scaled by 1/8) and Kb. pos = token & 2047.
// ---------------------------------------------------------------------------
__global__ __launch_bounds__(256) void rope_bf16_kernel(
    const float* __restrict__ q, const float* __restrict__ k,
    ushort* __restrict__ Qb, ushort* __restrict__ Kb)
{
    const int idx = blockIdx.x * 256 + threadIdx.x;   // < NTOK*512
    const int i  = idx & 31;
    const int nh = (idx >> 5) & 15;
    const int t  = idx >> 9;
    const int pos = t & 2047;
    const float inv = expf(-(float)i * (9.210340371976184f / 32.0f));
    float s, c;
    sincosf((float)pos * inv, &s, &c);
    const size_t base = (size_t)t * 1024 + nh * 64 + i;
    const float q1 = q[base], q2 = q[base + 32];
    Qb[base]      = f2bf((q1 * c - q2 * s) * 0.125f);
    Qb[base + 32] = f2bf((q2 * c + q1 * s) * 0.125f);
    const float k1 = k[base], k2 = k[base + 32];
    Kb[base]      = f2bf(k1 * c - k2 * s);
    Kb[base + 32] = f2bf(k2 * c + k1 * s);
}

// ---------------------------------------------------------------------------
// MFMA flash attention, bf16, LDS-staged K/V double-buffered prefetch,
// balanced q-tile pairs: block handles qb in {31-bx, bx} (work = 33 units
// per block, uniform). Grid (16, 32 b*h) = 512 blocks.
// ---------------------------------------------------------------------------
__global__ __launch_bounds__(256) void attn_mfma_kernel(
    const ushort* __restrict__ Qb, const ushort* __restrict__ Kb,
    const ushort* __restrict__ Vt, ushort* __restrict__ atno)
{
    __shared__ ushort Ks[2][64 * 64];
    __shared__ ushort Vs[2][64 * 64];
    const int bh = blockIdx.y;
    const int b = bh >> 4, h = bh & 15;
    const int w = threadIdx.x >> 6, l = threadIdx.x & 63;
    const int g = l >> 4, t = l & 15;
    const int tok0 = b * 2048;
    const int hoff = h * 64;

    const int srow = w * 16 + (l >> 3);
    const int schunk = (l & 7) ^ (l >> 3);
    const ushort* Kg = Kb + (size_t)(tok0 + srow) * 1024 + hoff + schunk * 8;
    const ushort* Vg = Vt + (size_t)(hoff + srow) * NTOK + tok0 + schunk * 8;
    const int ldsbase = w * 1024;

    const int srcA = ((g & 1) * 2) * 16 + t;
    const int srcB = srcA + 16;
    const bool hiSel = (g >> 1) != 0;

    int buf = 0;
    for (int pass = 0; pass < 2; ++pass) {
        const int qb = pass == 0 ? (31 - blockIdx.x) : blockIdx.x;
        const int qrow = tok0 + qb * 64 + w * 16 + t;

        short8_t qf[2];
#pragma unroll
        for (int ks = 0; ks < 2; ++ks)
            qf[ks] = *(const short8_t*)(Qb + (size_t)qrow * 1024 + hoff + ks * 32 + g * 8);

        float m_run = -3.0e38f, l_run = 0.0f;
        f32x4 oacc[4];
#pragma unroll
        for (int nf = 0; nf < 4; ++nf) oacc[nf] = (f32x4){0.f, 0.f, 0.f, 0.f};

        // prologue: stage kb=0 into buf
#pragma unroll
        for (int i = 0; i < 2; ++i) {
            gload_lds16(Kg + (size_t)(i * 8) * 1024, &Ks[buf][ldsbase + i * 512]);
            gload_lds16(Vg + (size_t)(i * 8) * NTOK, &Vs[buf][ldsbase + i * 512]);
        }
        __syncthreads();

        for (int kb = 0; kb <= qb; ++kb) {
            if (kb < qb) {
                const int nk = (kb + 1) * 64;
#pragma unroll
                for (int i = 0; i < 2; ++i) {
                    gload_lds16(Kg + (size_t)(nk + i * 8) * 1024, &Ks[buf ^ 1][ldsbase + i * 512]);
                    gload_lds16(Vg + nk + (size_t)(i * 8) * NTOK, &Vs[buf ^ 1][ldsbase + i * 512]);
                }
            }
            // QK^T from LDS K tile
            f32x4 sa[4];
#pragma unroll
            for (int mf = 0; mf < 4; ++mf) sa[mf] = (f32x4){0.f, 0.f, 0.f, 0.f};
            __builtin_amdgcn_s_setprio(1);
#pragma unroll
            for (int ks = 0; ks < 2; ++ks) {
                const int jc = ks * 4 + g;
#pragma unroll
                for (int mf = 0; mf < 4; ++mf) {
                    const short8_t kf = *(const short8_t*)&Ks[buf][(mf * 16 + t) * 64 + ((jc ^ (t & 7)) * 8)];
                    sa[mf] = __builtin_amdgcn_mfma_f32_16x16x32_bf16(kf, qf[ks], sa[mf], 0, 0, 0);
                }
            }
            __builtin_amdgcn_s_setprio(0);
            float p[4][4];
            float mloc = -3.0e38f;
#pragma unroll
            for (int mf = 0; mf < 4; ++mf)
#pragma unroll
                for (int r = 0; r < 4; ++r) {
                    float s = sa[mf][r];
                    if (kb == qb && (mf * 16 + g * 4 + r) > (w * 16 + t)) s = -3.0e38f;
                    p[mf][r] = s;
                    mloc = fmaxf(mloc, s);
                }
            mloc = fmaxf(mloc, __shfl_xor(mloc, 16));
            mloc = fmaxf(mloc, __shfl_xor(mloc, 32));
            const float mnew = fmaxf(m_run, mloc);
            float lsum = 0.f;
#pragma unroll
            for (int mf = 0; mf < 4; ++mf)
#pragma unroll
                for (int r = 0; r < 4; ++r) {
                    const float e = __expf(p[mf][r] - mnew);
                    p[mf][r] = e;
                    lsum += e;
                }
            lsum += __shfl_xor(lsum, 16);
            lsum += __shfl_xor(lsum, 32);
            const float fac = __expf(m_run - mnew);
            l_run = l_run * fac + lsum;
            m_run = mnew;
#pragma unroll
            for (int r = 0; r < 4; ++r) {
                const float fr = __shfl(fac, g * 4 + r);
#pragma unroll
                for (int nf = 0; nf < 4; ++nf) oacc[nf][r] *= fr;
            }
            uint32_t pk[4][2];
#pragma unroll
            for (int mf = 0; mf < 4; ++mf) {
                pk[mf][0] = pack2(p[mf][0], p[mf][1]);
                pk[mf][1] = pack2(p[mf][2], p[mf][3]);
            }
            // PV from LDS V tile
#pragma unroll
            for (int ks = 0; ks < 2; ++ks) {
                const uint32_t a00 = __shfl(pk[2 * ks][0], srcA);
                const uint32_t a01 = __shfl(pk[2 * ks][1], srcA);
                const uint32_t a10 = __shfl(pk[2 * ks + 1][0], srcA);
                const uint32_t a11 = __shfl(pk[2 * ks + 1][1], srcA);
                const uint32_t b00 = __shfl(pk[2 * ks][0], srcB);
                const uint32_t b01 = __shfl(pk[2 * ks][1], srcB);
                const uint32_t b10 = __shfl(pk[2 * ks + 1][0], srcB);
                const uint32_t b11 = __shfl(pk[2 * ks + 1][1], srcB);
                union { uint32_t u[4]; short8_t v; } pa;
                pa.u[0] = hiSel ? a10 : a00;
                pa.u[1] = hiSel ? a11 : a01;
                pa.u[2] = hiSel ? b10 : b00;
                pa.u[3] = hiSel ? b11 : b01;
                const int jc = ks * 4 + g;
                __builtin_amdgcn_s_setprio(1);
#pragma unroll
                for (int nf = 0; nf < 4; ++nf) {
                    const short8_t vf = *(const short8_t*)&Vs[buf][(nf * 16 + t) * 64 + ((jc ^ (t & 7)) * 8)];
                    oacc[nf] = __builtin_amdgcn_mfma_f32_16x16x32_bf16(pa.v, vf, oacc[nf], 0, 0, 0);
                }
                __builtin_amdgcn_s_setprio(0);
            }
            __syncthreads();   // prefetch resident + all reads of buf done
            buf ^= 1;
        }
        const float inv = 1.0f / l_run;
#pragma unroll
        for (int r = 0; r < 4; ++r) {
            const float ir = __shfl(inv, g * 4 + r);
            const int orow = tok0 + qb * 64 + w * 16 + g * 4 + r;
#pragma unroll
            for (int nf = 0; nf < 4; ++nf)
                atno[(size_t)orow * 1024 + hoff + nf * 16 + t] = f2bf(oacc[nf][r] * ir);
        }
    }
}

// ---------------------------------------------------------------------------
// rat_write: fused du-projection (K=8) + softplus + SSM update. f32.
// ---------------------------------------------------------------------------
__global__ __launch_bounds__(256) void rat_write_kernel(
    const float* res, const float* __restrict__ od,
    const float* __restrict__ AB, const float* __restrict__ du_w,
    const float* __restrict__ du_b, float* out)
{
    const int t = blockIdx.x;
    const int tid = threadIdx.x;
    __shared__ float sAB[112];
    __shared__ float sdl[8];
    if (tid < 112) sAB[tid] = AB[(size_t)t * 112 + tid];
    if (tid >= 128 && tid < 136) sdl[tid - 128] = od[(size_t)t * 1032 + 1024 + (tid - 128)];
    __syncthreads();
    const float* rp = res + (size_t)t * 4096;
    const float* odp = od + (size_t)t * 1032;
    float* op = out + (size_t)t * 4096;
#pragma unroll
    for (int ii = 0; ii < 4; ++ii) {
        const int hh = tid + 256 * ii;
        const int rh = hh & 15;
        const float4 w0 = *(const float4*)(du_w + hh * 8);
        const float4 w1 = *(const float4*)(du_w + hh * 8 + 4);
        float dacc = du_b[hh];
        dacc += sdl[0] * w0.x + sdl[1] * w0.y + sdl[2] * w0.z + sdl[3] * w0.w;
        dacc += sdl[4] * w1.x + sdl[5] * w1.y + sdl[6] * w1.z + sdl[7] * w1.w;
        const float delta = softplus_f(dacc);
        const float oh = odp[hh];
        const float4 hs = *(const float4*)(rp + hh * 4);
        const float r4[4] = {hs.x, hs.y, hs.z, hs.w};
        float o4[4];
#pragma unroll
        for (int c = 0; c < 3; ++c) {
            const float Aneg = -softplus_f(sAB[rh * 3 + c]);
            const float Abar = expf(delta * Aneg);
            const float Bbar = (Abar - 1.0f) / (Aneg - 1e-5f) * sAB[48 + rh * 3 + c];
            o4[c] = r4[c] * Abar + oh * Bbar;
        }
        o4[3] = r4[3] + oh * (delta * sAB[96 + rh]);
        *(float4*)(op + hh * 4) = make_float4(o4[0], o4[1], o4[2], o4[3]);
    }
}

// ---------------------------------------------------------------------------
extern "C" void kernel_launch(void* const* d_in, const int* in_sizes, int n_in,
                              void* d_out, int out_size, void* d_ws, size_t ws_size,
                              hipStream_t stream)
{
    const float* hidden      = (const float*)d_in[0];
    const float* attn_read_w = (const float*)d_in[2];
    const float* attn_read_g = (const float*)d_in[3];
    const float* attn_read_b = (const float*)d_in[4];
    const float* qkv_w       = (const float*)d_in[5];
    const float* attn_wod_w  = (const float*)d_in[6];
    const float* attn_wab_w  = (const float*)d_in[7];
    const float* attn_wab_b  = (const float*)d_in[8];
    const float* attn_du_w   = (const float*)d_in[9];
    const float* attn_du_b   = (const float*)d_in[10];
    const float* mlp_read_w  = (const float*)d_in[11];
    const float* mlp_read_g  = (const float*)d_in[12];
    const float* mlp_read_b  = (const float*)d_in[13];
    const float* mlp_in_w    = (const float*)d_in[14];
    const float* mlp_wod_w   = (const float*)d_in[15];
    const float* mlp_wab_w   = (const float*)d_in[16];
    const float* mlp_wab_b   = (const float*)d_in[17];
    const float* mlp_du_w    = (const float*)d_in[18];
    const float* mlp_du_b    = (const float*)d_in[19];
    float* out = (float*)d_out;
    char* wsb = (char*)d_ws;
    const size_t N = NTOK;

    // ---- workspace layout (bytes) ----
    ushort* qkv_wb  = (ushort*)(wsb + 0);          // 3*1024*1024
    ushort* wodA_b  = (ushort*)(wsb + 6291456);    // 1152*1024
    ushort* wabA_b  = (ushort*)(wsb + 8650752);    // 128*1024
    ushort* mlpin_b = (ushort*)(wsb + 8912896);    // 2*4096*1024
    ushort* wodM_b  = (ushort*)(wsb + 25690112);   // 1152*4096
    ushort* wabM_b  = (ushort*)(wsb + 35127296);   // 128*4096
    char* R1 = wsb + 36175872;                     // 25.2 MB region
    char* R2 = wsb + 61341696;                     // 67.1 MB region
    ushort* qkv_in = (ushort*)R1;                  // [N*3072] bf16
    ushort* Qb     = (ushort*)R1;                  // [N*1024] bf16 (after qkv GEMMs)
    ushort* Kb     = (ushort*)(R1 + 8388608);
    ushort* Vt     = (ushort*)(R1 + 16777216);     // [1024][N] bf16
    ushort* mlp_in = (ushort*)R1;                  // [N*2048] bf16 (phase M)
    float*  od_m   = (float*)R1;                   // [N*1032] (after mlp_in dead)
    float*  ab_m   = (float*)(R1 + 16908288);      // [N*112]
    float*  q_     = (float*)R2;                   // [N*1024] f32
    float*  k_     = (float*)(R2 + 16777216);
    ushort* atno   = (ushort*)R2;                  // [N*1024] bf16 (after rope)
    float*  od_a   = (float*)(R2 + 8388608);       // [N*1032]
    float*  ab_a   = (float*)(R2 + 25296896);      // [N*112]
    float*  skpA   = (float*)(R2 + 27131904);      // [8*N*112]
    ushort* up_    = (ushort*)R2;                  // [N*4096] bf16 (phase M)
    ushort* upb    = (ushort*)(R2 + 33554432);     // [N*4096] bf16
    float*  skpM   = (float*)R2;                   // [8*N*112] (after up_ dead)

    // ---- weight conversion (bf16, zero-padded output rows) ----
    convert_flat_kernel<<<1536, 256, 0, stream>>>(qkv_w, qkv_wb);
    convert_flat_kernel<<<4096, 256, 0, stream>>>(mlp_in_w, mlpin_b);
    convert_pad_kernel<<<576, 256, 0, stream>>>(attn_wod_w, wodA_b, 1032, 1024);
    convert_pad_kernel<<<64, 256, 0, stream>>>(attn_wab_w, wabA_b, 112, 1024);
    convert_pad_kernel<<<2304, 256, 0, stream>>>(mlp_wod_w, wodM_b, 1032, 4096);
    convert_pad_kernel<<<256, 256, 0, stream>>>(mlp_wab_w, wabM_b, 112, 4096);

    // ---- attention half ----
    rat_read_kernel<3><<<N, 256, 0, stream>>>(hidden, attn_read_w, attn_read_g, attn_read_b, qkv_in);

    mfma_gemm_kernel<0><<<dim3(32, 8), 256, 0, stream>>>(qkv_in, 3072, qkv_wb, 1024, q_, 1024, 1024, nullptr, 1024);
    mfma_gemm_kernel<0><<<dim3(32, 8), 256, 0, stream>>>(qkv_in + 1024, 3072, qkv_wb + 1048576, 1024, k_, 1024, 1024, nullptr, 1024);
    mfma_gemm_kernel<3><<<dim3(32, 8), 256, 0, stream>>>(qkv_in + 2048, 3072, qkv_wb + 2097152, 1024, Vt, NTOK, 1024, nullptr, 1024);

    rope_bf16_kernel<<<8192, 256, 0, stream>>>(q_, k_, Qb, Kb);

    attn_mfma_kernel<<<dim3(16, 32), 256, 0, stream>>>(Qb, Kb, Vt, atno);

    mfma_gemm_kernel<0><<<dim3(32, 9), 256, 0, stream>>>(atno, 1024, wodA_b, 1024, od_a, 1032, 1032, nullptr, 1024);
    mfma_gemm_kernel<0><<<dim3(32, 1, 8), 256, 0, stream>>>(atno, 1024, wabA_b, 1024, skpA, 112, 112, nullptr, 128);
    splitk_reduce_kernel<<<1792, 256, 0, stream>>>(skpA, attn_wab_b, ab_a, 8);

    rat_write_kernel<<<N, 256, 0, stream>>>(hidden, od_a, ab_a, attn_du_w, attn_du_b, out);

    // ---- MLP half ----
    rat_read_kernel<2><<<N, 256, 0, stream>>>(out, mlp_read_w, mlp_read_g, mlp_read_b, mlp_in);

    gemm256_kernel<1><<<dim3(16, 16), 512, 0, stream>>>(mlp_in + 1024, 2048, mlpin_b + 4194304, 1024, up_, 4096, nullptr, 1024);
    gemm256_kernel<2><<<dim3(16, 16), 512, 0, stream>>>(mlp_in, 2048, mlpin_b, 1024, upb, 4096, up_, 1024);

    mfma_gemm_kernel<0><<<dim3(32, 9), 256, 0, stream>>>(upb, 4096, wodM_b, 4096, od_m, 1032, 1032, nullptr, 4096);
    mfma_gemm_kernel<0><<<dim3(32, 1, 8), 256, 0, stream>>>(upb, 4096, wabM_b, 4096, skpM, 112, 112, nullptr, 512);
    splitk_reduce_kernel<<<1792, 256, 0, stream>>>(skpM, mlp_wab_b, ab_m, 8);

    rat_write_kernel<<<N, 256, 0, stream>>>(out, od_m, ab_m, mlp_du_w, mlp_du_b, out);
}

// Round 6
// 537.644 us; speedup vs baseline: 6.6781x; 1.0690x over previous
//
#include <hip/hip_runtime.h>
#include <math.h>
#include <stdint.h>

// ---------------------------------------------------------------------------
// RatLayer forward. bf16 MFMA GEMMs, 2-phase global_load_lds pipelines,
// A-panel-sharing XCD ordering, KVBLK=128 flash attention.
// H=1024 C=4 RH=16 HS=64 DR=8 M=4096 NH=16 HD=64 A_SIZE=48 B_SIZE=64
// B=2 L=2048 -> NTOK=4096 tokens.
// ---------------------------------------------------------------------------

constexpr int NTOK = 4096;

typedef __attribute__((ext_vector_type(8))) short short8_t;
typedef __attribute__((ext_vector_type(4))) float f32x4;

__device__ __forceinline__ ushort f2bf(float f) {
    union { float f; uint32_t u; } v; v.f = f;
    uint32_t r = v.u + 0x7fffu + ((v.u >> 16) & 1u);
    return (ushort)(r >> 16);
}
__device__ __forceinline__ float bf2f(ushort b) {
    union { uint32_t u; float f; } v; v.u = ((uint32_t)b) << 16;
    return v.f;
}
__device__ __forceinline__ uint32_t pack2(float lo, float hi) {
    return (uint32_t)f2bf(lo) | ((uint32_t)f2bf(hi) << 16);
}
__device__ __forceinline__ float softplus_f(float x) {
    return (x > 20.0f) ? x : log1pf(expf(x));
}

// async global->LDS, 16B per lane; LDS dest is wave-uniform base + lane*16.
__device__ __forceinline__ void gload_lds16(const void* g, void* l) {
    __builtin_amdgcn_global_load_lds(
        (const __attribute__((address_space(1))) uint32_t*)g,
        (__attribute__((address_space(3))) uint32_t*)l,
        16, 0, 0);
}

// ---------------------------------------------------------------------------
// Weight conversion f32 -> bf16.
// ---------------------------------------------------------------------------
__global__ __launch_bounds__(256) void convert_flat_kernel(
    const float* __restrict__ src, ushort* __restrict__ dst)
{
    const size_t i = ((size_t)blockIdx.x * 256 + threadIdx.x) * 8;
    const float4 a = *(const float4*)(src + i);
    const float4 b = *(const float4*)(src + i + 4);
    union { ushort u[8]; uint4 v; } o;
    o.u[0] = f2bf(a.x); o.u[1] = f2bf(a.y); o.u[2] = f2bf(a.z); o.u[3] = f2bf(a.w);
    o.u[4] = f2bf(b.x); o.u[5] = f2bf(b.y); o.u[6] = f2bf(b.z); o.u[7] = f2bf(b.w);
    *(uint4*)(dst + i) = o.v;
}

// combined small-GEMM weight: rows 0..111 = wab_w, 112..119 = wod_w rows
// 1024..1031 (delta_low), 120..127 = zero.  [128][K] bf16.
__global__ __launch_bounds__(256) void build_small_kernel(
    const float* __restrict__ wab, const float* __restrict__ wod,
    ushort* __restrict__ dst, int K)
{
    const size_t i = ((size_t)blockIdx.x * 256 + threadIdx.x) * 8;
    const int row = (int)(i / (size_t)K);
    const int col = (int)(i % (size_t)K);
    union { ushort u[8]; uint4 v; } o;
    const float* src = nullptr;
    if (row < 112) src = wab + (size_t)row * K + col;
    else if (row < 120) src = wod + (size_t)(1024 + row - 112) * K + col;
    if (src) {
        const float4 a = *(const float4*)(src);
        const float4 b = *(const float4*)(src + 4);
        o.u[0] = f2bf(a.x); o.u[1] = f2bf(a.y); o.u[2] = f2bf(a.z); o.u[3] = f2bf(a.w);
        o.u[4] = f2bf(b.x); o.u[5] = f2bf(b.y); o.u[6] = f2bf(b.z); o.u[7] = f2bf(b.w);
    } else {
        o.v = make_uint4(0, 0, 0, 0);
    }
    *(uint4*)(dst + i) = o.v;
}

// ---------------------------------------------------------------------------
// rat_read: y[o,h] = sum_c res[h*4+c] * W[h,o,c]; LayerNorm over h per o;
// writes bf16. One block per token.
// ---------------------------------------------------------------------------
template <int NO>
__global__ __launch_bounds__(256) void rat_read_kernel(
    const float* __restrict__ res, const float* __restrict__ W,
    const float* __restrict__ gamma, const float* __restrict__ beta,
    ushort* __restrict__ out)
{
    const int t = blockIdx.x;
    const int tid = threadIdx.x;
    const float* rp = res + (size_t)t * 4096;
    float y[4][NO];
#pragma unroll
    for (int i = 0; i < 4; ++i) {
        const int h = tid + 256 * i;
        const float4 x = *(const float4*)(rp + h * 4);
#pragma unroll
        for (int o = 0; o < NO; ++o) {
            const float4 w = *(const float4*)(W + ((size_t)h * NO + o) * 4);
            y[i][o] = x.x * w.x + x.y * w.y + x.z * w.z + x.w * w.w;
        }
    }
    __shared__ float red[4][NO][2];
    const int lane = tid & 63, wid = tid >> 6;
#pragma unroll
    for (int o = 0; o < NO; ++o) {
        float s = 0.f, ss = 0.f;
#pragma unroll
        for (int i = 0; i < 4; ++i) { s += y[i][o]; ss += y[i][o] * y[i][o]; }
        for (int off = 32; off > 0; off >>= 1) {
            s += __shfl_down(s, off);
            ss += __shfl_down(ss, off);
        }
        if (lane == 0) { red[wid][o][0] = s; red[wid][o][1] = ss; }
    }
    __syncthreads();
    float mu[NO], rs[NO];
#pragma unroll
    for (int o = 0; o < NO; ++o) {
        const float s  = red[0][o][0] + red[1][o][0] + red[2][o][0] + red[3][o][0];
        const float ss = red[0][o][1] + red[1][o][1] + red[2][o][1] + red[3][o][1];
        const float m = s * (1.0f / 1024.0f);
        const float v = ss * (1.0f / 1024.0f) - m * m;
        mu[o] = m;
        rs[o] = rsqrtf(v + 1e-5f);
    }
    ushort* op = out + (size_t)t * (NO * 1024);
#pragma unroll
    for (int i = 0; i < 4; ++i) {
        const int h = tid + 256 * i;
#pragma unroll
        for (int o = 0; o < NO; ++o) {
            op[o * 1024 + h] = f2bf((y[i][o] - mu[o]) * rs[o] * gamma[o * 1024 + h] + beta[o * 1024 + h]);
        }
    }
}

// ---------------------------------------------------------------------------
// bf16 MFMA GEMM, 128x128 tile, BK=64, 2-phase pipelined (global_load_lds).
// XCD ordering: each XCD gets a contiguous bm-band, bo inner (A-panel L2 reuse).
// EPI: 0 f32 (+z partials, col<O guard), 1 bf16, 2 silu*U bf16, 3 transposed.
// ---------------------------------------------------------------------------
__device__ __forceinline__ void stage_tile(
    ushort* AsB, ushort* BsB, const ushort* Ag, const ushort* Wg,
    size_t lda8, size_t ldw8, int w, int kofs)
{
#pragma unroll
    for (int i = 0; i < 4; ++i) {
        gload_lds16(Ag + kofs + i * lda8, AsB + (w * 4 + i) * 512);
        gload_lds16(Wg + kofs + i * ldw8, BsB + (w * 4 + i) * 512);
    }
}

template <int EPI>
__global__ __launch_bounds__(256) void mfma_gemm_kernel(
    const ushort* __restrict__ A, int lda,
    const ushort* __restrict__ W, int ldw,
    void* __restrict__ Cp, int ldc, int O,
    const ushort* __restrict__ U,
    int Kblk)
{
    __shared__ ushort As[2][128 * 64];
    __shared__ ushort Bs[2][128 * 64];
    const int tid = threadIdx.x;
    const int nwg = gridDim.x * gridDim.y;
    const int gy = gridDim.y;
    const int id = blockIdx.y * gridDim.x + blockIdx.x;
    const int swz = (id & 7) * (nwg >> 3) + (id >> 3);
    const int bm = (swz / gy) * 128;
    const int bo = (swz % gy) * 128;

    const int w = tid >> 6, l = tid & 63;
    const int lq = l & 15, lg = l >> 4;
    const int wr = (w >> 1) * 64, wc = (w & 1) * 64;

    f32x4 acc[4][4];
#pragma unroll
    for (int i = 0; i < 4; ++i)
#pragma unroll
        for (int j = 0; j < 4; ++j) acc[i][j] = (f32x4){0.f, 0.f, 0.f, 0.f};

    const int srow = 32 * w + (l >> 3);
    const int skc  = ((l & 7) ^ (l >> 3)) * 8;
    const ushort* Ag = A + (size_t)(bm + srow) * lda + (size_t)blockIdx.z * Kblk + skc;
    const ushort* Wg = W + (size_t)(bo + srow) * ldw + (size_t)blockIdx.z * Kblk + skc;
    const size_t lda8 = (size_t)8 * lda, ldw8 = (size_t)8 * ldw;

    const int nt = Kblk >> 6;
    stage_tile(As[0], Bs[0], Ag, Wg, lda8, ldw8, w, 0);
    __syncthreads();
    int cur = 0;
    for (int t = 0; t < nt; ++t) {
        if (t + 1 < nt)
            stage_tile(As[cur ^ 1], Bs[cur ^ 1], Ag, Wg, lda8, ldw8, w, (t + 1) * 64);
#pragma unroll
        for (int ks = 0; ks < 2; ++ks) {
            short8_t af[4], bf[4];
            const int jc = ks * 4 + lg;
#pragma unroll
            for (int mf = 0; mf < 4; ++mf) {
                const int ra = wr + mf * 16 + lq;
                af[mf] = *(const short8_t*)&As[cur][ra * 64 + ((jc ^ (ra & 7)) * 8)];
                const int rb = wc + mf * 16 + lq;
                bf[mf] = *(const short8_t*)&Bs[cur][rb * 64 + ((jc ^ (rb & 7)) * 8)];
            }
#pragma unroll
            for (int mf = 0; mf < 4; ++mf)
#pragma unroll
                for (int nf = 0; nf < 4; ++nf)
                    acc[mf][nf] = __builtin_amdgcn_mfma_f32_16x16x32_bf16(
                        af[mf], bf[nf], acc[mf][nf], 0, 0, 0);
        }
        __syncthreads();
        cur ^= 1;
    }

    if (EPI == 0) {
#pragma unroll
        for (int mf = 0; mf < 4; ++mf)
#pragma unroll
            for (int r = 0; r < 4; ++r) {
                const int row = bm + wr + mf * 16 + lg * 4 + r;
#pragma unroll
                for (int nf = 0; nf < 4; ++nf) {
                    const int col = bo + wc + nf * 16 + lq;
                    if (col < O)
                        ((float*)Cp)[(size_t)blockIdx.z * NTOK * ldc + (size_t)row * ldc + col] = acc[mf][nf][r];
                }
            }
    } else {
        ushort* eb = &As[0][0] + w * 4096;
#pragma unroll
        for (int mf = 0; mf < 4; ++mf)
#pragma unroll
            for (int r = 0; r < 4; ++r)
#pragma unroll
                for (int nf = 0; nf < 4; ++nf) {
                    const int rl = mf * 16 + lg * 4 + r;
                    const int cl = nf * 16 + lq;
                    if (EPI == 3) eb[cl * 64 + rl] = f2bf(acc[mf][nf][r]);
                    else          eb[rl * 64 + cl] = f2bf(acc[mf][nf][r]);
                }
#pragma unroll
        for (int p = 0; p < 8; ++p) {
            const int rl = p * 8 + (l >> 3);
            const int cl = (l & 7) * 8;
            uint4 v = *(const uint4*)&eb[rl * 64 + cl];
            if (EPI == 1) {
                *(uint4*)((ushort*)Cp + (size_t)(bm + wr + rl) * ldc + bo + wc + cl) = v;
            } else if (EPI == 2) {
                const ushort* up = U + (size_t)(bm + wr + rl) * ldc + bo + wc + cl;
                const uint4 uv = *(const uint4*)up;
                union { uint4 v; ushort u[8]; } g, uu, o;
                g.v = v; uu.v = uv;
#pragma unroll
                for (int e = 0; e < 8; ++e) {
                    const float gf = bf2f(g.u[e]);
                    o.u[e] = f2bf(gf / (1.0f + __expf(-gf)) * bf2f(uu.u[e]));
                }
                *(uint4*)((ushort*)Cp + (size_t)(bm + wr + rl) * ldc + bo + wc + cl) = o.v;
            } else {
                *(uint4*)((ushort*)Cp + (size_t)(bo + wc + rl) * ldc + bm + wr + cl) = v;
            }
        }
    }
}

// ---------------------------------------------------------------------------
// bf16 MFMA GEMM, 256x256 tile, BK=32, 512 thr = 8 waves (2M x 4N),
// 64KB LDS double-buffered, 2-phase global_load_lds pipeline.
// EPI: 1 bf16 store, 2 silu(acc)*U bf16 store.
// ---------------------------------------------------------------------------
template <int EPI>
__global__ __launch_bounds__(512) void gemm256_kernel(
    const ushort* __restrict__ A, int lda,
    const ushort* __restrict__ W, int ldw,
    ushort* __restrict__ Cp, int ldc,
    const ushort* __restrict__ U, int K)
{
    __shared__ ushort lds[2][2][256 * 32];   // [buf][A/B][row*32+col]
    const int tid = threadIdx.x;
    const int nwg = gridDim.x * gridDim.y;
    const int gy = gridDim.y;
    const int id = blockIdx.y * gridDim.x + blockIdx.x;
    const int swz = (id & 7) * (nwg >> 3) + (id >> 3);
    const int bm = (swz / gy) * 256;
    const int bo = (swz % gy) * 256;

    const int w = tid >> 6, l = tid & 63;
    const int lq = l & 15, lg = l >> 4;
    const int wrow = (w >> 2) * 128, wcol = (w & 3) * 64;

    f32x4 acc[8][4];
#pragma unroll
    for (int i = 0; i < 8; ++i)
#pragma unroll
        for (int j = 0; j < 4; ++j) acc[i][j] = (f32x4){0.f, 0.f, 0.f, 0.f};

    const int srow = w * 32 + (l >> 2);
    const int schunk = (l & 3) ^ ((l >> 3) & 3);
    const ushort* Ag = A + (size_t)(bm + srow) * lda + schunk * 8;
    const ushort* Wg = W + (size_t)(bo + srow) * ldw + schunk * 8;
    const size_t lda16 = (size_t)16 * lda, ldw16 = (size_t)16 * ldw;

    const int nt = K >> 5;
    int cur = 0;
#pragma unroll
    for (int i = 0; i < 2; ++i) {
        gload_lds16(Ag + i * lda16, &lds[0][0][(w * 32 + i * 16) * 32]);
        gload_lds16(Wg + i * ldw16, &lds[0][1][(w * 32 + i * 16) * 32]);
    }
    __syncthreads();
    for (int t = 0; t < nt; ++t) {
        if (t + 1 < nt) {
            const int k0 = (t + 1) * 32;
#pragma unroll
            for (int i = 0; i < 2; ++i) {
                gload_lds16(Ag + k0 + i * lda16, &lds[cur ^ 1][0][(w * 32 + i * 16) * 32]);
                gload_lds16(Wg + k0 + i * ldw16, &lds[cur ^ 1][1][(w * 32 + i * 16) * 32]);
            }
        }
        short8_t af[8], bf[4];
#pragma unroll
        for (int mf = 0; mf < 8; ++mf) {
            const int ra = wrow + mf * 16 + lq;
            af[mf] = *(const short8_t*)&lds[cur][0][ra * 32 + ((lg ^ ((ra >> 1) & 3)) * 8)];
        }
#pragma unroll
        for (int nf = 0; nf < 4; ++nf) {
            const int rb = wcol + nf * 16 + lq;
            bf[nf] = *(const short8_t*)&lds[cur][1][rb * 32 + ((lg ^ ((rb >> 1) & 3)) * 8)];
        }
        __builtin_amdgcn_s_setprio(1);
#pragma unroll
        for (int mf = 0; mf < 8; ++mf)
#pragma unroll
            for (int nf = 0; nf < 4; ++nf)
                acc[mf][nf] = __builtin_amdgcn_mfma_f32_16x16x32_bf16(
                    af[mf], bf[nf], acc[mf][nf], 0, 0, 0);
        __builtin_amdgcn_s_setprio(0);
        __syncthreads();
        cur ^= 1;
    }

    ushort* eb = &lds[0][0][0] + w * 4096;
#pragma unroll
    for (int h = 0; h < 2; ++h) {
#pragma unroll
        for (int mf2 = 0; mf2 < 4; ++mf2)
#pragma unroll
            for (int r = 0; r < 4; ++r)
#pragma unroll
                for (int nf = 0; nf < 4; ++nf) {
                    const int rl = mf2 * 16 + lg * 4 + r;
                    const int cl = nf * 16 + lq;
                    eb[rl * 64 + cl] = f2bf(acc[h * 4 + mf2][nf][r]);
                }
#pragma unroll
        for (int p = 0; p < 8; ++p) {
            const int rl = p * 8 + (l >> 3);
            const int cl = (l & 7) * 8;
            const uint4 v = *(const uint4*)&eb[rl * 64 + cl];
            const size_t row = bm + wrow + h * 64 + rl;
            const size_t col = bo + wcol + cl;
            if (EPI == 1) {
                *(uint4*)(Cp + row * ldc + col) = v;
            } else {
                const uint4 uv = *(const uint4*)(U + row * ldc + col);
                union { uint4 v; ushort u[8]; } g, uu, o;
                g.v = v; uu.v = uv;
#pragma unroll
                for (int e = 0; e < 8; ++e) {
                    const float gf = bf2f(g.u[e]);
                    o.u[e] = f2bf(gf / (1.0f + __expf(-gf)) * bf2f(uu.u[e]));
                }
                *(uint4*)(Cp + row * ldc + col) = o.v;
            }
        }
    }
}

// Sum split-K partials (8 x NTOK x 120) + bias (cols 0..111) -> C [NTOK][120].
__global__ __launch_bounds__(256) void splitk_reduce_kernel(
    const float* __restrict__ part, const float* __restrict__ bias,
    float* __restrict__ C, int nz)
{
    const int idx = blockIdx.x * 256 + threadIdx.x;
    const int col = idx % 120;
    float s = (col < 112) ? bias[col] : 0.0f;
    for (int z = 0; z < nz; ++z) s += part[(size_t)z * NTOK * 120 + idx];
    C[idx] = s;
}

// ---------------------------------------------------------------------------
// RoPE: read q,k f32, write bf16 Qb (scaled by 1/8) and Kb. pos = token & 2047.
// ---------------------------------------------------------------------------
__global__ __launch_bounds__(256) void rope_bf16_kernel(
    const float* __restrict__ q, const float* __restrict__ k,
    ushort* __restrict__ Qb, ushort* __restrict__ Kb)
{
    const int idx = blockIdx.x * 256 + threadIdx.x;   // < NTOK*512
    const int i  = idx & 31;
    const int nh = (idx >> 5) & 15;
    const int t  = idx >> 9;
    const int pos = t & 2047;
    const float inv = expf(-(float)i * (9.210340371976184f / 32.0f));
    float s, c;
    sincosf((float)pos * inv, &s, &c);
    const size_t base = (size_t)t * 1024 + nh * 64 + i;
    const float q1 = q[base], q2 = q[base + 32];
    Qb[base]      = f2bf((q1 * c - q2 * s) * 0.125f);
    Qb[base + 32] = f2bf((q2 * c + q1 * s) * 0.125f);
    const float k1 = k[base], k2 = k[base + 32];
    Kb[base]      = f2bf(k1 * c - k2 * s);
    Kb[base + 32] = f2bf(k2 * c + k1 * s);
}

// ---------------------------------------------------------------------------
// MFMA flash attention, bf16, KVBLK=128 (two 64-wide halves), LDS-staged K/V
// double-buffered prefetch, balanced q-tile pairs {31-bx, bx}.
// Grid (16, 32 b*h). Block = 256 thr = 4 waves, each owning 16 q-rows.
// ---------------------------------------------------------------------------
__global__ __launch_bounds__(256) void attn_mfma_kernel(
    const ushort* __restrict__ Qb, const ushort* __restrict__ Kb,
    const ushort* __restrict__ Vt, ushort* __restrict__ atno)
{
    __shared__ ushort Ks[2][2][64 * 64];   // [buf][half][tok][d]
    __shared__ ushort Vs[2][2][64 * 64];   // [buf][half][d][tok]
    const int bh = blockIdx.y;
    const int b = bh >> 4, h = bh & 15;
    const int w = threadIdx.x >> 6, l = threadIdx.x & 63;
    const int g = l >> 4, t = l & 15;
    const int tok0 = b * 2048;
    const int hoff = h * 64;

    const int srow = w * 16 + (l >> 3);
    const int schunk = (l & 7) ^ (l >> 3);
    const ushort* Kg = Kb + (size_t)(tok0 + srow) * 1024 + hoff + schunk * 8;
    const ushort* Vg = Vt + (size_t)(hoff + srow) * NTOK + tok0 + schunk * 8;
    const int ldsbase = w * 1024;

    const int srcA = ((g & 1) * 2) * 16 + t;
    const int srcB = srcA + 16;
    const bool hiSel = (g >> 1) != 0;

    int buf = 0;
    for (int pass = 0; pass < 2; ++pass) {
        const int qb = pass == 0 ? (31 - blockIdx.x) : blockIdx.x;
        const int qrow = tok0 + qb * 64 + w * 16 + t;
        const int qabs = qb * 64 + w * 16 + t;   // within batch
        const int nt = (qb + 2) >> 1;            // 128-wide tiles

        short8_t qf[2];
#pragma unroll
        for (int ks = 0; ks < 2; ++ks)
            qf[ks] = *(const short8_t*)(Qb + (size_t)qrow * 1024 + hoff + ks * 32 + g * 8);

        float m_run = -3.0e38f, l_run = 0.0f;
        f32x4 oacc[4];
#pragma unroll
        for (int nf = 0; nf < 4; ++nf) oacc[nf] = (f32x4){0.f, 0.f, 0.f, 0.f};

        // prologue: stage tile 0 (both halves)
#pragma unroll
        for (int hf = 0; hf < 2; ++hf)
#pragma unroll
            for (int i = 0; i < 2; ++i) {
                gload_lds16(Kg + (size_t)(hf * 64 + i * 8) * 1024, &Ks[buf][hf][ldsbase + i * 512]);
                gload_lds16(Vg + hf * 64 + (size_t)(i * 8) * NTOK, &Vs[buf][hf][ldsbase + i * 512]);
            }
        __syncthreads();

        for (int kt = 0; kt < nt; ++kt) {
            if (kt + 1 < nt) {
                const int nk = (kt + 1) * 128;
#pragma unroll
                for (int hf = 0; hf < 2; ++hf)
#pragma unroll
                    for (int i = 0; i < 2; ++i) {
                        gload_lds16(Kg + (size_t)(nk + hf * 64 + i * 8) * 1024, &Ks[buf ^ 1][hf][ldsbase + i * 512]);
                        gload_lds16(Vg + nk + hf * 64 + (size_t)(i * 8) * NTOK, &Vs[buf ^ 1][hf][ldsbase + i * 512]);
                    }
            }
            // QK^T over 128 keys (two halves)
            f32x4 sa[2][4];
#pragma unroll
            for (int hf = 0; hf < 2; ++hf)
#pragma unroll
                for (int mf = 0; mf < 4; ++mf) sa[hf][mf] = (f32x4){0.f, 0.f, 0.f, 0.f};
            __builtin_amdgcn_s_setprio(1);
#pragma unroll
            for (int hf = 0; hf < 2; ++hf)
#pragma unroll
                for (int ks = 0; ks < 2; ++ks) {
                    const int jc = ks * 4 + g;
#pragma unroll
                    for (int mf = 0; mf < 4; ++mf) {
                        const short8_t kf = *(const short8_t*)&Ks[buf][hf][(mf * 16 + t) * 64 + ((jc ^ (t & 7)) * 8)];
                        sa[hf][mf] = __builtin_amdgcn_mfma_f32_16x16x32_bf16(kf, qf[ks], sa[hf][mf], 0, 0, 0);
                    }
                }
            __builtin_amdgcn_s_setprio(0);

            float p[2][4][4];
            float mloc = -3.0e38f;
            const bool lastTile = (kt == nt - 1);
#pragma unroll
            for (int hf = 0; hf < 2; ++hf)
#pragma unroll
                for (int mf = 0; mf < 4; ++mf)
#pragma unroll
                    for (int r = 0; r < 4; ++r) {
                        float s = sa[hf][mf][r];
                        if (lastTile && (kt * 128 + hf * 64 + mf * 16 + g * 4 + r) > qabs) s = -3.0e38f;
                        p[hf][mf][r] = s;
                        mloc = fmaxf(mloc, s);
                    }
            mloc = fmaxf(mloc, __shfl_xor(mloc, 16));
            mloc = fmaxf(mloc, __shfl_xor(mloc, 32));
            const float mnew = fmaxf(m_run, mloc);
            float lsum = 0.f;
#pragma unroll
            for (int hf = 0; hf < 2; ++hf)
#pragma unroll
                for (int mf = 0; mf < 4; ++mf)
#pragma unroll
                    for (int r = 0; r < 4; ++r) {
                        const float e = __expf(p[hf][mf][r] - mnew);
                        p[hf][mf][r] = e;
                        lsum += e;
                    }
            lsum += __shfl_xor(lsum, 16);
            lsum += __shfl_xor(lsum, 32);
            const float fac = __expf(m_run - mnew);
            l_run = l_run * fac + lsum;
            m_run = mnew;
#pragma unroll
            for (int r = 0; r < 4; ++r) {
                const float fr = __shfl(fac, g * 4 + r);
#pragma unroll
                for (int nf = 0; nf < 4; ++nf) oacc[nf][r] *= fr;
            }
            // PV per half
#pragma unroll
            for (int hf = 0; hf < 2; ++hf) {
                uint32_t pk[4][2];
#pragma unroll
                for (int mf = 0; mf < 4; ++mf) {
                    pk[mf][0] = pack2(p[hf][mf][0], p[hf][mf][1]);
                    pk[mf][1] = pack2(p[hf][mf][2], p[hf][mf][3]);
                }
#pragma unroll
                for (int ks = 0; ks < 2; ++ks) {
                    const uint32_t a00 = __shfl(pk[2 * ks][0], srcA);
                    const uint32_t a01 = __shfl(pk[2 * ks][1], srcA);
                    const uint32_t a10 = __shfl(pk[2 * ks + 1][0], srcA);
                    const uint32_t a11 = __shfl(pk[2 * ks + 1][1], srcA);
                    const uint32_t b00 = __shfl(pk[2 * ks][0], srcB);
                    const uint32_t b01 = __shfl(pk[2 * ks][1], srcB);
                    const uint32_t b10 = __shfl(pk[2 * ks + 1][0], srcB);
                    const uint32_t b11 = __shfl(pk[2 * ks + 1][1], srcB);
                    union { uint32_t u[4]; short8_t v; } pa;
                    pa.u[0] = hiSel ? a10 : a00;
                    pa.u[1] = hiSel ? a11 : a01;
                    pa.u[2] = hiSel ? b10 : b00;
                    pa.u[3] = hiSel ? b11 : b01;
                    const int jc = ks * 4 + g;
                    __builtin_amdgcn_s_setprio(1);
#pragma unroll
                    for (int nf = 0; nf < 4; ++nf) {
                        const short8_t vf = *(const short8_t*)&Vs[buf][hf][(nf * 16 + t) * 64 + ((jc ^ (t & 7)) * 8)];
                        oacc[nf] = __builtin_amdgcn_mfma_f32_16x16x32_bf16(pa.v, vf, oacc[nf], 0, 0, 0);
                    }
                    __builtin_amdgcn_s_setprio(0);
                }
            }
            __syncthreads();   // prefetch resident + all reads of buf done
            buf ^= 1;
        }
        const float inv = 1.0f / l_run;
#pragma unroll
        for (int r = 0; r < 4; ++r) {
            const float ir = __shfl(inv, g * 4 + r);
            const int orow = tok0 + qb * 64 + w * 16 + g * 4 + r;
#pragma unroll
            for (int nf = 0; nf < 4; ++nf)
                atno[(size_t)orow * 1024 + hoff + nf * 16 + t] = f2bf(oacc[nf][r] * ir);
        }
    }
}

// ---------------------------------------------------------------------------
// rat_write: fused du-projection (K=8) + softplus + SSM update. f32.
// od [N][1024]; ab [N][120] (0..111 = A_B, 112..119 = delta_low).
// ---------------------------------------------------------------------------
__global__ __launch_bounds__(256) void rat_write_kernel(
    const float* res, const float* __restrict__ od,
    const float* __restrict__ ab, const float* __restrict__ du_w,
    const float* __restrict__ du_b, float* out)
{
    const int t = blockIdx.x;
    const int tid = threadIdx.x;
    __shared__ float sAB[112];
    __shared__ float sdl[8];
    if (tid < 112) sAB[tid] = ab[(size_t)t * 120 + tid];
    if (tid >= 128 && tid < 136) sdl[tid - 128] = ab[(size_t)t * 120 + 112 + (tid - 128)];
    __syncthreads();
    const float* rp = res + (size_t)t * 4096;
    const float* odp = od + (size_t)t * 1024;
    float* op = out + (size_t)t * 4096;
#pragma unroll
    for (int ii = 0; ii < 4; ++ii) {
        const int hh = tid + 256 * ii;
        const int rh = hh & 15;
        const float4 w0 = *(const float4*)(du_w + hh * 8);
        const float4 w1 = *(const float4*)(du_w + hh * 8 + 4);
        float dacc = du_b[hh];
        dacc += sdl[0] * w0.x + sdl[1] * w0.y + sdl[2] * w0.z + sdl[3] * w0.w;
        dacc += sdl[4] * w1.x + sdl[5] * w1.y + sdl[6] * w1.z + sdl[7] * w1.w;
        const float delta = softplus_f(dacc);
        const float oh = odp[hh];
        const float4 hs = *(const float4*)(rp + hh * 4);
        const float r4[4] = {hs.x, hs.y, hs.z, hs.w};
        float o4[4];
#pragma unroll
        for (int c = 0; c < 3; ++c) {
            const float Aneg = -softplus_f(sAB[rh * 3 + c]);
            const float Abar = expf(delta * Aneg);
            const float Bbar = (Abar - 1.0f) / (Aneg - 1e-5f) * sAB[48 + rh * 3 + c];
            o4[c] = r4[c] * Abar + oh * Bbar;
        }
        o4[3] = r4[3] + oh * (delta * sAB[96 + rh]);
        *(float4*)(op + hh * 4) = make_float4(o4[0], o4[1], o4[2], o4[3]);
    }
}

// ---------------------------------------------------------------------------
extern "C" void kernel_launch(void* const* d_in, const int* in_sizes, int n_in,
                              void* d_out, int out_size, void* d_ws, size_t ws_size,
                              hipStream_t stream)
{
    const float* hidden      = (const float*)d_in[0];
    const float* attn_read_w = (const float*)d_in[2];
    const float* attn_read_g = (const float*)d_in[3];
    const float* attn_read_b = (const float*)d_in[4];
    const float* qkv_w       = (const float*)d_in[5];
    const float* attn_wod_w  = (const float*)d_in[6];
    const float* attn_wab_w  = (const float*)d_in[7];
    const float* attn_wab_b  = (const float*)d_in[8];
    const float* attn_du_w   = (const float*)d_in[9];
    const float* attn_du_b   = (const float*)d_in[10];
    const float* mlp_read_w  = (const float*)d_in[11];
    const float* mlp_read_g  = (const float*)d_in[12];
    const float* mlp_read_b  = (const float*)d_in[13];
    const float* mlp_in_w    = (const float*)d_in[14];
    const float* mlp_wod_w   = (const float*)d_in[15];
    const float* mlp_wab_w   = (const float*)d_in[16];
    const float* mlp_wab_b   = (const float*)d_in[17];
    const float* mlp_du_w    = (const float*)d_in[18];
    const float* mlp_du_b    = (const float*)d_in[19];
    float* out = (float*)d_out;
    char* wsb = (char*)d_ws;
    const size_t N = NTOK;

    // ---- workspace layout (bytes) ----
    ushort* qkv_wb  = (ushort*)(wsb + 0);          // 3*1024*1024           -> 6291456
    ushort* wodA_b  = (ushort*)(wsb + 6291456);    // 1024*1024             -> 8388608
    ushort* sabA_b  = (ushort*)(wsb + 8388608);    // 128*1024              -> 8650752
    ushort* mlpin_b = (ushort*)(wsb + 8650752);    // 2*4096*1024           -> 25427968
    ushort* wodM_b  = (ushort*)(wsb + 25427968);   // 1024*4096             -> 33816576
    ushort* sabM_b  = (ushort*)(wsb + 33816576);   // 128*4096              -> 34865152
    char* R1 = wsb + 34865152;                     // 25165824 B
    char* R2 = wsb + 60030976;                     // 67108864 B -> ends 127139840
    // R1 (attn): qkv_in [N*3072]b = whole region; after qkv GEMMs: Qb, Kb.
    ushort* qkv_in = (ushort*)R1;
    ushort* Qb     = (ushort*)R1;                  // [N*1024] bf16
    ushort* Kb     = (ushort*)(R1 + 8388608);      // [N*1024] bf16
    // R1 (mlp): mlp_in [N*2048]b; later od_m f32 [N*1024], ab_m f32 [N*120]
    ushort* mlp_in = (ushort*)R1;
    float*  od_m   = (float*)R1;
    float*  ab_m   = (float*)(R1 + 16777216);
    // R2 (attn): q_ f32, k_ f32, Vt; later atno, od_a, ab_a, skpA
    float*  q_     = (float*)R2;                   // [N*1024] f32
    float*  k_     = (float*)(R2 + 16777216);      // [N*1024] f32
    ushort* Vt     = (ushort*)(R2 + 33554432);     // [1024][N] bf16 -> 41943040
    ushort* atno   = (ushort*)R2;                  // [N*1024] bf16 (after rope)
    float*  od_a   = (float*)(R2 + 8388608);       // [N*1024] f32 -> 25165824
    float*  ab_a   = (float*)(R2 + 25165824);      // [N*120] f32  -> 27131904
    float*  skpA   = (float*)(R2 + 27131904);      // [8*N*120] f32 -> 42860544
    // R2 (mlp): up_, upb, skpM
    ushort* up_    = (ushort*)R2;                  // [N*4096] bf16
    ushort* upb    = (ushort*)(R2 + 33554432);     // [N*4096] bf16
    float*  skpM   = (float*)R2;                   // [8*N*120] f32 (after up_ dead)

    // ---- weight conversion ----
    convert_flat_kernel<<<1536, 256, 0, stream>>>(qkv_w, qkv_wb);
    convert_flat_kernel<<<4096, 256, 0, stream>>>(mlp_in_w, mlpin_b);
    convert_flat_kernel<<<512, 256, 0, stream>>>(attn_wod_w, wodA_b);    // rows 0..1023
    convert_flat_kernel<<<2048, 256, 0, stream>>>(mlp_wod_w, wodM_b);    // rows 0..1023
    build_small_kernel<<<64, 256, 0, stream>>>(attn_wab_w, attn_wod_w, sabA_b, 1024);
    build_small_kernel<<<256, 256, 0, stream>>>(mlp_wab_w, mlp_wod_w, sabM_b, 4096);

    // ---- attention half ----
    rat_read_kernel<3><<<N, 256, 0, stream>>>(hidden, attn_read_w, attn_read_g, attn_read_b, qkv_in);

    mfma_gemm_kernel<0><<<dim3(32, 8), 256, 0, stream>>>(qkv_in, 3072, qkv_wb, 1024, q_, 1024, 1024, nullptr, 1024);
    mfma_gemm_kernel<0><<<dim3(32, 8), 256, 0, stream>>>(qkv_in + 1024, 3072, qkv_wb + 1048576, 1024, k_, 1024, 1024, nullptr, 1024);
    mfma_gemm_kernel<3><<<dim3(32, 8), 256, 0, stream>>>(qkv_in + 2048, 3072, qkv_wb + 2097152, 1024, Vt, NTOK, 1024, nullptr, 1024);

    rope_bf16_kernel<<<8192, 256, 0, stream>>>(q_, k_, Qb, Kb);

    attn_mfma_kernel<<<dim3(16, 32), 256, 0, stream>>>(Qb, Kb, Vt, atno);

    mfma_gemm_kernel<0><<<dim3(32, 8), 256, 0, stream>>>(atno, 1024, wodA_b, 1024, od_a, 1024, 1024, nullptr, 1024);
    mfma_gemm_kernel<0><<<dim3(32, 1, 8), 256, 0, stream>>>(atno, 1024, sabA_b, 1024, skpA, 120, 120, nullptr, 128);
    splitk_reduce_kernel<<<1920, 256, 0, stream>>>(skpA, attn_wab_b, ab_a, 8);

    rat_write_kernel<<<N, 256, 0, stream>>>(hidden, od_a, ab_a, attn_du_w, attn_du_b, out);

    // ---- MLP half ----
    rat_read_kernel<2><<<N, 256, 0, stream>>>(out, mlp_read_w, mlp_read_g, mlp_read_b, mlp_in);

    gemm256_kernel<1><<<dim3(16, 16), 512, 0, stream>>>(mlp_in + 1024, 2048, mlpin_b + 4194304, 1024, up_, 4096, nullptr, 1024);
    gemm256_kernel<2><<<dim3(16, 16), 512, 0, stream>>>(mlp_in, 2048, mlpin_b, 1024, upb, 4096, up_, 1024);

    mfma_gemm_kernel<0><<<dim3(32, 8), 256, 0, stream>>>(upb, 4096, wodM_b, 4096, od_m, 1024, 1024, nullptr, 4096);
    mfma_gemm_kernel<0><<<dim3(32, 1, 8), 256, 0, stream>>>(upb, 4096, sabM_b, 4096, skpM, 120, 120, nullptr, 512);
    splitk_reduce_kernel<<<1920, 256, 0, stream>>>(skpM, mlp_wab_b, ab_m, 8);

    rat_write_kernel<<<N, 256, 0, stream>>>(out, od_m, ab_m, mlp_du_w, mlp_du_b, out);
}

// Round 7
// 496.775 us; speedup vs baseline: 7.2275x; 1.0823x over previous
//
#include <hip/hip_runtime.h>
#include <math.h>
#include <stdint.h>

// ---------------------------------------------------------------------------
// RatLayer forward. bf16 MFMA GEMMs, 2-phase global_load_lds pipelines,
// fused qkv (grid.z=3), merged wod+wab split-K GEMMs with reduction folded
// into rat_write, KVBLK=128 flash attention.
// H=1024 C=4 RH=16 HS=64 DR=8 M=4096 NH=16 HD=64 A_SIZE=48 B_SIZE=64
// ---------------------------------------------------------------------------

constexpr int NTOK = 4096;

typedef __attribute__((ext_vector_type(8))) short short8_t;
typedef __attribute__((ext_vector_type(4))) float f32x4;

__device__ __forceinline__ ushort f2bf(float f) {
    union { float f; uint32_t u; } v; v.f = f;
    uint32_t r = v.u + 0x7fffu + ((v.u >> 16) & 1u);
    return (ushort)(r >> 16);
}
__device__ __forceinline__ float bf2f(ushort b) {
    union { uint32_t u; float f; } v; v.u = ((uint32_t)b) << 16;
    return v.f;
}
__device__ __forceinline__ uint32_t pack2(float lo, float hi) {
    return (uint32_t)f2bf(lo) | ((uint32_t)f2bf(hi) << 16);
}
__device__ __forceinline__ float softplus_f(float x) {
    return (x > 20.0f) ? x : log1pf(expf(x));
}

__device__ __forceinline__ void gload_lds16(const void* g, void* l) {
    __builtin_amdgcn_global_load_lds(
        (const __attribute__((address_space(1))) uint32_t*)g,
        (__attribute__((address_space(3))) uint32_t*)l,
        16, 0, 0);
}

// ---------------------------------------------------------------------------
// Weight conversion f32 -> bf16.
// ---------------------------------------------------------------------------
__global__ __launch_bounds__(256) void convert_flat_kernel(
    const float* __restrict__ src, ushort* __restrict__ dst)
{
    const size_t i = ((size_t)blockIdx.x * 256 + threadIdx.x) * 8;
    const float4 a = *(const float4*)(src + i);
    const float4 b = *(const float4*)(src + i + 4);
    union { ushort u[8]; uint4 v; } o;
    o.u[0] = f2bf(a.x); o.u[1] = f2bf(a.y); o.u[2] = f2bf(a.z); o.u[3] = f2bf(a.w);
    o.u[4] = f2bf(b.x); o.u[5] = f2bf(b.y); o.u[6] = f2bf(b.z); o.u[7] = f2bf(b.w);
    *(uint4*)(dst + i) = o.v;
}

// combined weight [1152][K]: rows 0..1023 = wod[0..1023]; 1024..1135 = wab;
// 1136..1143 = wod rows 1024..1031 (delta_low); 1144..1151 = zero.
__global__ __launch_bounds__(256) void build_comb_kernel(
    const float* __restrict__ wod, const float* __restrict__ wab,
    ushort* __restrict__ dst, int K)
{
    const size_t i = ((size_t)blockIdx.x * 256 + threadIdx.x) * 8;
    const int row = (int)(i / (size_t)K);
    const int col = (int)(i % (size_t)K);
    const float* src = nullptr;
    if (row < 1024)      src = wod + (size_t)row * K + col;
    else if (row < 1136) src = wab + (size_t)(row - 1024) * K + col;
    else if (row < 1144) src = wod + (size_t)(1024 + row - 1136) * K + col;
    union { ushort u[8]; uint4 v; } o;
    if (src) {
        const float4 a = *(const float4*)(src);
        const float4 b = *(const float4*)(src + 4);
        o.u[0] = f2bf(a.x); o.u[1] = f2bf(a.y); o.u[2] = f2bf(a.z); o.u[3] = f2bf(a.w);
        o.u[4] = f2bf(b.x); o.u[5] = f2bf(b.y); o.u[6] = f2bf(b.z); o.u[7] = f2bf(b.w);
    } else {
        o.v = make_uint4(0, 0, 0, 0);
    }
    *(uint4*)(dst + i) = o.v;
}

// ---------------------------------------------------------------------------
// rat_read: mix + LayerNorm + affine; writes bf16. One block per token.
// ---------------------------------------------------------------------------
template <int NO>
__global__ __launch_bounds__(256) void rat_read_kernel(
    const float* __restrict__ res, const float* __restrict__ W,
    const float* __restrict__ gamma, const float* __restrict__ beta,
    ushort* __restrict__ out)
{
    const int t = blockIdx.x;
    const int tid = threadIdx.x;
    const float* rp = res + (size_t)t * 4096;
    float y[4][NO];
#pragma unroll
    for (int i = 0; i < 4; ++i) {
        const int h = tid + 256 * i;
        const float4 x = *(const float4*)(rp + h * 4);
#pragma unroll
        for (int o = 0; o < NO; ++o) {
            const float4 w = *(const float4*)(W + ((size_t)h * NO + o) * 4);
            y[i][o] = x.x * w.x + x.y * w.y + x.z * w.z + x.w * w.w;
        }
    }
    __shared__ float red[4][NO][2];
    const int lane = tid & 63, wid = tid >> 6;
#pragma unroll
    for (int o = 0; o < NO; ++o) {
        float s = 0.f, ss = 0.f;
#pragma unroll
        for (int i = 0; i < 4; ++i) { s += y[i][o]; ss += y[i][o] * y[i][o]; }
        for (int off = 32; off > 0; off >>= 1) {
            s += __shfl_down(s, off);
            ss += __shfl_down(ss, off);
        }
        if (lane == 0) { red[wid][o][0] = s; red[wid][o][1] = ss; }
    }
    __syncthreads();
    float mu[NO], rs[NO];
#pragma unroll
    for (int o = 0; o < NO; ++o) {
        const float s  = red[0][o][0] + red[1][o][0] + red[2][o][0] + red[3][o][0];
        const float ss = red[0][o][1] + red[1][o][1] + red[2][o][1] + red[3][o][1];
        const float m = s * (1.0f / 1024.0f);
        const float v = ss * (1.0f / 1024.0f) - m * m;
        mu[o] = m;
        rs[o] = rsqrtf(v + 1e-5f);
    }
    ushort* op = out + (size_t)t * (NO * 1024);
#pragma unroll
    for (int i = 0; i < 4; ++i) {
        const int h = tid + 256 * i;
#pragma unroll
        for (int o = 0; o < NO; ++o) {
            op[o * 1024 + h] = f2bf((y[i][o] - mu[o]) * rs[o] * gamma[o * 1024 + h] + beta[o * 1024 + h]);
        }
    }
}

// ---------------------------------------------------------------------------
// bf16 MFMA GEMM, 128x128 tile, BK=64, 2-phase pipelined (global_load_lds).
// EPI: 0 f32 (+z partials, col<O guard), 1 bf16, 2 silu*U bf16, 3 transposed.
// ---------------------------------------------------------------------------
__device__ __forceinline__ void stage_tile(
    ushort* AsB, ushort* BsB, const ushort* Ag, const ushort* Wg,
    size_t lda8, size_t ldw8, int w, int kofs)
{
#pragma unroll
    for (int i = 0; i < 4; ++i) {
        gload_lds16(Ag + kofs + i * lda8, AsB + (w * 4 + i) * 512);
        gload_lds16(Wg + kofs + i * ldw8, BsB + (w * 4 + i) * 512);
    }
}

template <int EPI>
__global__ __launch_bounds__(256) void mfma_gemm_kernel(
    const ushort* __restrict__ A, int lda,
    const ushort* __restrict__ W, int ldw,
    void* __restrict__ Cp, int ldc, int O,
    const ushort* __restrict__ U,
    int Kblk)
{
    __shared__ ushort As[2][128 * 64];
    __shared__ ushort Bs[2][128 * 64];
    const int tid = threadIdx.x;
    const int nwg = gridDim.x * gridDim.y;
    const int gy = gridDim.y;
    const int id = blockIdx.y * gridDim.x + blockIdx.x;
    const int swz = (id & 7) * (nwg >> 3) + (id >> 3);
    const int bm = (swz / gy) * 128;
    const int bo = (swz % gy) * 128;

    const int w = tid >> 6, l = tid & 63;
    const int lq = l & 15, lg = l >> 4;
    const int wr = (w >> 1) * 64, wc = (w & 1) * 64;

    f32x4 acc[4][4];
#pragma unroll
    for (int i = 0; i < 4; ++i)
#pragma unroll
        for (int j = 0; j < 4; ++j) acc[i][j] = (f32x4){0.f, 0.f, 0.f, 0.f};

    const int srow = 32 * w + (l >> 3);
    const int skc  = ((l & 7) ^ (l >> 3)) * 8;
    const ushort* Ag = A + (size_t)(bm + srow) * lda + (size_t)blockIdx.z * Kblk + skc;
    const ushort* Wg = W + (size_t)(bo + srow) * ldw + (size_t)blockIdx.z * Kblk + skc;
    const size_t lda8 = (size_t)8 * lda, ldw8 = (size_t)8 * ldw;

    const int nt = Kblk >> 6;
    stage_tile(As[0], Bs[0], Ag, Wg, lda8, ldw8, w, 0);
    __syncthreads();
    int cur = 0;
    for (int t = 0; t < nt; ++t) {
        if (t + 1 < nt)
            stage_tile(As[cur ^ 1], Bs[cur ^ 1], Ag, Wg, lda8, ldw8, w, (t + 1) * 64);
#pragma unroll
        for (int ks = 0; ks < 2; ++ks) {
            short8_t af[4], bf[4];
            const int jc = ks * 4 + lg;
#pragma unroll
            for (int mf = 0; mf < 4; ++mf) {
                const int ra = wr + mf * 16 + lq;
                af[mf] = *(const short8_t*)&As[cur][ra * 64 + ((jc ^ (ra & 7)) * 8)];
                const int rb = wc + mf * 16 + lq;
                bf[mf] = *(const short8_t*)&Bs[cur][rb * 64 + ((jc ^ (rb & 7)) * 8)];
            }
#pragma unroll
            for (int mf = 0; mf < 4; ++mf)
#pragma unroll
                for (int nf = 0; nf < 4; ++nf)
                    acc[mf][nf] = __builtin_amdgcn_mfma_f32_16x16x32_bf16(
                        af[mf], bf[nf], acc[mf][nf], 0, 0, 0);
        }
        __syncthreads();
        cur ^= 1;
    }

    if (EPI == 0) {
#pragma unroll
        for (int mf = 0; mf < 4; ++mf)
#pragma unroll
            for (int r = 0; r < 4; ++r) {
                const int row = bm + wr + mf * 16 + lg * 4 + r;
#pragma unroll
                for (int nf = 0; nf < 4; ++nf) {
                    const int col = bo + wc + nf * 16 + lq;
                    if (col < O)
                        ((float*)Cp)[(size_t)blockIdx.z * NTOK * ldc + (size_t)row * ldc + col] = acc[mf][nf][r];
                }
            }
    } else {
        ushort* eb = &As[0][0] + w * 4096;
#pragma unroll
        for (int mf = 0; mf < 4; ++mf)
#pragma unroll
            for (int r = 0; r < 4; ++r)
#pragma unroll
                for (int nf = 0; nf < 4; ++nf) {
                    const int rl = mf * 16 + lg * 4 + r;
                    const int cl = nf * 16 + lq;
                    if (EPI == 3) eb[cl * 64 + rl] = f2bf(acc[mf][nf][r]);
                    else          eb[rl * 64 + cl] = f2bf(acc[mf][nf][r]);
                }
#pragma unroll
        for (int p = 0; p < 8; ++p) {
            const int rl = p * 8 + (l >> 3);
            const int cl = (l & 7) * 8;
            uint4 v = *(const uint4*)&eb[rl * 64 + cl];
            if (EPI == 1) {
                *(uint4*)((ushort*)Cp + (size_t)(bm + wr + rl) * ldc + bo + wc + cl) = v;
            } else if (EPI == 2) {
                const ushort* up = U + (size_t)(bm + wr + rl) * ldc + bo + wc + cl;
                const uint4 uv = *(const uint4*)up;
                union { uint4 v; ushort u[8]; } g, uu, o;
                g.v = v; uu.v = uv;
#pragma unroll
                for (int e = 0; e < 8; ++e) {
                    const float gf = bf2f(g.u[e]);
                    o.u[e] = f2bf(gf / (1.0f + __expf(-gf)) * bf2f(uu.u[e]));
                }
                *(uint4*)((ushort*)Cp + (size_t)(bm + wr + rl) * ldc + bo + wc + cl) = o.v;
            } else {
                *(uint4*)((ushort*)Cp + (size_t)(bo + wc + rl) * ldc + bm + wr + cl) = v;
            }
        }
    }
}

// ---------------------------------------------------------------------------
// Fused qkv GEMM: grid (32, 8, 3); z selects matrix. A = qkv_in[:, z*1024+..]
// (lda 3072), W = qkv_wb + z*1M. z<2 -> f32 store (q_, k_); z=2 -> transposed
// bf16 store into Vt [1024][NTOK]. Same 2-phase BK=64 pipeline as above.
// ---------------------------------------------------------------------------
__global__ __launch_bounds__(256) void qkv_gemm_kernel(
    const ushort* __restrict__ Ain, const ushort* __restrict__ Wall,
    float* __restrict__ qo, float* __restrict__ ko, ushort* __restrict__ Vt)
{
    __shared__ ushort As[2][128 * 64];
    __shared__ ushort Bs[2][128 * 64];
    const int tid = threadIdx.x;
    const int z = blockIdx.z;
    const int nwg = gridDim.x * gridDim.y;
    const int gy = gridDim.y;
    const int id = blockIdx.y * gridDim.x + blockIdx.x;
    const int swz = (id & 7) * (nwg >> 3) + (id >> 3);
    const int bm = (swz / gy) * 128;
    const int bo = (swz % gy) * 128;

    const int w = tid >> 6, l = tid & 63;
    const int lq = l & 15, lg = l >> 4;
    const int wr = (w >> 1) * 64, wc = (w & 1) * 64;

    f32x4 acc[4][4];
#pragma unroll
    for (int i = 0; i < 4; ++i)
#pragma unroll
        for (int j = 0; j < 4; ++j) acc[i][j] = (f32x4){0.f, 0.f, 0.f, 0.f};

    const int srow = 32 * w + (l >> 3);
    const int skc  = ((l & 7) ^ (l >> 3)) * 8;
    const ushort* Ag = Ain + z * 1024 + (size_t)(bm + srow) * 3072 + skc;
    const ushort* Wg = Wall + (size_t)z * 1048576 + (size_t)(bo + srow) * 1024 + skc;
    const size_t lda8 = (size_t)8 * 3072, ldw8 = (size_t)8 * 1024;

    stage_tile(As[0], Bs[0], Ag, Wg, lda8, ldw8, w, 0);
    __syncthreads();
    int cur = 0;
    for (int t = 0; t < 16; ++t) {
        if (t + 1 < 16)
            stage_tile(As[cur ^ 1], Bs[cur ^ 1], Ag, Wg, lda8, ldw8, w, (t + 1) * 64);
#pragma unroll
        for (int ks = 0; ks < 2; ++ks) {
            short8_t af[4], bf[4];
            const int jc = ks * 4 + lg;
#pragma unroll
            for (int mf = 0; mf < 4; ++mf) {
                const int ra = wr + mf * 16 + lq;
                af[mf] = *(const short8_t*)&As[cur][ra * 64 + ((jc ^ (ra & 7)) * 8)];
                const int rb = wc + mf * 16 + lq;
                bf[mf] = *(const short8_t*)&Bs[cur][rb * 64 + ((jc ^ (rb & 7)) * 8)];
            }
#pragma unroll
            for (int mf = 0; mf < 4; ++mf)
#pragma unroll
                for (int nf = 0; nf < 4; ++nf)
                    acc[mf][nf] = __builtin_amdgcn_mfma_f32_16x16x32_bf16(
                        af[mf], bf[nf], acc[mf][nf], 0, 0, 0);
        }
        __syncthreads();
        cur ^= 1;
    }

    if (z < 2) {
        float* Cp = z ? ko : qo;
#pragma unroll
        for (int mf = 0; mf < 4; ++mf)
#pragma unroll
            for (int r = 0; r < 4; ++r) {
                const int row = bm + wr + mf * 16 + lg * 4 + r;
#pragma unroll
                for (int nf = 0; nf < 4; ++nf) {
                    const int col = bo + wc + nf * 16 + lq;
                    Cp[(size_t)row * 1024 + col] = acc[mf][nf][r];
                }
            }
    } else {
        ushort* eb = &As[0][0] + w * 4096;
#pragma unroll
        for (int mf = 0; mf < 4; ++mf)
#pragma unroll
            for (int r = 0; r < 4; ++r)
#pragma unroll
                for (int nf = 0; nf < 4; ++nf) {
                    const int rl = mf * 16 + lg * 4 + r;
                    const int cl = nf * 16 + lq;
                    eb[cl * 64 + rl] = f2bf(acc[mf][nf][r]);
                }
#pragma unroll
        for (int p = 0; p < 8; ++p) {
            const int rl = p * 8 + (l >> 3);
            const int cl = (l & 7) * 8;
            const uint4 v = *(const uint4*)&eb[rl * 64 + cl];
            *(uint4*)(Vt + (size_t)(bo + wc + rl) * NTOK + bm + wr + cl) = v;
        }
    }
}

// ---------------------------------------------------------------------------
// bf16 MFMA GEMM, 256x256 tile, BK=32, 512 thr = 8 waves (2M x 4N),
// 64KB LDS double-buffered, 2-phase global_load_lds pipeline.
// EPI: 1 bf16 store, 2 silu(acc)*U bf16 store.
// ---------------------------------------------------------------------------
template <int EPI>
__global__ __launch_bounds__(512) void gemm256_kernel(
    const ushort* __restrict__ A, int lda,
    const ushort* __restrict__ W, int ldw,
    ushort* __restrict__ Cp, int ldc,
    const ushort* __restrict__ U, int K)
{
    __shared__ ushort lds[2][2][256 * 32];
    const int tid = threadIdx.x;
    const int nwg = gridDim.x * gridDim.y;
    const int gy = gridDim.y;
    const int id = blockIdx.y * gridDim.x + blockIdx.x;
    const int swz = (id & 7) * (nwg >> 3) + (id >> 3);
    const int bm = (swz / gy) * 256;
    const int bo = (swz % gy) * 256;

    const int w = tid >> 6, l = tid & 63;
    const int lq = l & 15, lg = l >> 4;
    const int wrow = (w >> 2) * 128, wcol = (w & 3) * 64;

    f32x4 acc[8][4];
#pragma unroll
    for (int i = 0; i < 8; ++i)
#pragma unroll
        for (int j = 0; j < 4; ++j) acc[i][j] = (f32x4){0.f, 0.f, 0.f, 0.f};

    const int srow = w * 32 + (l >> 2);
    const int schunk = (l & 3) ^ ((l >> 3) & 3);
    const ushort* Ag = A + (size_t)(bm + srow) * lda + schunk * 8;
    const ushort* Wg = W + (size_t)(bo + srow) * ldw + schunk * 8;
    const size_t lda16 = (size_t)16 * lda, ldw16 = (size_t)16 * ldw;

    const int nt = K >> 5;
    int cur = 0;
#pragma unroll
    for (int i = 0; i < 2; ++i) {
        gload_lds16(Ag + i * lda16, &lds[0][0][(w * 32 + i * 16) * 32]);
        gload_lds16(Wg + i * ldw16, &lds[0][1][(w * 32 + i * 16) * 32]);
    }
    __syncthreads();
    for (int t = 0; t < nt; ++t) {
        if (t + 1 < nt) {
            const int k0 = (t + 1) * 32;
#pragma unroll
            for (int i = 0; i < 2; ++i) {
                gload_lds16(Ag + k0 + i * lda16, &lds[cur ^ 1][0][(w * 32 + i * 16) * 32]);
                gload_lds16(Wg + k0 + i * ldw16, &lds[cur ^ 1][1][(w * 32 + i * 16) * 32]);
            }
        }
        short8_t af[8], bf[4];
#pragma unroll
        for (int mf = 0; mf < 8; ++mf) {
            const int ra = wrow + mf * 16 + lq;
            af[mf] = *(const short8_t*)&lds[cur][0][ra * 32 + ((lg ^ ((ra >> 1) & 3)) * 8)];
        }
#pragma unroll
        for (int nf = 0; nf < 4; ++nf) {
            const int rb = wcol + nf * 16 + lq;
            bf[nf] = *(const short8_t*)&lds[cur][1][rb * 32 + ((lg ^ ((rb >> 1) & 3)) * 8)];
        }
        __builtin_amdgcn_s_setprio(1);
#pragma unroll
        for (int mf = 0; mf < 8; ++mf)
#pragma unroll
            for (int nf = 0; nf < 4; ++nf)
                acc[mf][nf] = __builtin_amdgcn_mfma_f32_16x16x32_bf16(
                    af[mf], bf[nf], acc[mf][nf], 0, 0, 0);
        __builtin_amdgcn_s_setprio(0);
        __syncthreads();
        cur ^= 1;
    }

    ushort* eb = &lds[0][0][0] + w * 4096;
#pragma unroll
    for (int h = 0; h < 2; ++h) {
#pragma unroll
        for (int mf2 = 0; mf2 < 4; ++mf2)
#pragma unroll
            for (int r = 0; r < 4; ++r)
#pragma unroll
                for (int nf = 0; nf < 4; ++nf) {
                    const int rl = mf2 * 16 + lg * 4 + r;
                    const int cl = nf * 16 + lq;
                    eb[rl * 64 + cl] = f2bf(acc[h * 4 + mf2][nf][r]);
                }
#pragma unroll
        for (int p = 0; p < 8; ++p) {
            const int rl = p * 8 + (l >> 3);
            const int cl = (l & 7) * 8;
            const uint4 v = *(const uint4*)&eb[rl * 64 + cl];
            const size_t row = bm + wrow + h * 64 + rl;
            const size_t col = bo + wcol + cl;
            if (EPI == 1) {
                *(uint4*)(Cp + row * ldc + col) = v;
            } else {
                const uint4 uv = *(const uint4*)(U + row * ldc + col);
                union { uint4 v; ushort u[8]; } g, uu, o;
                g.v = v; uu.v = uv;
#pragma unroll
                for (int e = 0; e < 8; ++e) {
                    const float gf = bf2f(g.u[e]);
                    o.u[e] = f2bf(gf / (1.0f + __expf(-gf)) * bf2f(uu.u[e]));
                }
                *(uint4*)(Cp + row * ldc + col) = o.v;
            }
        }
    }
}

// ---------------------------------------------------------------------------
// RoPE: read q,k f32, write bf16 Qb (scaled by 1/8) and Kb. pos = token & 2047.
// ---------------------------------------------------------------------------
__global__ __launch_bounds__(256) void rope_bf16_kernel(
    const float* __restrict__ q, const float* __restrict__ k,
    ushort* __restrict__ Qb, ushort* __restrict__ Kb)
{
    const int idx = blockIdx.x * 256 + threadIdx.x;
    const int i  = idx & 31;
    const int nh = (idx >> 5) & 15;
    const int t  = idx >> 9;
    const int pos = t & 2047;
    const float inv = expf(-(float)i * (9.210340371976184f / 32.0f));
    float s, c;
    sincosf((float)pos * inv, &s, &c);
    const size_t base = (size_t)t * 1024 + nh * 64 + i;
    const float q1 = q[base], q2 = q[base + 32];
    Qb[base]      = f2bf((q1 * c - q2 * s) * 0.125f);
    Qb[base + 32] = f2bf((q2 * c + q1 * s) * 0.125f);
    const float k1 = k[base], k2 = k[base + 32];
    Kb[base]      = f2bf(k1 * c - k2 * s);
    Kb[base + 32] = f2bf(k2 * c + k1 * s);
}

// ---------------------------------------------------------------------------
// MFMA flash attention, bf16, KVBLK=128, LDS-staged double-buffered prefetch,
// balanced q-tile pairs {31-bx, bx}. Grid (16, 32).
// ---------------------------------------------------------------------------
__global__ __launch_bounds__(256) void attn_mfma_kernel(
    const ushort* __restrict__ Qb, const ushort* __restrict__ Kb,
    const ushort* __restrict__ Vt, ushort* __restrict__ atno)
{
    __shared__ ushort Ks[2][2][64 * 64];
    __shared__ ushort Vs[2][2][64 * 64];
    const int bh = blockIdx.y;
    const int b = bh >> 4, h = bh & 15;
    const int w = threadIdx.x >> 6, l = threadIdx.x & 63;
    const int g = l >> 4, t = l & 15;
    const int tok0 = b * 2048;
    const int hoff = h * 64;

    const int srow = w * 16 + (l >> 3);
    const int schunk = (l & 7) ^ (l >> 3);
    const ushort* Kg = Kb + (size_t)(tok0 + srow) * 1024 + hoff + schunk * 8;
    const ushort* Vg = Vt + (size_t)(hoff + srow) * NTOK + tok0 + schunk * 8;
    const int ldsbase = w * 1024;

    const int srcA = ((g & 1) * 2) * 16 + t;
    const int srcB = srcA + 16;
    const bool hiSel = (g >> 1) != 0;

    int buf = 0;
    for (int pass = 0; pass < 2; ++pass) {
        const int qb = pass == 0 ? (31 - blockIdx.x) : blockIdx.x;
        const int qrow = tok0 + qb * 64 + w * 16 + t;
        const int qabs = qb * 64 + w * 16 + t;
        const int nt = (qb + 2) >> 1;

        short8_t qf[2];
#pragma unroll
        for (int ks = 0; ks < 2; ++ks)
            qf[ks] = *(const short8_t*)(Qb + (size_t)qrow * 1024 + hoff + ks * 32 + g * 8);

        float m_run = -3.0e38f, l_run = 0.0f;
        f32x4 oacc[4];
#pragma unroll
        for (int nf = 0; nf < 4; ++nf) oacc[nf] = (f32x4){0.f, 0.f, 0.f, 0.f};

#pragma unroll
        for (int hf = 0; hf < 2; ++hf)
#pragma unroll
            for (int i = 0; i < 2; ++i) {
                gload_lds16(Kg + (size_t)(hf * 64 + i * 8) * 1024, &Ks[buf][hf][ldsbase + i * 512]);
                gload_lds16(Vg + hf * 64 + (size_t)(i * 8) * NTOK, &Vs[buf][hf][ldsbase + i * 512]);
            }
        __syncthreads();

        for (int kt = 0; kt < nt; ++kt) {
            if (kt + 1 < nt) {
                const int nk = (kt + 1) * 128;
#pragma unroll
                for (int hf = 0; hf < 2; ++hf)
#pragma unroll
                    for (int i = 0; i < 2; ++i) {
                        gload_lds16(Kg + (size_t)(nk + hf * 64 + i * 8) * 1024, &Ks[buf ^ 1][hf][ldsbase + i * 512]);
                        gload_lds16(Vg + nk + hf * 64 + (size_t)(i * 8) * NTOK, &Vs[buf ^ 1][hf][ldsbase + i * 512]);
                    }
            }
            f32x4 sa[2][4];
#pragma unroll
            for (int hf = 0; hf < 2; ++hf)
#pragma unroll
                for (int mf = 0; mf < 4; ++mf) sa[hf][mf] = (f32x4){0.f, 0.f, 0.f, 0.f};
            __builtin_amdgcn_s_setprio(1);
#pragma unroll
            for (int hf = 0; hf < 2; ++hf)
#pragma unroll
                for (int ks = 0; ks < 2; ++ks) {
                    const int jc = ks * 4 + g;
#pragma unroll
                    for (int mf = 0; mf < 4; ++mf) {
                        const short8_t kf = *(const short8_t*)&Ks[buf][hf][(mf * 16 + t) * 64 + ((jc ^ (t & 7)) * 8)];
                        sa[hf][mf] = __builtin_amdgcn_mfma_f32_16x16x32_bf16(kf, qf[ks], sa[hf][mf], 0, 0, 0);
                    }
                }
            __builtin_amdgcn_s_setprio(0);

            float p[2][4][4];
            float mloc = -3.0e38f;
            const bool lastTile = (kt == nt - 1);
#pragma unroll
            for (int hf = 0; hf < 2; ++hf)
#pragma unroll
                for (int mf = 0; mf < 4; ++mf)
#pragma unroll
                    for (int r = 0; r < 4; ++r) {
                        float s = sa[hf][mf][r];
                        if (lastTile && (kt * 128 + hf * 64 + mf * 16 + g * 4 + r) > qabs) s = -3.0e38f;
                        p[hf][mf][r] = s;
                        mloc = fmaxf(mloc, s);
                    }
            mloc = fmaxf(mloc, __shfl_xor(mloc, 16));
            mloc = fmaxf(mloc, __shfl_xor(mloc, 32));
            const float mnew = fmaxf(m_run, mloc);
            float lsum = 0.f;
#pragma unroll
            for (int hf = 0; hf < 2; ++hf)
#pragma unroll
                for (int mf = 0; mf < 4; ++mf)
#pragma unroll
                    for (int r = 0; r < 4; ++r) {
                        const float e = __expf(p[hf][mf][r] - mnew);
                        p[hf][mf][r] = e;
                        lsum += e;
                    }
            lsum += __shfl_xor(lsum, 16);
            lsum += __shfl_xor(lsum, 32);
            const float fac = __expf(m_run - mnew);
            l_run = l_run * fac + lsum;
            m_run = mnew;
#pragma unroll
            for (int r = 0; r < 4; ++r) {
                const float fr = __shfl(fac, g * 4 + r);
#pragma unroll
                for (int nf = 0; nf < 4; ++nf) oacc[nf][r] *= fr;
            }
#pragma unroll
            for (int hf = 0; hf < 2; ++hf) {
                uint32_t pk[4][2];
#pragma unroll
                for (int mf = 0; mf < 4; ++mf) {
                    pk[mf][0] = pack2(p[hf][mf][0], p[hf][mf][1]);
                    pk[mf][1] = pack2(p[hf][mf][2], p[hf][mf][3]);
                }
#pragma unroll
                for (int ks = 0; ks < 2; ++ks) {
                    const uint32_t a00 = __shfl(pk[2 * ks][0], srcA);
                    const uint32_t a01 = __shfl(pk[2 * ks][1], srcA);
                    const uint32_t a10 = __shfl(pk[2 * ks + 1][0], srcA);
                    const uint32_t a11 = __shfl(pk[2 * ks + 1][1], srcA);
                    const uint32_t b00 = __shfl(pk[2 * ks][0], srcB);
                    const uint32_t b01 = __shfl(pk[2 * ks][1], srcB);
                    const uint32_t b10 = __shfl(pk[2 * ks + 1][0], srcB);
                    const uint32_t b11 = __shfl(pk[2 * ks + 1][1], srcB);
                    union { uint32_t u[4]; short8_t v; } pa;
                    pa.u[0] = hiSel ? a10 : a00;
                    pa.u[1] = hiSel ? a11 : a01;
                    pa.u[2] = hiSel ? b10 : b00;
                    pa.u[3] = hiSel ? b11 : b01;
                    const int jc = ks * 4 + g;
                    __builtin_amdgcn_s_setprio(1);
#pragma unroll
                    for (int nf = 0; nf < 4; ++nf) {
                        const short8_t vf = *(const short8_t*)&Vs[buf][hf][(nf * 16 + t) * 64 + ((jc ^ (t & 7)) * 8)];
                        oacc[nf] = __builtin_amdgcn_mfma_f32_16x16x32_bf16(pa.v, vf, oacc[nf], 0, 0, 0);
                    }
                    __builtin_amdgcn_s_setprio(0);
                }
            }
            __syncthreads();
            buf ^= 1;
        }
        const float inv = 1.0f / l_run;
#pragma unroll
        for (int r = 0; r < 4; ++r) {
            const float ir = __shfl(inv, g * 4 + r);
            const int orow = tok0 + qb * 64 + w * 16 + g * 4 + r;
#pragma unroll
            for (int nf = 0; nf < 4; ++nf)
                atno[(size_t)orow * 1024 + hoff + nf * 16 + t] = f2bf(oacc[nf][r] * ir);
        }
    }
}

// ---------------------------------------------------------------------------
// rat_write: fused split-K reduce + du-projection + softplus + SSM update.
// part = [2][NTOK][1152] f32 (cols: 0..1023 od, 1024..1135 A_B, 1136..1143 dl).
// ---------------------------------------------------------------------------
__global__ __launch_bounds__(256) void rat_write_kernel(
    const float* res, const float* __restrict__ part,
    const float* __restrict__ wab_b, const float* __restrict__ du_w,
    const float* __restrict__ du_b, float* out)
{
    const int t = blockIdx.x;
    const int tid = threadIdx.x;
    const float* p0 = part + (size_t)t * 1152;
    const float* p1 = p0 + (size_t)NTOK * 1152;
    __shared__ float sAB[112];
    __shared__ float sdl[8];
    if (tid < 112) sAB[tid] = p0[1024 + tid] + p1[1024 + tid] + wab_b[tid];
    if (tid >= 128 && tid < 136) {
        const int j = tid - 128;
        sdl[j] = p0[1136 + j] + p1[1136 + j];
    }
    __syncthreads();
    const float* rp = res + (size_t)t * 4096;
    float* op = out + (size_t)t * 4096;
#pragma unroll
    for (int ii = 0; ii < 4; ++ii) {
        const int hh = tid + 256 * ii;
        const int rh = hh & 15;
        const float4 w0 = *(const float4*)(du_w + hh * 8);
        const float4 w1 = *(const float4*)(du_w + hh * 8 + 4);
        float dacc = du_b[hh];
        dacc += sdl[0] * w0.x + sdl[1] * w0.y + sdl[2] * w0.z + sdl[3] * w0.w;
        dacc += sdl[4] * w1.x + sdl[5] * w1.y + sdl[6] * w1.z + sdl[7] * w1.w;
        const float delta = softplus_f(dacc);
        const float oh = p0[hh] + p1[hh];
        const float4 hs = *(const float4*)(rp + hh * 4);
        const float r4[4] = {hs.x, hs.y, hs.z, hs.w};
        float o4[4];
#pragma unroll
        for (int c = 0; c < 3; ++c) {
            const float Aneg = -softplus_f(sAB[rh * 3 + c]);
            const float Abar = expf(delta * Aneg);
            const float Bbar = (Abar - 1.0f) / (Aneg - 1e-5f) * sAB[48 + rh * 3 + c];
            o4[c] = r4[c] * Abar + oh * Bbar;
        }
        o4[3] = r4[3] + oh * (delta * sAB[96 + rh]);
        *(float4*)(op + hh * 4) = make_float4(o4[0], o4[1], o4[2], o4[3]);
    }
}

// ---------------------------------------------------------------------------
extern "C" void kernel_launch(void* const* d_in, const int* in_sizes, int n_in,
                              void* d_out, int out_size, void* d_ws, size_t ws_size,
                              hipStream_t stream)
{
    const float* hidden      = (const float*)d_in[0];
    const float* attn_read_w = (const float*)d_in[2];
    const float* attn_read_g = (const float*)d_in[3];
    const float* attn_read_b = (const float*)d_in[4];
    const float* qkv_w       = (const float*)d_in[5];
    const float* attn_wod_w  = (const float*)d_in[6];
    const float* attn_wab_w  = (const float*)d_in[7];
    const float* attn_wab_b  = (const float*)d_in[8];
    const float* attn_du_w   = (const float*)d_in[9];
    const float* attn_du_b   = (const float*)d_in[10];
    const float* mlp_read_w  = (const float*)d_in[11];
    const float* mlp_read_g  = (const float*)d_in[12];
    const float* mlp_read_b  = (const float*)d_in[13];
    const float* mlp_in_w    = (const float*)d_in[14];
    const float* mlp_wod_w   = (const float*)d_in[15];
    const float* mlp_wab_w   = (const float*)d_in[16];
    const float* mlp_wab_b   = (const float*)d_in[17];
    const float* mlp_du_w    = (const float*)d_in[18];
    const float* mlp_du_b    = (const float*)d_in[19];
    float* out = (float*)d_out;
    char* wsb = (char*)d_ws;
    const size_t N = NTOK;

    // ---- workspace layout (bytes), end = 131,334,144 ----
    ushort* qkv_wb  = (ushort*)(wsb + 0);          // 6,291,456
    ushort* wcombA  = (ushort*)(wsb + 6291456);    // 1152*1024*2 -> 8,650,752
    ushort* mlpin_b = (ushort*)(wsb + 8650752);    // 16,777,216 -> 25,427,968
    ushort* wcombM  = (ushort*)(wsb + 25427968);   // 1152*4096*2 -> 34,865,152
    char* R1 = wsb + 34865152;                     // 25,165,824 -> 60,030,976
    char* R2 = wsb + 60030976;                     // 71,303,168 -> 131,334,144
    // R1 attn: qkv_in [N*3072]b; after qkv GEMMs+rope: Qb, Kb
    ushort* qkv_in = (ushort*)R1;
    ushort* Qb     = (ushort*)R1;
    ushort* Kb     = (ushort*)(R1 + 8388608);
    // R1 mlp: mlp_in [N*2048]b
    ushort* mlp_in = (ushort*)R1;
    // R2 attn: q_ f32 | k_ f32 | Vt bf16 ; later atno bf16 @0, pA f32 @8.4M
    float*  q_   = (float*)R2;
    float*  k_   = (float*)(R2 + 16777216);
    ushort* Vt   = (ushort*)(R2 + 33554432);       // 8,388,608
    ushort* atno = (ushort*)R2;                    // 8,388,608 (over q_)
    float*  pA   = (float*)(R2 + 8388608);         // 2*N*1152*4 = 37,748,736
    // R2 mlp: upb @0 (32MB), up_ @33.5M (32MB); pM @33.5M after up_ dead
    ushort* upb  = (ushort*)R2;
    ushort* up_  = (ushort*)(R2 + 33554432);
    float*  pM   = (float*)(R2 + 33554432);

    // ---- weight conversion ----
    convert_flat_kernel<<<1536, 256, 0, stream>>>(qkv_w, qkv_wb);
    convert_flat_kernel<<<4096, 256, 0, stream>>>(mlp_in_w, mlpin_b);
    build_comb_kernel<<<576, 256, 0, stream>>>(attn_wod_w, attn_wab_w, wcombA, 1024);
    build_comb_kernel<<<2304, 256, 0, stream>>>(mlp_wod_w, mlp_wab_w, wcombM, 4096);

    // ---- attention half ----
    rat_read_kernel<3><<<N, 256, 0, stream>>>(hidden, attn_read_w, attn_read_g, attn_read_b, qkv_in);

    qkv_gemm_kernel<<<dim3(32, 8, 3), 256, 0, stream>>>(qkv_in, qkv_wb, q_, k_, Vt);

    rope_bf16_kernel<<<8192, 256, 0, stream>>>(q_, k_, Qb, Kb);

    attn_mfma_kernel<<<dim3(16, 32), 256, 0, stream>>>(Qb, Kb, Vt, atno);

    mfma_gemm_kernel<0><<<dim3(32, 9, 2), 256, 0, stream>>>(atno, 1024, wcombA, 1024, pA, 1152, 1144, nullptr, 512);

    rat_write_kernel<<<N, 256, 0, stream>>>(hidden, pA, attn_wab_b, attn_du_w, attn_du_b, out);

    // ---- MLP half ----
    rat_read_kernel<2><<<N, 256, 0, stream>>>(out, mlp_read_w, mlp_read_g, mlp_read_b, mlp_in);

    gemm256_kernel<1><<<dim3(16, 16), 512, 0, stream>>>(mlp_in + 1024, 2048, mlpin_b + 4194304, 1024, up_, 4096, nullptr, 1024);
    gemm256_kernel<2><<<dim3(16, 16), 512, 0, stream>>>(mlp_in, 2048, mlpin_b, 1024, upb, 4096, up_, 1024);

    mfma_gemm_kernel<0><<<dim3(32, 9, 2), 256, 0, stream>>>(upb, 4096, wcombM, 4096, pM, 1152, 1144, nullptr, 2048);

    rat_write_kernel<<<N, 256, 0, stream>>>(out, pM, mlp_wab_b, mlp_du_w, mlp_du_b, out);
}